// Round 1
// baseline (12372.747 us; speedup 1.0000x reference)
//
#include <hip/hip_runtime.h>
#include <hip/hip_bf16.h>
#include <math.h>

// ---------------- constants of the problem ----------------
#define IN_DIM 512
#define HID 256
#define HEADS 8
#define HC (HEADS * HID)   // 2048
#define OUT_DIM 5
#define NEG_SLOPE 0.2f

// ---------------- fp32 tiled GEMM: out[M,Nc] = A[M,K] @ W[K,Nc] + bias ----------------
#define BM 64
#define BN 64
#define BK 16

template <bool RELU>
__global__ __launch_bounds__(256) void gemm_bias(
    const float* __restrict__ A, const float* __restrict__ W,
    const float* __restrict__ bias, float* __restrict__ out,
    int M, int Nc, int K) {
  __shared__ float As[BK][BM + 1];
  __shared__ float Bs[BK][BN + 1];
  const int tid = threadIdx.x;
  const int tx = tid & 15;        // 0..15 (cols)
  const int ty = tid >> 4;        // 0..15 (rows)
  const int row0 = blockIdx.y * BM;
  const int col0 = blockIdx.x * BN;

  float acc[4][4] = {};

  for (int k0 = 0; k0 < K; k0 += BK) {
    // load A tile (BM x BK) -> As[k][m]
#pragma unroll
    for (int i = 0; i < 4; i++) {
      int idx = tid + i * 256;      // 0..1023
      int m = idx >> 4;             // /16
      int kk = idx & 15;
      int gm = row0 + m;
      As[kk][m] = (gm < M) ? A[(size_t)gm * K + k0 + kk] : 0.f;
    }
    // load B tile (BK x BN) -> Bs[k][n]
#pragma unroll
    for (int i = 0; i < 4; i++) {
      int idx = tid + i * 256;
      int kk = idx >> 6;            // /64
      int nn = idx & 63;
      Bs[kk][nn] = W[(size_t)(k0 + kk) * Nc + col0 + nn];
    }
    __syncthreads();
#pragma unroll
    for (int kk = 0; kk < BK; kk++) {
      float a[4], b[4];
#pragma unroll
      for (int i = 0; i < 4; i++) a[i] = As[kk][ty * 4 + i];
#pragma unroll
      for (int j = 0; j < 4; j++) b[j] = Bs[kk][tx * 4 + j];
#pragma unroll
      for (int i = 0; i < 4; i++)
#pragma unroll
        for (int j = 0; j < 4; j++) acc[i][j] += a[i] * b[j];
    }
    __syncthreads();
  }

#pragma unroll
  for (int i = 0; i < 4; i++) {
    int gm = row0 + ty * 4 + i;
    if (gm >= M) continue;
#pragma unroll
    for (int j = 0; j < 4; j++) {
      int gn = col0 + tx * 4 + j;
      float v = acc[i][j] + bias[gn];
      if (RELU) v = fmaxf(v, 0.f);
      out[(size_t)gm * Nc + gn] = v;
    }
  }
}

// ---------------- monotone float<->uint encoding for atomicMax ----------------
__device__ inline unsigned fenc(float f) {
  unsigned u = __float_as_uint(f);
  return (u & 0x80000000u) ? ~u : (u | 0x80000000u);
}
__device__ inline float fdec(unsigned u) {
  return (u & 0x80000000u) ? __uint_as_float(u & 0x7FFFFFFFu)
                           : __uint_as_float(~u);
}

// ---------------- edge scores + segment max ----------------
// grid = Et blocks, block = (64, 8): wave per head
__global__ __launch_bounds__(512) void edge_scores(
    const float* __restrict__ hl, const float* __restrict__ hr,
    const int* __restrict__ ei, const float* __restrict__ att,
    float* __restrict__ scores, unsigned* __restrict__ m_int,
    int E, int Et) {
  int e = blockIdx.x;
  int h = threadIdx.y;
  int lane = threadIdx.x;
  int s, d;
  if (e < E) { s = ei[e]; d = ei[E + e]; } else { s = e - E; d = s; }

  const float4 a4 = ((const float4*)(att + h * HID))[lane];
  const float4 l4 = ((const float4*)(hl + (size_t)s * HC + h * HID))[lane];
  const float4 r4 = ((const float4*)(hr + (size_t)d * HC + h * HID))[lane];

  float sum = 0.f, g;
  g = l4.x + r4.x; g = (g > 0.f) ? g : NEG_SLOPE * g; sum += a4.x * g;
  g = l4.y + r4.y; g = (g > 0.f) ? g : NEG_SLOPE * g; sum += a4.y * g;
  g = l4.z + r4.z; g = (g > 0.f) ? g : NEG_SLOPE * g; sum += a4.z * g;
  g = l4.w + r4.w; g = (g > 0.f) ? g : NEG_SLOPE * g; sum += a4.w * g;

#pragma unroll
  for (int off = 32; off > 0; off >>= 1) sum += __shfl_down(sum, off);

  if (lane == 0) {
    scores[(size_t)e * HEADS + h] = sum;
    atomicMax(&m_int[d * HEADS + h], fenc(sum));
  }
}

// ---------------- alpha = exp(score - m[dst]); denom += alpha ----------------
__global__ void edge_alpha(float* __restrict__ scores,
                           const unsigned* __restrict__ m_int,
                           float* __restrict__ denom,
                           const int* __restrict__ ei, int E, int Et) {
  int t = blockIdx.x * blockDim.x + threadIdx.x;
  if (t >= Et * HEADS) return;
  int e = t >> 3, h = t & 7;
  int d = (e < E) ? ei[E + e] : e - E;
  float m = fdec(m_int[d * HEADS + h]);
  float a = expf(scores[t] - m);
  scores[t] = a;  // now holds unnormalized alpha
  atomicAdd(&denom[d * HEADS + h], a);
}

// ---------------- out[dst] += (alpha/denom) * hl[src] ----------------
__global__ __launch_bounds__(512) void edge_aggregate(
    const float* __restrict__ hl, const float* __restrict__ alpha,
    const float* __restrict__ denom, const int* __restrict__ ei,
    float* __restrict__ out, int E, int Et) {
  int e = blockIdx.x;
  int h = threadIdx.y;
  int lane = threadIdx.x;
  int s, d;
  if (e < E) { s = ei[e]; d = ei[E + e]; } else { s = e - E; d = s; }
  float a = alpha[(size_t)e * HEADS + h] / (denom[d * HEADS + h] + 1e-16f);
  const float4 l4 = ((const float4*)(hl + (size_t)s * HC + h * HID))[lane];
  float* o = out + (size_t)d * HC + h * HID + lane * 4;
  atomicAdd(o + 0, a * l4.x);
  atomicAdd(o + 1, a * l4.y);
  atomicAdd(o + 2, a * l4.z);
  atomicAdd(o + 3, a * l4.w);
}

// ---------------- h = elu(h + bias) in place ----------------
__global__ void bias_elu(float* __restrict__ buf, const float* __restrict__ bias,
                         int total, int cols) {
  int t = blockIdx.x * blockDim.x + threadIdx.x;
  if (t >= total) return;
  float v = buf[t] + bias[t % cols];
  buf[t] = (v > 0.f) ? v : (expf(v) - 1.f);
}

// ---------------- mean over heads + bias: [N, H*C] -> [N, C] ----------------
__global__ void mean_heads(const float* __restrict__ in,
                           const float* __restrict__ bias,
                           float* __restrict__ out, int N) {
  int t = blockIdx.x * blockDim.x + threadIdx.x;
  if (t >= N * HID) return;
  int n = t >> 8;        // /256
  int c = t & 255;
  const float* r = in + (size_t)n * HC + c;
  float s = 0.f;
#pragma unroll
  for (int h = 0; h < HEADS; h++) s += r[h * HID];
  out[t] = 0.125f * s + bias[c];
}

// ---------------- tiny final projection: out[N,O] = hid[N,K] @ W[K,O] + b ----------------
__global__ void head_final(const float* __restrict__ hid,
                           const float* __restrict__ W,
                           const float* __restrict__ b,
                           float* __restrict__ out, int N, int K, int O) {
  int t = blockIdx.x * blockDim.x + threadIdx.x;
  if (t >= N * O) return;
  int n = t / O, j = t % O;
  float s = b[j];
  const float* hrow = hid + (size_t)n * K;
  for (int k = 0; k < K; k++) s += hrow[k] * W[(size_t)k * O + j];
  out[t] = s;
}

// ---------------- host side ----------------
static inline void run_gemm(const float* A, const float* W, const float* bias,
                            float* out, int M, int Nc, int K, bool relu,
                            hipStream_t stream) {
  dim3 grid((Nc + BN - 1) / BN, (M + BM - 1) / BM);
  if (relu)
    gemm_bias<true><<<grid, 256, 0, stream>>>(A, W, bias, out, M, Nc, K);
  else
    gemm_bias<false><<<grid, 256, 0, stream>>>(A, W, bias, out, M, Nc, K);
}

extern "C" void kernel_launch(void* const* d_in, const int* in_sizes, int n_in,
                              void* d_out, int out_size, void* d_ws, size_t ws_size,
                              hipStream_t stream) {
  const float* x   = (const float*)d_in[0];
  const int*   ei  = (const int*)d_in[1];
  const float* Wl0 = (const float*)d_in[2];  const float* bl0 = (const float*)d_in[3];
  const float* Wr0 = (const float*)d_in[4];  const float* br0 = (const float*)d_in[5];
  const float* att0= (const float*)d_in[6];  const float* b0  = (const float*)d_in[7];
  const float* Wl1 = (const float*)d_in[8];  const float* bl1 = (const float*)d_in[9];
  const float* Wr1 = (const float*)d_in[10]; const float* br1 = (const float*)d_in[11];
  const float* att1= (const float*)d_in[12]; const float* b1  = (const float*)d_in[13];
  const float* Wl2 = (const float*)d_in[14]; const float* bl2 = (const float*)d_in[15];
  const float* Wr2 = (const float*)d_in[16]; const float* br2 = (const float*)d_in[17];
  const float* att2= (const float*)d_in[18]; const float* b2  = (const float*)d_in[19];
  const float* W_pam1 = (const float*)d_in[20]; const float* b_pam1 = (const float*)d_in[21];
  const float* W_pam2 = (const float*)d_in[22]; const float* b_pam2 = (const float*)d_in[23];
  const float* W_sur1 = (const float*)d_in[24]; const float* b_sur1 = (const float*)d_in[25];
  const float* W_sur2 = (const float*)d_in[26]; const float* b_sur2 = (const float*)d_in[27];

  const int N  = in_sizes[0] / IN_DIM;   // 10000
  const int E  = in_sizes[1] / 2;        // 40000
  const int Et = E + N;                  // with self loops

  // workspace layout
  const size_t NF = (size_t)N * HC;
  float* bufA   = (float*)d_ws;
  float* bufB   = bufA + NF;
  float* bufC   = bufB + NF;
  float* scores = bufC + NF;                       // Et*HEADS
  unsigned* m_int = (unsigned*)(scores + (size_t)Et * HEADS);
  float* denom  = (float*)(m_int + (size_t)N * HEADS);
  float* hfin   = denom + (size_t)N * HEADS;       // N*HID
  float* hid    = hfin + (size_t)N * HID;          // N*128 (reused by both heads)

  float* out_pam = (float*)d_out;           // N*5
  float* out_sur = out_pam + (size_t)N * OUT_DIM;  // N*1

  dim3 eblk(64, HEADS);
  int alpha_threads = Et * HEADS;

  // ---------- layer 0 ----------
  run_gemm(x, Wl0, bl0, bufA, N, HC, IN_DIM, false, stream);
  run_gemm(x, Wr0, br0, bufB, N, HC, IN_DIM, false, stream);
  hipMemsetAsync(m_int, 0, (size_t)N * HEADS * 4, stream);
  hipMemsetAsync(denom, 0, (size_t)N * HEADS * 4, stream);
  edge_scores<<<Et, eblk, 0, stream>>>(bufA, bufB, ei, att0, scores, m_int, E, Et);
  edge_alpha<<<(alpha_threads + 255) / 256, 256, 0, stream>>>(scores, m_int, denom, ei, E, Et);
  hipMemsetAsync(bufC, 0, NF * 4, stream);
  edge_aggregate<<<Et, eblk, 0, stream>>>(bufA, scores, denom, ei, bufC, E, Et);
  bias_elu<<<((int)NF + 255) / 256, 256, 0, stream>>>(bufC, b0, (int)NF, HC);

  // ---------- layer 1 ----------
  run_gemm(bufC, Wl1, bl1, bufA, N, HC, HC, false, stream);
  run_gemm(bufC, Wr1, br1, bufB, N, HC, HC, false, stream);
  hipMemsetAsync(m_int, 0, (size_t)N * HEADS * 4, stream);
  hipMemsetAsync(denom, 0, (size_t)N * HEADS * 4, stream);
  edge_scores<<<Et, eblk, 0, stream>>>(bufA, bufB, ei, att1, scores, m_int, E, Et);
  edge_alpha<<<(alpha_threads + 255) / 256, 256, 0, stream>>>(scores, m_int, denom, ei, E, Et);
  hipMemsetAsync(bufC, 0, NF * 4, stream);
  edge_aggregate<<<Et, eblk, 0, stream>>>(bufA, scores, denom, ei, bufC, E, Et);
  bias_elu<<<((int)NF + 255) / 256, 256, 0, stream>>>(bufC, b1, (int)NF, HC);

  // ---------- layer 2 (mean over heads) ----------
  run_gemm(bufC, Wl2, bl2, bufA, N, HC, HC, false, stream);
  run_gemm(bufC, Wr2, br2, bufB, N, HC, HC, false, stream);
  hipMemsetAsync(m_int, 0, (size_t)N * HEADS * 4, stream);
  hipMemsetAsync(denom, 0, (size_t)N * HEADS * 4, stream);
  edge_scores<<<Et, eblk, 0, stream>>>(bufA, bufB, ei, att2, scores, m_int, E, Et);
  edge_alpha<<<(alpha_threads + 255) / 256, 256, 0, stream>>>(scores, m_int, denom, ei, E, Et);
  hipMemsetAsync(bufC, 0, NF * 4, stream);
  edge_aggregate<<<Et, eblk, 0, stream>>>(bufA, scores, denom, ei, bufC, E, Et);
  mean_heads<<<(N * HID + 255) / 256, 256, 0, stream>>>(bufC, b2, hfin, N);

  // ---------- heads ----------
  run_gemm(hfin, W_pam1, b_pam1, hid, N, HID / 2, HID, true, stream);
  head_final<<<(N * OUT_DIM + 255) / 256, 256, 0, stream>>>(hid, W_pam2, b_pam2, out_pam, N, HID / 2, OUT_DIM);
  run_gemm(hfin, W_sur1, b_sur1, hid, N, HID / 2, HID, true, stream);
  head_final<<<(N + 255) / 256, 256, 0, stream>>>(hid, W_sur2, b_sur2, out_sur, N, HID / 2, 1);
}

// Round 3
// 6006.036 us; speedup vs baseline: 2.0601x; 2.0601x over previous
//
#include <hip/hip_runtime.h>
#include <hip/hip_bf16.h>
#include <math.h>

// ---------------- constants of the problem ----------------
#define IN_DIM 512
#define HID 256
#define HEADS 8
#define HC (HEADS * HID)   // 2048
#define OUT_DIM 5
#define NEG_SLOPE 0.2f

typedef short s16x8 __attribute__((ext_vector_type(8)));
typedef float f32x4 __attribute__((ext_vector_type(4)));

// ---------------- bf16 split helpers (round-to-nearest-even) ----------------
__device__ inline unsigned short bf16_rne(float f) {
  unsigned u = __float_as_uint(f);
  unsigned r = (u + 0x7fffu + ((u >> 16) & 1u)) >> 16;
  return (unsigned short)r;
}
__device__ inline float bf16_to_f(unsigned short h) {
  return __uint_as_float(((unsigned)h) << 16);
}
__device__ inline void split8(const float* f, s16x8& hv, s16x8& lv) {
  s16x8 h, l;
#pragma unroll
  for (int i = 0; i < 8; i++) {
    unsigned short hs = bf16_rne(f[i]);
    h[i] = (short)hs;
    l[i] = (short)bf16_rne(f[i] - bf16_to_f(hs));
  }
  hv = h; lv = l;
}

// ---------------- fused split-bf16 MFMA GEMM ----------------
// C[M][Nc] = A[M][K] @ W[K][Nc] + bias,  A,W fp32 in global.
// In-kernel: A tile -> (hi,lo) bf16 in LDS; W tile transposed+split in LDS.
// 3-product accumulation: Ah*Bh + Ah*Bl + Al*Bh in fp32 (MFMA).
__global__ __launch_bounds__(256, 2) void gemm_fused(
    const float* __restrict__ A, const float* __restrict__ W,
    const float* __restrict__ bias, float* __restrict__ C,
    int M, int Nc, int K) {
  __shared__ __attribute__((aligned(16))) unsigned short ah_s[128 * 32];
  __shared__ __attribute__((aligned(16))) unsigned short al_s[128 * 32];
  __shared__ __attribute__((aligned(16))) unsigned short bh_s[128 * 32];
  __shared__ __attribute__((aligned(16))) unsigned short bl_s[128 * 32];

  const int tid = threadIdx.x;
  const int lane = tid & 63;
  const int w = tid >> 6;          // wave 0..3
  const int wr = w >> 1, wc = w & 1;
  const int row0 = blockIdx.y * 128;
  const int col0 = blockIdx.x * 128;

  // staging block mapping: block b (0..511) -> (rc = b>>2, k8 = (b&3)*8)
  // thread handles b = tid and b = tid + 256; LDS byte dest = b*16 (contiguous).
  const int rc = tid >> 2;              // 0..63  (row for A, col for Bt)
  const int k8 = (tid & 3) * 8;         // k offset within 32-k tile
  const bool av0 = (row0 + rc) < M;
  const bool av1 = (row0 + rc + 64) < M;
  const float* gA0 = A + (size_t)(row0 + rc) * K + k8;
  const float* gA1 = A + (size_t)(row0 + rc + 64) * K + k8;

  f32x4 acc[4][4];
#pragma unroll
  for (int i = 0; i < 4; i++)
#pragma unroll
    for (int j = 0; j < 4; j++) acc[i][j] = (f32x4){0.f, 0.f, 0.f, 0.f};

  const int fr = lane & 15;   // frag fast index
  const int fq = lane >> 4;   // 0..3

  for (int k0 = 0; k0 < K; k0 += 32) {
    // ---- global loads (regs) ----
    float fa0[8] = {}, fa1[8] = {};
    if (av0) {
      float4 t0 = *(const float4*)(gA0 + k0);
      float4 t1 = *(const float4*)(gA0 + k0 + 4);
      fa0[0] = t0.x; fa0[1] = t0.y; fa0[2] = t0.z; fa0[3] = t0.w;
      fa0[4] = t1.x; fa0[5] = t1.y; fa0[6] = t1.z; fa0[7] = t1.w;
    }
    if (av1) {
      float4 t0 = *(const float4*)(gA1 + k0);
      float4 t1 = *(const float4*)(gA1 + k0 + 4);
      fa1[0] = t0.x; fa1[1] = t0.y; fa1[2] = t0.z; fa1[3] = t0.w;
      fa1[4] = t1.x; fa1[5] = t1.y; fa1[6] = t1.z; fa1[7] = t1.w;
    }
    // W transpose gather: 8 k-values for columns col0+rc and col0+rc+64
    float fb0[8], fb1[8];
    {
      const float* p = W + (size_t)(k0 + k8) * Nc + col0;
#pragma unroll
      for (int j = 0; j < 8; j++) {
        fb0[j] = p[(size_t)j * Nc + rc];
        fb1[j] = p[(size_t)j * Nc + rc + 64];
      }
    }

    __syncthreads();   // previous iteration's frag reads complete

    // ---- convert + LDS writes (contiguous, conflict-free) ----
    s16x8 h, l;
    split8(fa0, h, l);
    *(s16x8*)&ah_s[rc * 32 + k8] = h;  *(s16x8*)&al_s[rc * 32 + k8] = l;
    split8(fa1, h, l);
    *(s16x8*)&ah_s[(rc + 64) * 32 + k8] = h;  *(s16x8*)&al_s[(rc + 64) * 32 + k8] = l;
    split8(fb0, h, l);
    *(s16x8*)&bh_s[rc * 32 + k8] = h;  *(s16x8*)&bl_s[rc * 32 + k8] = l;
    split8(fb1, h, l);
    *(s16x8*)&bh_s[(rc + 64) * 32 + k8] = h;  *(s16x8*)&bl_s[(rc + 64) * 32 + k8] = l;

    __syncthreads();   // LDS tile visible

    // ---- fragment reads + MFMA ----
    s16x8 ah[4], al[4], bh[4], bl[4];
#pragma unroll
    for (int i = 0; i < 4; i++) {
      int off = (wr * 64 + i * 16 + fr) * 32 + fq * 8;
      ah[i] = *(const s16x8*)&ah_s[off];
      al[i] = *(const s16x8*)&al_s[off];
    }
#pragma unroll
    for (int j = 0; j < 4; j++) {
      int off = (wc * 64 + j * 16 + fr) * 32 + fq * 8;
      bh[j] = *(const s16x8*)&bh_s[off];
      bl[j] = *(const s16x8*)&bl_s[off];
    }
#pragma unroll
    for (int i = 0; i < 4; i++)
#pragma unroll
      for (int j = 0; j < 4; j++) {
        acc[i][j] = __builtin_amdgcn_mfma_f32_16x16x32_bf16(ah[i], bh[j], acc[i][j], 0, 0, 0);
        acc[i][j] = __builtin_amdgcn_mfma_f32_16x16x32_bf16(ah[i], bl[j], acc[i][j], 0, 0, 0);
        acc[i][j] = __builtin_amdgcn_mfma_f32_16x16x32_bf16(al[i], bh[j], acc[i][j], 0, 0, 0);
      }
  }

  // epilogue: C col = lane&15, row = (lane>>4)*4 + reg (per 16x16 frag)
#pragma unroll
  for (int j = 0; j < 4; j++) {
    int col = col0 + wc * 64 + j * 16 + fr;
    float bj = bias[col];
#pragma unroll
    for (int i = 0; i < 4; i++) {
      int rbase = row0 + wr * 64 + i * 16 + fq * 4;
#pragma unroll
      for (int r = 0; r < 4; r++) {
        int row = rbase + r;
        if (row < M) C[(size_t)row * Nc + col] = acc[i][j][r] + bj;
      }
    }
  }
}

// ---------------- fp32 tiled GEMM (small head matmuls only) ----------------
#define BM 64
#define BN 64
#define BK 16

template <bool RELU>
__global__ __launch_bounds__(256) void gemm_bias(
    const float* __restrict__ A, const float* __restrict__ W,
    const float* __restrict__ bias, float* __restrict__ out,
    int M, int Nc, int K) {
  __shared__ float As[BK][BM + 1];
  __shared__ float Bs[BK][BN + 1];
  const int tid = threadIdx.x;
  const int tx = tid & 15;
  const int ty = tid >> 4;
  const int row0 = blockIdx.y * BM;
  const int col0 = blockIdx.x * BN;

  float acc[4][4] = {};

  for (int k0 = 0; k0 < K; k0 += BK) {
#pragma unroll
    for (int i = 0; i < 4; i++) {
      int idx = tid + i * 256;
      int m = idx >> 4;
      int kk = idx & 15;
      int gm = row0 + m;
      As[kk][m] = (gm < M) ? A[(size_t)gm * K + k0 + kk] : 0.f;
    }
#pragma unroll
    for (int i = 0; i < 4; i++) {
      int idx = tid + i * 256;
      int kk = idx >> 6;
      int nn = idx & 63;
      Bs[kk][nn] = W[(size_t)(k0 + kk) * Nc + col0 + nn];
    }
    __syncthreads();
#pragma unroll
    for (int kk = 0; kk < BK; kk++) {
      float a[4], b[4];
#pragma unroll
      for (int i = 0; i < 4; i++) a[i] = As[kk][ty * 4 + i];
#pragma unroll
      for (int j = 0; j < 4; j++) b[j] = Bs[kk][tx * 4 + j];
#pragma unroll
      for (int i = 0; i < 4; i++)
#pragma unroll
        for (int j = 0; j < 4; j++) acc[i][j] += a[i] * b[j];
    }
    __syncthreads();
  }

#pragma unroll
  for (int i = 0; i < 4; i++) {
    int gm = row0 + ty * 4 + i;
    if (gm >= M) continue;
#pragma unroll
    for (int j = 0; j < 4; j++) {
      int gn = col0 + tx * 4 + j;
      float v = acc[i][j] + bias[gn];
      if (RELU) v = fmaxf(v, 0.f);
      out[(size_t)gm * Nc + gn] = v;
    }
  }
}

// ---------------- monotone float<->uint encoding for atomicMax ----------------
__device__ inline unsigned fenc(float f) {
  unsigned u = __float_as_uint(f);
  return (u & 0x80000000u) ? ~u : (u | 0x80000000u);
}
__device__ inline float fdec(unsigned u) {
  return (u & 0x80000000u) ? __uint_as_float(u & 0x7FFFFFFFu)
                           : __uint_as_float(~u);
}

// ---------------- edge scores + segment max ----------------
__global__ __launch_bounds__(512) void edge_scores(
    const float* __restrict__ hl, const float* __restrict__ hr,
    const int* __restrict__ ei, const float* __restrict__ att,
    float* __restrict__ scores, unsigned* __restrict__ m_int,
    int E, int Et) {
  int e = blockIdx.x;
  int h = threadIdx.y;
  int lane = threadIdx.x;
  int s, d;
  if (e < E) { s = ei[e]; d = ei[E + e]; } else { s = e - E; d = s; }

  const float4 a4 = ((const float4*)(att + h * HID))[lane];
  const float4 l4 = ((const float4*)(hl + (size_t)s * HC + h * HID))[lane];
  const float4 r4 = ((const float4*)(hr + (size_t)d * HC + h * HID))[lane];

  float sum = 0.f, g;
  g = l4.x + r4.x; g = (g > 0.f) ? g : NEG_SLOPE * g; sum += a4.x * g;
  g = l4.y + r4.y; g = (g > 0.f) ? g : NEG_SLOPE * g; sum += a4.y * g;
  g = l4.z + r4.z; g = (g > 0.f) ? g : NEG_SLOPE * g; sum += a4.z * g;
  g = l4.w + r4.w; g = (g > 0.f) ? g : NEG_SLOPE * g; sum += a4.w * g;

#pragma unroll
  for (int off = 32; off > 0; off >>= 1) sum += __shfl_down(sum, off);

  if (lane == 0) {
    scores[(size_t)e * HEADS + h] = sum;
    atomicMax(&m_int[d * HEADS + h], fenc(sum));
  }
}

// ---------------- alpha = exp(score - m[dst]); denom += alpha ----------------
__global__ void edge_alpha(float* __restrict__ scores,
                           const unsigned* __restrict__ m_int,
                           float* __restrict__ denom,
                           const int* __restrict__ ei, int E, int Et) {
  int t = blockIdx.x * blockDim.x + threadIdx.x;
  if (t >= Et * HEADS) return;
  int e = t >> 3, h = t & 7;
  int d = (e < E) ? ei[E + e] : e - E;
  float m = fdec(m_int[d * HEADS + h]);
  float a = expf(scores[t] - m);
  scores[t] = a;
  atomicAdd(&denom[d * HEADS + h], a);
}

// ---------------- out[dst] += (alpha/denom) * hl[src] ----------------
__global__ __launch_bounds__(512) void edge_aggregate(
    const float* __restrict__ hl, const float* __restrict__ alpha,
    const float* __restrict__ denom, const int* __restrict__ ei,
    float* __restrict__ out, int E, int Et) {
  int e = blockIdx.x;
  int h = threadIdx.y;
  int lane = threadIdx.x;
  int s, d;
  if (e < E) { s = ei[e]; d = ei[E + e]; } else { s = e - E; d = s; }
  float a = alpha[(size_t)e * HEADS + h] / (denom[d * HEADS + h] + 1e-16f);
  const float4 l4 = ((const float4*)(hl + (size_t)s * HC + h * HID))[lane];
  float* o = out + (size_t)d * HC + h * HID + lane * 4;
  atomicAdd(o + 0, a * l4.x);
  atomicAdd(o + 1, a * l4.y);
  atomicAdd(o + 2, a * l4.z);
  atomicAdd(o + 3, a * l4.w);
}

// ---------------- h = elu(h + bias) in place ----------------
__global__ void bias_elu(float* __restrict__ buf, const float* __restrict__ bias,
                         int total, int cols) {
  int t = blockIdx.x * blockDim.x + threadIdx.x;
  if (t >= total) return;
  float v = buf[t] + bias[t % cols];
  buf[t] = (v > 0.f) ? v : (expf(v) - 1.f);
}

// ---------------- mean over heads + bias: [N, H*C] -> [N, C] ----------------
__global__ void mean_heads(const float* __restrict__ in,
                           const float* __restrict__ bias,
                           float* __restrict__ out, int N) {
  int t = blockIdx.x * blockDim.x + threadIdx.x;
  if (t >= N * HID) return;
  int n = t >> 8;
  int c = t & 255;
  const float* r = in + (size_t)n * HC + c;
  float s = 0.f;
#pragma unroll
  for (int h = 0; h < HEADS; h++) s += r[h * HID];
  out[t] = 0.125f * s + bias[c];
}

// ---------------- tiny final projection ----------------
__global__ void head_final(const float* __restrict__ hid,
                           const float* __restrict__ W,
                           const float* __restrict__ b,
                           float* __restrict__ out, int N, int K, int O) {
  int t = blockIdx.x * blockDim.x + threadIdx.x;
  if (t >= N * O) return;
  int n = t / O, j = t % O;
  float s = b[j];
  const float* hrow = hid + (size_t)n * K;
  for (int k = 0; k < K; k++) s += hrow[k] * W[(size_t)k * O + j];
  out[t] = s;
}

// ---------------- host side ----------------
static inline void run_big_gemm(const float* A, const float* W, const float* bias,
                                float* out, int M, int Nc, int K, hipStream_t stream) {
  dim3 grid(Nc / 128, (M + 127) / 128);
  gemm_fused<<<grid, 256, 0, stream>>>(A, W, bias, out, M, Nc, K);
}

static inline void run_gemm_f32(const float* A, const float* W, const float* bias,
                                float* out, int M, int Nc, int K, bool relu,
                                hipStream_t stream) {
  dim3 grid((Nc + BN - 1) / BN, (M + BM - 1) / BM);
  if (relu)
    gemm_bias<true><<<grid, 256, 0, stream>>>(A, W, bias, out, M, Nc, K);
  else
    gemm_bias<false><<<grid, 256, 0, stream>>>(A, W, bias, out, M, Nc, K);
}

extern "C" void kernel_launch(void* const* d_in, const int* in_sizes, int n_in,
                              void* d_out, int out_size, void* d_ws, size_t ws_size,
                              hipStream_t stream) {
  const float* x   = (const float*)d_in[0];
  const int*   ei  = (const int*)d_in[1];
  const float* Wl0 = (const float*)d_in[2];  const float* bl0 = (const float*)d_in[3];
  const float* Wr0 = (const float*)d_in[4];  const float* br0 = (const float*)d_in[5];
  const float* att0= (const float*)d_in[6];  const float* b0  = (const float*)d_in[7];
  const float* Wl1 = (const float*)d_in[8];  const float* bl1 = (const float*)d_in[9];
  const float* Wr1 = (const float*)d_in[10]; const float* br1 = (const float*)d_in[11];
  const float* att1= (const float*)d_in[12]; const float* b1  = (const float*)d_in[13];
  const float* Wl2 = (const float*)d_in[14]; const float* bl2 = (const float*)d_in[15];
  const float* Wr2 = (const float*)d_in[16]; const float* br2 = (const float*)d_in[17];
  const float* att2= (const float*)d_in[18]; const float* b2  = (const float*)d_in[19];
  const float* W_pam1 = (const float*)d_in[20]; const float* b_pam1 = (const float*)d_in[21];
  const float* W_pam2 = (const float*)d_in[22]; const float* b_pam2 = (const float*)d_in[23];
  const float* W_sur1 = (const float*)d_in[24]; const float* b_sur1 = (const float*)d_in[25];
  const float* W_sur2 = (const float*)d_in[26]; const float* b_sur2 = (const float*)d_in[27];

  const int N  = in_sizes[0] / IN_DIM;   // 10000
  const int E  = in_sizes[1] / 2;        // 40000
  const int Et = E + N;

  // ---- workspace layout (248 MB total; round-1-proven footprint) ----
  const size_t NF = (size_t)N * HC;
  float* bufA   = (float*)d_ws;
  float* bufB   = bufA + NF;
  float* bufC   = bufB + NF;
  float* scores = bufC + NF;                       // Et*HEADS
  unsigned* m_int = (unsigned*)(scores + (size_t)Et * HEADS);
  float* denom  = (float*)(m_int + (size_t)N * HEADS);
  // head-stage buffers alias bufA (dead after layer-2 aggregation)
  float* hfin = bufA;                   // N*HID
  float* hid  = bufA + (size_t)N * HID; // N*128

  float* out_pam = (float*)d_out;
  float* out_sur = out_pam + (size_t)N * OUT_DIM;

  dim3 eblk(64, HEADS);
  int alpha_threads = Et * HEADS;

  // ---------- layer 0 ----------
  run_big_gemm(x, Wl0, bl0, bufA, N, HC, IN_DIM, stream);
  run_big_gemm(x, Wr0, br0, bufB, N, HC, IN_DIM, stream);
  hipMemsetAsync(m_int, 0, (size_t)N * HEADS * 4, stream);
  hipMemsetAsync(denom, 0, (size_t)N * HEADS * 4, stream);
  edge_scores<<<Et, eblk, 0, stream>>>(bufA, bufB, ei, att0, scores, m_int, E, Et);
  edge_alpha<<<(alpha_threads + 255) / 256, 256, 0, stream>>>(scores, m_int, denom, ei, E, Et);
  hipMemsetAsync(bufC, 0, NF * 4, stream);
  edge_aggregate<<<Et, eblk, 0, stream>>>(bufA, scores, denom, ei, bufC, E, Et);
  bias_elu<<<((int)NF + 255) / 256, 256, 0, stream>>>(bufC, b0, (int)NF, HC);

  // ---------- layer 1 ----------
  run_big_gemm(bufC, Wl1, bl1, bufA, N, HC, HC, stream);
  run_big_gemm(bufC, Wr1, br1, bufB, N, HC, HC, stream);
  hipMemsetAsync(m_int, 0, (size_t)N * HEADS * 4, stream);
  hipMemsetAsync(denom, 0, (size_t)N * HEADS * 4, stream);
  edge_scores<<<Et, eblk, 0, stream>>>(bufA, bufB, ei, att1, scores, m_int, E, Et);
  edge_alpha<<<(alpha_threads + 255) / 256, 256, 0, stream>>>(scores, m_int, denom, ei, E, Et);
  hipMemsetAsync(bufC, 0, NF * 4, stream);
  edge_aggregate<<<Et, eblk, 0, stream>>>(bufA, scores, denom, ei, bufC, E, Et);
  bias_elu<<<((int)NF + 255) / 256, 256, 0, stream>>>(bufC, b1, (int)NF, HC);

  // ---------- layer 2 (mean over heads) ----------
  run_big_gemm(bufC, Wl2, bl2, bufA, N, HC, HC, stream);
  run_big_gemm(bufC, Wr2, br2, bufB, N, HC, HC, stream);
  hipMemsetAsync(m_int, 0, (size_t)N * HEADS * 4, stream);
  hipMemsetAsync(denom, 0, (size_t)N * HEADS * 4, stream);
  edge_scores<<<Et, eblk, 0, stream>>>(bufA, bufB, ei, att2, scores, m_int, E, Et);
  edge_alpha<<<(alpha_threads + 255) / 256, 256, 0, stream>>>(scores, m_int, denom, ei, E, Et);
  hipMemsetAsync(bufC, 0, NF * 4, stream);
  edge_aggregate<<<Et, eblk, 0, stream>>>(bufA, scores, denom, ei, bufC, E, Et);
  mean_heads<<<(N * HID + 255) / 256, 256, 0, stream>>>(bufC, b2, hfin, N);

  // ---------- heads (tiny, fp32) ----------
  run_gemm_f32(hfin, W_pam1, b_pam1, hid, N, HID / 2, HID, true, stream);
  head_final<<<(N * OUT_DIM + 255) / 256, 256, 0, stream>>>(hid, W_pam2, b_pam2, out_pam, N, HID / 2, OUT_DIM);
  run_gemm_f32(hfin, W_sur1, b_sur1, hid, N, HID / 2, HID, true, stream);
  head_final<<<(N + 255) / 256, 256, 0, stream>>>(hid, W_sur2, b_sur2, out_sur, N, HID / 2, 1);
}

// Round 4
// 2312.256 us; speedup vs baseline: 5.3509x; 2.5975x over previous
//
#include <hip/hip_runtime.h>
#include <hip/hip_bf16.h>
#include <math.h>

// ---------------- constants of the problem ----------------
#define IN_DIM 512
#define HID 256
#define HEADS 8
#define HC (HEADS * HID)   // 2048
#define OUT_DIM 5
#define NEG_SLOPE 0.2f

typedef short s16x8 __attribute__((ext_vector_type(8)));
typedef float f32x4 __attribute__((ext_vector_type(4)));

// ---------------- bf16 split helpers (round-to-nearest-even) ----------------
__device__ inline unsigned short bf16_rne(float f) {
  unsigned u = __float_as_uint(f);
  unsigned r = (u + 0x7fffu + ((u >> 16) & 1u)) >> 16;
  return (unsigned short)r;
}
__device__ inline float bf16_to_f(unsigned short h) {
  return __uint_as_float(((unsigned)h) << 16);
}
__device__ inline void split8(const float* f, s16x8& hv, s16x8& lv) {
  s16x8 h, l;
#pragma unroll
  for (int i = 0; i < 8; i++) {
    unsigned short hs = bf16_rne(f[i]);
    h[i] = (short)hs;
    l[i] = (short)bf16_rne(f[i] - bf16_to_f(hs));
  }
  hv = h; lv = l;
}

// ---------------- fused split-bf16 MFMA GEMM ----------------
__global__ __launch_bounds__(256, 2) void gemm_fused(
    const float* __restrict__ A, const float* __restrict__ W,
    const float* __restrict__ bias, float* __restrict__ C,
    int M, int Nc, int K) {
  __shared__ __attribute__((aligned(16))) unsigned short ah_s[128 * 32];
  __shared__ __attribute__((aligned(16))) unsigned short al_s[128 * 32];
  __shared__ __attribute__((aligned(16))) unsigned short bh_s[128 * 32];
  __shared__ __attribute__((aligned(16))) unsigned short bl_s[128 * 32];

  const int tid = threadIdx.x;
  const int lane = tid & 63;
  const int w = tid >> 6;
  const int wr = w >> 1, wc = w & 1;
  const int row0 = blockIdx.y * 128;
  const int col0 = blockIdx.x * 128;

  const int rc = tid >> 2;              // 0..63
  const int k8 = (tid & 3) * 8;
  const bool av0 = (row0 + rc) < M;
  const bool av1 = (row0 + rc + 64) < M;
  const float* gA0 = A + (size_t)(row0 + rc) * K + k8;
  const float* gA1 = A + (size_t)(row0 + rc + 64) * K + k8;

  f32x4 acc[4][4];
#pragma unroll
  for (int i = 0; i < 4; i++)
#pragma unroll
    for (int j = 0; j < 4; j++) acc[i][j] = (f32x4){0.f, 0.f, 0.f, 0.f};

  const int fr = lane & 15;
  const int fq = lane >> 4;

  for (int k0 = 0; k0 < K; k0 += 32) {
    float fa0[8] = {}, fa1[8] = {};
    if (av0) {
      float4 t0 = *(const float4*)(gA0 + k0);
      float4 t1 = *(const float4*)(gA0 + k0 + 4);
      fa0[0] = t0.x; fa0[1] = t0.y; fa0[2] = t0.z; fa0[3] = t0.w;
      fa0[4] = t1.x; fa0[5] = t1.y; fa0[6] = t1.z; fa0[7] = t1.w;
    }
    if (av1) {
      float4 t0 = *(const float4*)(gA1 + k0);
      float4 t1 = *(const float4*)(gA1 + k0 + 4);
      fa1[0] = t0.x; fa1[1] = t0.y; fa1[2] = t0.z; fa1[3] = t0.w;
      fa1[4] = t1.x; fa1[5] = t1.y; fa1[6] = t1.z; fa1[7] = t1.w;
    }
    float fb0[8], fb1[8];
    {
      const float* p = W + (size_t)(k0 + k8) * Nc + col0;
#pragma unroll
      for (int j = 0; j < 8; j++) {
        fb0[j] = p[(size_t)j * Nc + rc];
        fb1[j] = p[(size_t)j * Nc + rc + 64];
      }
    }

    __syncthreads();

    s16x8 h, l;
    split8(fa0, h, l);
    *(s16x8*)&ah_s[rc * 32 + k8] = h;  *(s16x8*)&al_s[rc * 32 + k8] = l;
    split8(fa1, h, l);
    *(s16x8*)&ah_s[(rc + 64) * 32 + k8] = h;  *(s16x8*)&al_s[(rc + 64) * 32 + k8] = l;
    split8(fb0, h, l);
    *(s16x8*)&bh_s[rc * 32 + k8] = h;  *(s16x8*)&bl_s[rc * 32 + k8] = l;
    split8(fb1, h, l);
    *(s16x8*)&bh_s[(rc + 64) * 32 + k8] = h;  *(s16x8*)&bl_s[(rc + 64) * 32 + k8] = l;

    __syncthreads();

    s16x8 ah[4], al[4], bh[4], bl[4];
#pragma unroll
    for (int i = 0; i < 4; i++) {
      int off = (wr * 64 + i * 16 + fr) * 32 + fq * 8;
      ah[i] = *(const s16x8*)&ah_s[off];
      al[i] = *(const s16x8*)&al_s[off];
    }
#pragma unroll
    for (int j = 0; j < 4; j++) {
      int off = (wc * 64 + j * 16 + fr) * 32 + fq * 8;
      bh[j] = *(const s16x8*)&bh_s[off];
      bl[j] = *(const s16x8*)&bl_s[off];
    }
#pragma unroll
    for (int i = 0; i < 4; i++)
#pragma unroll
      for (int j = 0; j < 4; j++) {
        acc[i][j] = __builtin_amdgcn_mfma_f32_16x16x32_bf16(ah[i], bh[j], acc[i][j], 0, 0, 0);
        acc[i][j] = __builtin_amdgcn_mfma_f32_16x16x32_bf16(ah[i], bl[j], acc[i][j], 0, 0, 0);
        acc[i][j] = __builtin_amdgcn_mfma_f32_16x16x32_bf16(al[i], bh[j], acc[i][j], 0, 0, 0);
      }
  }

#pragma unroll
  for (int j = 0; j < 4; j++) {
    int col = col0 + wc * 64 + j * 16 + fr;
    float bj = bias[col];
#pragma unroll
    for (int i = 0; i < 4; i++) {
      int rbase = row0 + wr * 64 + i * 16 + fq * 4;
#pragma unroll
      for (int r = 0; r < 4; r++) {
        int row = rbase + r;
        if (row < M) C[(size_t)row * Nc + col] = acc[i][j][r] + bj;
      }
    }
  }
}

// ---------------- fp32 tiled GEMM (small head matmuls only) ----------------
#define BM 64
#define BN 64
#define BK 16

template <bool RELU>
__global__ __launch_bounds__(256) void gemm_bias(
    const float* __restrict__ A, const float* __restrict__ W,
    const float* __restrict__ bias, float* __restrict__ out,
    int M, int Nc, int K) {
  __shared__ float As[BK][BM + 1];
  __shared__ float Bs[BK][BN + 1];
  const int tid = threadIdx.x;
  const int tx = tid & 15;
  const int ty = tid >> 4;
  const int row0 = blockIdx.y * BM;
  const int col0 = blockIdx.x * BN;

  float acc[4][4] = {};

  for (int k0 = 0; k0 < K; k0 += BK) {
#pragma unroll
    for (int i = 0; i < 4; i++) {
      int idx = tid + i * 256;
      int m = idx >> 4;
      int kk = idx & 15;
      int gm = row0 + m;
      As[kk][m] = (gm < M) ? A[(size_t)gm * K + k0 + kk] : 0.f;
    }
#pragma unroll
    for (int i = 0; i < 4; i++) {
      int idx = tid + i * 256;
      int kk = idx >> 6;
      int nn = idx & 63;
      Bs[kk][nn] = W[(size_t)(k0 + kk) * Nc + col0 + nn];
    }
    __syncthreads();
#pragma unroll
    for (int kk = 0; kk < BK; kk++) {
      float a[4], b[4];
#pragma unroll
      for (int i = 0; i < 4; i++) a[i] = As[kk][ty * 4 + i];
#pragma unroll
      for (int j = 0; j < 4; j++) b[j] = Bs[kk][tx * 4 + j];
#pragma unroll
      for (int i = 0; i < 4; i++)
#pragma unroll
        for (int j = 0; j < 4; j++) acc[i][j] += a[i] * b[j];
    }
    __syncthreads();
  }

#pragma unroll
  for (int i = 0; i < 4; i++) {
    int gm = row0 + ty * 4 + i;
    if (gm >= M) continue;
#pragma unroll
    for (int j = 0; j < 4; j++) {
      int gn = col0 + tx * 4 + j;
      float v = acc[i][j] + bias[gn];
      if (RELU) v = fmaxf(v, 0.f);
      out[(size_t)gm * Nc + gn] = v;
    }
  }
}

// ---------------- monotone float<->uint encoding for atomicMax ----------------
__device__ inline unsigned fenc(float f) {
  unsigned u = __float_as_uint(f);
  return (u & 0x80000000u) ? ~u : (u | 0x80000000u);
}
__device__ inline float fdec(unsigned u) {
  return (u & 0x80000000u) ? __uint_as_float(u & 0x7FFFFFFFu)
                           : __uint_as_float(~u);
}

// ---------------- CSR build ----------------
__global__ void count_dst(const int* __restrict__ ei, int* __restrict__ cnt,
                          int E, int Et) {
  int t = blockIdx.x * blockDim.x + threadIdx.x;
  if (t >= Et) return;
  int d = (t < E) ? ei[E + t] : t - E;
  atomicAdd(&cnt[d], 1);
}

#define SCAN_T 1024
__global__ __launch_bounds__(SCAN_T) void scan_offsets(
    const int* __restrict__ cnt, int* __restrict__ row_off, int N) {
  __shared__ int ssum[SCAN_T];
  int t = threadIdx.x;
  int per = (N + SCAN_T - 1) / SCAN_T;
  int beg = t * per, end = min(beg + per, N);
  int s = 0;
  for (int i = beg; i < end; i++) s += cnt[i];
  ssum[t] = s;
  __syncthreads();
  for (int off = 1; off < SCAN_T; off <<= 1) {
    int v = (t >= off) ? ssum[t - off] : 0;
    __syncthreads();
    ssum[t] += v;
    __syncthreads();
  }
  int run = (t == 0) ? 0 : ssum[t - 1];
  for (int i = beg; i < end; i++) { row_off[i] = run; run += cnt[i]; }
  if (t == 0) row_off[N] = ssum[SCAN_T - 1];
}

__global__ void scatter_edges(const int* __restrict__ ei,
                              const int* __restrict__ row_off,
                              int* __restrict__ fill,
                              int* __restrict__ esrc, int* __restrict__ pos_of,
                              int E, int Et) {
  int t = blockIdx.x * blockDim.x + threadIdx.x;
  if (t >= Et) return;
  int s, d;
  if (t < E) { s = ei[t]; d = ei[E + t]; } else { s = t - E; d = s; }
  int pos = row_off[d] + atomicAdd(&fill[d], 1);
  esrc[pos] = s;
  pos_of[t] = pos;
}

// ---------------- edge scores + segment max ----------------
__global__ __launch_bounds__(512) void edge_scores(
    const float* __restrict__ hl, const float* __restrict__ hr,
    const int* __restrict__ ei, const float* __restrict__ att,
    float* __restrict__ scores, unsigned* __restrict__ m_int,
    int E, int Et) {
  int e = blockIdx.x;
  int h = threadIdx.y;
  int lane = threadIdx.x;
  int s, d;
  if (e < E) { s = ei[e]; d = ei[E + e]; } else { s = e - E; d = s; }

  const float4 a4 = ((const float4*)(att + h * HID))[lane];
  const float4 l4 = ((const float4*)(hl + (size_t)s * HC + h * HID))[lane];
  const float4 r4 = ((const float4*)(hr + (size_t)d * HC + h * HID))[lane];

  float sum = 0.f, g;
  g = l4.x + r4.x; g = (g > 0.f) ? g : NEG_SLOPE * g; sum += a4.x * g;
  g = l4.y + r4.y; g = (g > 0.f) ? g : NEG_SLOPE * g; sum += a4.y * g;
  g = l4.z + r4.z; g = (g > 0.f) ? g : NEG_SLOPE * g; sum += a4.z * g;
  g = l4.w + r4.w; g = (g > 0.f) ? g : NEG_SLOPE * g; sum += a4.w * g;

#pragma unroll
  for (int off = 32; off > 0; off >>= 1) sum += __shfl_down(sum, off);

  if (lane == 0) {
    scores[(size_t)e * HEADS + h] = sum;
    atomicMax(&m_int[d * HEADS + h], fenc(sum));
  }
}

// ---------------- alpha = exp(score - m[dst]) -> CSR order; denom += alpha ----------------
__global__ void edge_alpha(const float* __restrict__ scores,
                           float* __restrict__ asort,
                           const unsigned* __restrict__ m_int,
                           float* __restrict__ denom,
                           const int* __restrict__ ei,
                           const int* __restrict__ pos_of, int E, int Et) {
  int t = blockIdx.x * blockDim.x + threadIdx.x;
  if (t >= Et * HEADS) return;
  int e = t >> 3, h = t & 7;
  int d = (e < E) ? ei[E + e] : e - E;
  float m = fdec(m_int[d * HEADS + h]);
  float a = expf(scores[t] - m);
  asort[(size_t)pos_of[e] * HEADS + h] = a;
  atomicAdd(&denom[d * HEADS + h], a);
}

// ---------------- CSR aggregation: out[n] = sum_j alpha_j * hl[src_j] / denom ----------------
// block = 256 threads: head h = t>>5, lane l = t&31 handles dims [l*8, l*8+8)
template <bool ELU>
__global__ __launch_bounds__(256) void aggregate_csr(
    const float* __restrict__ hl, const float* __restrict__ asort,
    const float* __restrict__ denom, const int* __restrict__ row_off,
    const int* __restrict__ esrc, const float* __restrict__ bias,
    float* __restrict__ out, int N) {
  int n = blockIdx.x;
  int t = threadIdx.x;
  int h = t >> 5;
  int l = t & 31;
  int beg = row_off[n], end = row_off[n + 1];

  f32x4 a0 = {0.f, 0.f, 0.f, 0.f}, a1 = {0.f, 0.f, 0.f, 0.f};
  for (int j = beg; j < end; j++) {
    int src = esrc[j];
    float a = asort[(size_t)j * HEADS + h];
    const f32x4* p = (const f32x4*)(hl + (size_t)src * HC + h * HID + l * 8);
    f32x4 v0 = p[0], v1 = p[1];
    a0 += a * v0;
    a1 += a * v1;
  }
  float dn = 1.f / (denom[n * HEADS + h] + 1e-16f);
  int cbase = h * HID + l * 8;
  float* o = out + (size_t)n * HC + cbase;
#pragma unroll
  for (int q = 0; q < 4; q++) {
    float v = a0[q] * dn + (ELU ? bias[cbase + q] : 0.f);
    if (ELU) v = (v > 0.f) ? v : (expf(v) - 1.f);
    o[q] = v;
  }
#pragma unroll
  for (int q = 0; q < 4; q++) {
    float v = a1[q] * dn + (ELU ? bias[cbase + 4 + q] : 0.f);
    if (ELU) v = (v > 0.f) ? v : (expf(v) - 1.f);
    o[4 + q] = v;
  }
}

// ---------------- mean over heads + bias: [N, H*C] -> [N, C] ----------------
__global__ void mean_heads(const float* __restrict__ in,
                           const float* __restrict__ bias,
                           float* __restrict__ out, int N) {
  int t = blockIdx.x * blockDim.x + threadIdx.x;
  if (t >= N * HID) return;
  int n = t >> 8;
  int c = t & 255;
  const float* r = in + (size_t)n * HC + c;
  float s = 0.f;
#pragma unroll
  for (int h = 0; h < HEADS; h++) s += r[h * HID];
  out[t] = 0.125f * s + bias[c];
}

// ---------------- tiny final projection ----------------
__global__ void head_final(const float* __restrict__ hid,
                           const float* __restrict__ W,
                           const float* __restrict__ b,
                           float* __restrict__ out, int N, int K, int O) {
  int t = blockIdx.x * blockDim.x + threadIdx.x;
  if (t >= N * O) return;
  int n = t / O, j = t % O;
  float s = b[j];
  const float* hrow = hid + (size_t)n * K;
  for (int k = 0; k < K; k++) s += hrow[k] * W[(size_t)k * O + j];
  out[t] = s;
}

// ---------------- host side ----------------
static inline void run_big_gemm(const float* A, const float* W, const float* bias,
                                float* out, int M, int Nc, int K, hipStream_t stream) {
  dim3 grid(Nc / 128, (M + 127) / 128);
  gemm_fused<<<grid, 256, 0, stream>>>(A, W, bias, out, M, Nc, K);
}

static inline void run_gemm_f32(const float* A, const float* W, const float* bias,
                                float* out, int M, int Nc, int K, bool relu,
                                hipStream_t stream) {
  dim3 grid((Nc + BN - 1) / BN, (M + BM - 1) / BM);
  if (relu)
    gemm_bias<true><<<grid, 256, 0, stream>>>(A, W, bias, out, M, Nc, K);
  else
    gemm_bias<false><<<grid, 256, 0, stream>>>(A, W, bias, out, M, Nc, K);
}

extern "C" void kernel_launch(void* const* d_in, const int* in_sizes, int n_in,
                              void* d_out, int out_size, void* d_ws, size_t ws_size,
                              hipStream_t stream) {
  const float* x   = (const float*)d_in[0];
  const int*   ei  = (const int*)d_in[1];
  const float* Wl0 = (const float*)d_in[2];  const float* bl0 = (const float*)d_in[3];
  const float* Wr0 = (const float*)d_in[4];  const float* br0 = (const float*)d_in[5];
  const float* att0= (const float*)d_in[6];  const float* b0  = (const float*)d_in[7];
  const float* Wl1 = (const float*)d_in[8];  const float* bl1 = (const float*)d_in[9];
  const float* Wr1 = (const float*)d_in[10]; const float* br1 = (const float*)d_in[11];
  const float* att1= (const float*)d_in[12]; const float* b1  = (const float*)d_in[13];
  const float* Wl2 = (const float*)d_in[14]; const float* bl2 = (const float*)d_in[15];
  const float* Wr2 = (const float*)d_in[16]; const float* br2 = (const float*)d_in[17];
  const float* att2= (const float*)d_in[18]; const float* b2  = (const float*)d_in[19];
  const float* W_pam1 = (const float*)d_in[20]; const float* b_pam1 = (const float*)d_in[21];
  const float* W_pam2 = (const float*)d_in[22]; const float* b_pam2 = (const float*)d_in[23];
  const float* W_sur1 = (const float*)d_in[24]; const float* b_sur1 = (const float*)d_in[25];
  const float* W_sur2 = (const float*)d_in[26]; const float* b_sur2 = (const float*)d_in[27];

  const int N  = in_sizes[0] / IN_DIM;   // 10000
  const int E  = in_sizes[1] / 2;        // 40000
  const int Et = E + N;

  // ---- workspace layout ----
  const size_t NF = (size_t)N * HC;
  float* bufA   = (float*)d_ws;
  float* bufB   = bufA + NF;
  float* bufC   = bufB + NF;
  float* scores = bufC + NF;                           // Et*HEADS
  float* asort  = scores + (size_t)Et * HEADS;         // Et*HEADS
  unsigned* m_int = (unsigned*)(asort + (size_t)Et * HEADS);  // N*HEADS
  float* denom  = (float*)(m_int + (size_t)N * HEADS); // N*HEADS
  int* cnt      = (int*)(denom + (size_t)N * HEADS);   // N
  int* fill     = cnt + N;                             // N
  int* row_off  = fill + N;                            // N+1
  int* esrc     = row_off + (N + 1);                   // Et
  int* pos_of   = esrc + Et;                           // Et
  // head-stage buffers alias bufA (dead after layer-2 aggregation)
  float* hfin = bufA;                   // N*HID
  float* hid  = bufA + (size_t)N * HID; // N*128

  float* out_pam = (float*)d_out;
  float* out_sur = out_pam + (size_t)N * OUT_DIM;

  dim3 eblk(64, HEADS);
  int alpha_threads = Et * HEADS;

  // ---------- CSR build (graph identical for all layers) ----------
  hipMemsetAsync(cnt, 0, N * 4, stream);
  hipMemsetAsync(fill, 0, N * 4, stream);
  count_dst<<<(Et + 255) / 256, 256, 0, stream>>>(ei, cnt, E, Et);
  scan_offsets<<<1, SCAN_T, 0, stream>>>(cnt, row_off, N);
  scatter_edges<<<(Et + 255) / 256, 256, 0, stream>>>(ei, row_off, fill, esrc, pos_of, E, Et);

  // ---------- layer 0 ----------
  run_big_gemm(x, Wl0, bl0, bufA, N, HC, IN_DIM, stream);
  run_big_gemm(x, Wr0, br0, bufB, N, HC, IN_DIM, stream);
  hipMemsetAsync(m_int, 0, (size_t)N * HEADS * 4, stream);
  hipMemsetAsync(denom, 0, (size_t)N * HEADS * 4, stream);
  edge_scores<<<Et, eblk, 0, stream>>>(bufA, bufB, ei, att0, scores, m_int, E, Et);
  edge_alpha<<<(alpha_threads + 255) / 256, 256, 0, stream>>>(scores, asort, m_int, denom, ei, pos_of, E, Et);
  aggregate_csr<true><<<N, 256, 0, stream>>>(bufA, asort, denom, row_off, esrc, b0, bufC, N);

  // ---------- layer 1 ----------
  run_big_gemm(bufC, Wl1, bl1, bufA, N, HC, HC, stream);
  run_big_gemm(bufC, Wr1, br1, bufB, N, HC, HC, stream);
  hipMemsetAsync(m_int, 0, (size_t)N * HEADS * 4, stream);
  hipMemsetAsync(denom, 0, (size_t)N * HEADS * 4, stream);
  edge_scores<<<Et, eblk, 0, stream>>>(bufA, bufB, ei, att1, scores, m_int, E, Et);
  edge_alpha<<<(alpha_threads + 255) / 256, 256, 0, stream>>>(scores, asort, m_int, denom, ei, pos_of, E, Et);
  aggregate_csr<true><<<N, 256, 0, stream>>>(bufA, asort, denom, row_off, esrc, b1, bufC, N);

  // ---------- layer 2 (mean over heads) ----------
  run_big_gemm(bufC, Wl2, bl2, bufA, N, HC, HC, stream);
  run_big_gemm(bufC, Wr2, br2, bufB, N, HC, HC, stream);
  hipMemsetAsync(m_int, 0, (size_t)N * HEADS * 4, stream);
  hipMemsetAsync(denom, 0, (size_t)N * HEADS * 4, stream);
  edge_scores<<<Et, eblk, 0, stream>>>(bufA, bufB, ei, att2, scores, m_int, E, Et);
  edge_alpha<<<(alpha_threads + 255) / 256, 256, 0, stream>>>(scores, asort, m_int, denom, ei, pos_of, E, Et);
  aggregate_csr<false><<<N, 256, 0, stream>>>(bufA, asort, denom, row_off, esrc, nullptr, bufB, N);
  mean_heads<<<(N * HID + 255) / 256, 256, 0, stream>>>(bufB, b2, hfin, N);

  // ---------- heads (tiny, fp32) ----------
  run_gemm_f32(hfin, W_pam1, b_pam1, hid, N, HID / 2, HID, true, stream);
  head_final<<<(N * OUT_DIM + 255) / 256, 256, 0, stream>>>(hid, W_pam2, b_pam2, out_pam, N, HID / 2, OUT_DIM);
  run_gemm_f32(hfin, W_sur1, b_sur1, hid, N, HID / 2, HID, true, stream);
  head_final<<<(N + 255) / 256, 256, 0, stream>>>(hid, W_sur2, b_sur2, out_sur, N, HID / 2, 1);
}

// Round 6
// 2267.925 us; speedup vs baseline: 5.4555x; 1.0195x over previous
//
#include <hip/hip_runtime.h>
#include <hip/hip_bf16.h>
#include <math.h>

// ---------------- constants of the problem ----------------
#define IN_DIM 512
#define HID 256
#define HEADS 8
#define HC (HEADS * HID)   // 2048
#define OUT_DIM 5
#define NEG_SLOPE 0.2f
#define M_PAD 10112        // 79 * 128

typedef short s16x8 __attribute__((ext_vector_type(8)));
typedef float f32x4 __attribute__((ext_vector_type(4)));

// ---------------- bf16 split helpers (round-to-nearest-even) ----------------
__device__ inline unsigned short bf16_rne(float f) {
  unsigned u = __float_as_uint(f);
  unsigned r = (u + 0x7fffu + ((u >> 16) & 1u)) >> 16;
  return (unsigned short)r;
}
__device__ inline float bf16_to_f(unsigned short h) {
  return __uint_as_float(((unsigned)h) << 16);
}
__device__ inline void split8(const float* f, s16x8& hv, s16x8& lv) {
  s16x8 h, l;
#pragma unroll
  for (int i = 0; i < 8; i++) {
    unsigned short hs = bf16_rne(f[i]);
    h[i] = (short)hs;
    l[i] = (short)bf16_rne(f[i] - bf16_to_f(hs));
  }
  hv = h; lv = l;
}

// ---------------- split fp32 -> (hi, lo) bf16 planes, zero-pad rows ----------------
__global__ void split_pad(const float* __restrict__ X,
                          unsigned short* __restrict__ hi,
                          unsigned short* __restrict__ lo,
                          long nvalid, long ntotal) {
  long i = ((long)blockIdx.x * blockDim.x + threadIdx.x) * 4;
  if (i >= ntotal) return;
  float4 v = (i < nvalid) ? *(const float4*)(X + i) : make_float4(0.f, 0.f, 0.f, 0.f);
  ushort4 h, l;
  h.x = bf16_rne(v.x); l.x = bf16_rne(v.x - bf16_to_f(h.x));
  h.y = bf16_rne(v.y); l.y = bf16_rne(v.y - bf16_to_f(h.y));
  h.z = bf16_rne(v.z); l.z = bf16_rne(v.z - bf16_to_f(h.z));
  h.w = bf16_rne(v.w); l.w = bf16_rne(v.w - bf16_to_f(h.w));
  *(ushort4*)(hi + i) = h;
  *(ushort4*)(lo + i) = l;
}

// ---------------- split-bf16 MFMA GEMM, A from dual bf16 planes ----------------
// C[M][Nc] = (Ahi+Alo)[M][K] @ W[K][Nc] + bias;  W fp32 transposed+split in-kernel.
#define GL16(gp, lp) __builtin_amdgcn_global_load_lds( \
    (const __attribute__((address_space(1))) void*)(gp), \
    (__attribute__((address_space(3))) void*)(lp), 16, 0, 0)

__global__ __launch_bounds__(256, 2) void gemm_planes(
    const unsigned short* __restrict__ Ahi, const unsigned short* __restrict__ Alo,
    const float* __restrict__ W, const float* __restrict__ bias,
    float* __restrict__ C, int M, int Nc, int K) {
  __shared__ __attribute__((aligned(16))) unsigned short ah_s[128 * 32];
  __shared__ __attribute__((aligned(16))) unsigned short al_s[128 * 32];
  __shared__ __attribute__((aligned(16))) unsigned short bh_s[128 * 32];
  __shared__ __attribute__((aligned(16))) unsigned short bl_s[128 * 32];

  const int tid = threadIdx.x;
  const int lane = tid & 63;
  const int w = tid >> 6;
  const int wr = w >> 1, wc = w & 1;

  // XCD-aware bijective swizzle (m204): blocks sharing an A row-panel -> same XCD
  int nwg = gridDim.x * gridDim.y;
  int wgid = blockIdx.y * gridDim.x + blockIdx.x;
  int qq = nwg >> 3, rr = nwg & 7, xcd = wgid & 7, lid = wgid >> 3;
  int nid = (xcd < rr) ? xcd * (qq + 1) + lid
                       : rr * (qq + 1) + (xcd - rr) * qq + lid;
  const int col0 = (nid % gridDim.x) * 128;
  const int row0 = (nid / gridDim.x) * 128;

  // A staging: tile = 128 rows x 32 k-shorts = 8 chunks of 16 rows (1 KiB each).
  // Wave w stages chunks {2w, 2w+1} of BOTH planes (4 GL16/wave, 16 total).
  // chunk c: lane l -> row 16c + l/4, k-elems (l%4)*8..+8; LDS dest = base + lane*16B.
  const int lr = lane >> 2;
  const int lk = (lane & 3) * 8;
  const unsigned short* gAh = Ahi + (size_t)(row0 + lr) * K + lk;
  const unsigned short* gAl = Alo + (size_t)(row0 + lr) * K + lk;

  // B gather: thread covers W cols col0+rc and col0+rc+64 at k-rows k8..k8+7
  const int rc = tid >> 2;
  const int k8 = (tid & 3) * 8;
  const float* gW = W + (size_t)k8 * Nc + col0;

  f32x4 acc[4][4];
#pragma unroll
  for (int i = 0; i < 4; i++)
#pragma unroll
    for (int j = 0; j < 4; j++) acc[i][j] = (f32x4){0.f, 0.f, 0.f, 0.f};

  const int fr = lane & 15;
  const int fq = lane >> 4;

  for (int k0 = 0; k0 < K; k0 += 32) {
    // ---- B gather (issue early; fp32) ----
    float fb0[8], fb1[8];
    const float* p = gW + (size_t)k0 * Nc;
#pragma unroll
    for (int j = 0; j < 8; j++) {
      fb0[j] = p[(size_t)j * Nc + rc];
      fb1[j] = p[(size_t)j * Nc + rc + 64];
    }

    __syncthreads();   // previous iteration's fragment reads complete

    // ---- A planes: direct global->LDS (4 issues/wave, chunks 2w..2w+1) ----
#pragma unroll
    for (int c2 = 0; c2 < 2; c2++) {
      int c = w * 2 + c2;
      GL16(gAh + (size_t)c * 16 * K + k0, &ah_s[c * 512]);
      GL16(gAl + (size_t)c * 16 * K + k0, &al_s[c * 512]);
    }

    // ---- B convert + LDS write (contiguous b128) ----
    s16x8 h, l;
    split8(fb0, h, l);
    *(s16x8*)&bh_s[rc * 32 + k8] = h;  *(s16x8*)&bl_s[rc * 32 + k8] = l;
    split8(fb1, h, l);
    *(s16x8*)&bh_s[(rc + 64) * 32 + k8] = h;  *(s16x8*)&bl_s[(rc + 64) * 32 + k8] = l;

    __syncthreads();   // drains vmcnt (gload_lds) + lgkm; tile published

    // ---- fragment reads + MFMA (3-product split accumulation) ----
    s16x8 ah[4], al[4], bh[4], bl[4];
#pragma unroll
    for (int i = 0; i < 4; i++) {
      int off = (wr * 64 + i * 16 + fr) * 32 + fq * 8;
      ah[i] = *(const s16x8*)&ah_s[off];
      al[i] = *(const s16x8*)&al_s[off];
    }
#pragma unroll
    for (int j = 0; j < 4; j++) {
      int off = (wc * 64 + j * 16 + fr) * 32 + fq * 8;
      bh[j] = *(const s16x8*)&bh_s[off];
      bl[j] = *(const s16x8*)&bl_s[off];
    }
#pragma unroll
    for (int i = 0; i < 4; i++)
#pragma unroll
      for (int j = 0; j < 4; j++) {
        acc[i][j] = __builtin_amdgcn_mfma_f32_16x16x32_bf16(ah[i], bh[j], acc[i][j], 0, 0, 0);
        acc[i][j] = __builtin_amdgcn_mfma_f32_16x16x32_bf16(ah[i], bl[j], acc[i][j], 0, 0, 0);
        acc[i][j] = __builtin_amdgcn_mfma_f32_16x16x32_bf16(al[i], bh[j], acc[i][j], 0, 0, 0);
      }
  }

  // epilogue: C col = lane&15, row = (lane>>4)*4 + reg (per 16x16 frag)
#pragma unroll
  for (int j = 0; j < 4; j++) {
    int col = col0 + wc * 64 + j * 16 + fr;
    float bj = bias[col];
#pragma unroll
    for (int i = 0; i < 4; i++) {
      int rbase = row0 + wr * 64 + i * 16 + fq * 4;
#pragma unroll
      for (int r = 0; r < 4; r++) {
        int row = rbase + r;
        if (row < M) C[(size_t)row * Nc + col] = acc[i][j][r] + bj;
      }
    }
  }
}

// ---------------- fp32 tiled GEMM (small head matmuls only) ----------------
#define BM 64
#define BN 64
#define BK 16

template <bool RELU>
__global__ __launch_bounds__(256) void gemm_bias(
    const float* __restrict__ A, const float* __restrict__ W,
    const float* __restrict__ bias, float* __restrict__ out,
    int M, int Nc, int K) {
  __shared__ float As[BK][BM + 1];
  __shared__ float Bs[BK][BN + 1];
  const int tid = threadIdx.x;
  const int tx = tid & 15;
  const int ty = tid >> 4;
  const int row0 = blockIdx.y * BM;
  const int col0 = blockIdx.x * BN;

  float acc[4][4] = {};

  for (int k0 = 0; k0 < K; k0 += BK) {
#pragma unroll
    for (int i = 0; i < 4; i++) {
      int idx = tid + i * 256;
      int m = idx >> 4;
      int kk = idx & 15;
      int gm = row0 + m;
      As[kk][m] = (gm < M) ? A[(size_t)gm * K + k0 + kk] : 0.f;
    }
#pragma unroll
    for (int i = 0; i < 4; i++) {
      int idx = tid + i * 256;
      int kk = idx >> 6;
      int nn = idx & 63;
      Bs[kk][nn] = W[(size_t)(k0 + kk) * Nc + col0 + nn];
    }
    __syncthreads();
#pragma unroll
    for (int kk = 0; kk < BK; kk++) {
      float a[4], b[4];
#pragma unroll
      for (int i = 0; i < 4; i++) a[i] = As[kk][ty * 4 + i];
#pragma unroll
      for (int j = 0; j < 4; j++) b[j] = Bs[kk][tx * 4 + j];
#pragma unroll
      for (int i = 0; i < 4; i++)
#pragma unroll
        for (int j = 0; j < 4; j++) acc[i][j] += a[i] * b[j];
    }
    __syncthreads();
  }

#pragma unroll
  for (int i = 0; i < 4; i++) {
    int gm = row0 + ty * 4 + i;
    if (gm >= M) continue;
#pragma unroll
    for (int j = 0; j < 4; j++) {
      int gn = col0 + tx * 4 + j;
      float v = acc[i][j] + bias[gn];
      if (RELU) v = fmaxf(v, 0.f);
      out[(size_t)gm * Nc + gn] = v;
    }
  }
}

// ---------------- monotone float<->uint encoding for atomicMax ----------------
__device__ inline unsigned fenc(float f) {
  unsigned u = __float_as_uint(f);
  return (u & 0x80000000u) ? ~u : (u | 0x80000000u);
}
__device__ inline float fdec(unsigned u) {
  return (u & 0x80000000u) ? __uint_as_float(u & 0x7FFFFFFFu)
                           : __uint_as_float(~u);
}

// ---------------- CSR build ----------------
__global__ void count_dst(const int* __restrict__ ei, int* __restrict__ cnt,
                          int E, int Et) {
  int t = blockIdx.x * blockDim.x + threadIdx.x;
  if (t >= Et) return;
  int d = (t < E) ? ei[E + t] : t - E;
  atomicAdd(&cnt[d], 1);
}

#define SCAN_T 1024
__global__ __launch_bounds__(SCAN_T) void scan_offsets(
    const int* __restrict__ cnt, int* __restrict__ row_off, int N) {
  __shared__ int ssum[SCAN_T];
  int t = threadIdx.x;
  int per = (N + SCAN_T - 1) / SCAN_T;
  int beg = t * per, end = min(beg + per, N);
  int s = 0;
  for (int i = beg; i < end; i++) s += cnt[i];
  ssum[t] = s;
  __syncthreads();
  for (int off = 1; off < SCAN_T; off <<= 1) {
    int v = (t >= off) ? ssum[t - off] : 0;
    __syncthreads();
    ssum[t] += v;
    __syncthreads();
  }
  int run = (t == 0) ? 0 : ssum[t - 1];
  for (int i = beg; i < end; i++) { row_off[i] = run; run += cnt[i]; }
  if (t == 0) row_off[N] = ssum[SCAN_T - 1];
}

__global__ void scatter_edges(const int* __restrict__ ei,
                              const int* __restrict__ row_off,
                              int* __restrict__ fill,
                              int* __restrict__ esrc, int* __restrict__ pos_of,
                              int E, int Et) {
  int t = blockIdx.x * blockDim.x + threadIdx.x;
  if (t >= Et) return;
  int s, d;
  if (t < E) { s = ei[t]; d = ei[E + t]; } else { s = t - E; d = s; }
  int pos = row_off[d] + atomicAdd(&fill[d], 1);
  esrc[pos] = s;
  pos_of[t] = pos;
}

// ---------------- edge scores + segment max ----------------
__global__ __launch_bounds__(512) void edge_scores(
    const float* __restrict__ hl, const float* __restrict__ hr,
    const int* __restrict__ ei, const float* __restrict__ att,
    float* __restrict__ scores, unsigned* __restrict__ m_int,
    int E, int Et) {
  int e = blockIdx.x;
  int h = threadIdx.y;
  int lane = threadIdx.x;
  int s, d;
  if (e < E) { s = ei[e]; d = ei[E + e]; } else { s = e - E; d = s; }

  const float4 a4 = ((const float4*)(att + h * HID))[lane];
  const float4 l4 = ((const float4*)(hl + (size_t)s * HC + h * HID))[lane];
  const float4 r4 = ((const float4*)(hr + (size_t)d * HC + h * HID))[lane];

  float sum = 0.f, g;
  g = l4.x + r4.x; g = (g > 0.f) ? g : NEG_SLOPE * g; sum += a4.x * g;
  g = l4.y + r4.y; g = (g > 0.f) ? g : NEG_SLOPE * g; sum += a4.y * g;
  g = l4.z + r4.z; g = (g > 0.f) ? g : NEG_SLOPE * g; sum += a4.z * g;
  g = l4.w + r4.w; g = (g > 0.f) ? g : NEG_SLOPE * g; sum += a4.w * g;

#pragma unroll
  for (int off = 32; off > 0; off >>= 1) sum += __shfl_down(sum, off);

  if (lane == 0) {
    scores[(size_t)e * HEADS + h] = sum;
    atomicMax(&m_int[d * HEADS + h], fenc(sum));
  }
}

// ---------------- alpha = exp(score - m[dst]) -> CSR order; denom += alpha ----------------
__global__ void edge_alpha(const float* __restrict__ scores,
                           float* __restrict__ asort,
                           const unsigned* __restrict__ m_int,
                           float* __restrict__ denom,
                           const int* __restrict__ ei,
                           const int* __restrict__ pos_of, int E, int Et) {
  int t = blockIdx.x * blockDim.x + threadIdx.x;
  if (t >= Et * HEADS) return;
  int e = t >> 3, h = t & 7;
  int d = (e < E) ? ei[E + e] : e - E;
  float m = fdec(m_int[d * HEADS + h]);
  float a = expf(scores[t] - m);
  asort[(size_t)pos_of[e] * HEADS + h] = a;
  atomicAdd(&denom[d * HEADS + h], a);
}

// ---------------- CSR aggregation ----------------
// MODE 0: fp32 out, no bias/elu (layer 2).  MODE 1: bias+ELU, split to bf16 planes.
template <int MODE>
__global__ __launch_bounds__(256) void aggregate_csr(
    const float* __restrict__ hl, const float* __restrict__ asort,
    const float* __restrict__ denom, const int* __restrict__ row_off,
    const int* __restrict__ esrc, const float* __restrict__ bias,
    float* __restrict__ outf, unsigned short* __restrict__ Chi,
    unsigned short* __restrict__ Clo, int N) {
  int n = blockIdx.x;
  int t = threadIdx.x;
  int h = t >> 5;
  int l = t & 31;
  int beg = row_off[n], end = row_off[n + 1];

  f32x4 a0 = {0.f, 0.f, 0.f, 0.f}, a1 = {0.f, 0.f, 0.f, 0.f};
  for (int j = beg; j < end; j++) {
    int src = esrc[j];
    float a = asort[(size_t)j * HEADS + h];
    const f32x4* p = (const f32x4*)(hl + (size_t)src * HC + h * HID + l * 8);
    f32x4 v0 = p[0], v1 = p[1];
    a0 += a * v0;
    a1 += a * v1;
  }
  float dn = 1.f / (denom[n * HEADS + h] + 1e-16f);
  int cbase = h * HID + l * 8;
  if (MODE == 0) {
    float* o = outf + (size_t)n * HC + cbase;
#pragma unroll
    for (int q = 0; q < 4; q++) o[q] = a0[q] * dn;
#pragma unroll
    for (int q = 0; q < 4; q++) o[4 + q] = a1[q] * dn;
  } else {
    float v[8];
#pragma unroll
    for (int q = 0; q < 4; q++) {
      float x = a0[q] * dn + bias[cbase + q];
      v[q] = (x > 0.f) ? x : (expf(x) - 1.f);
    }
#pragma unroll
    for (int q = 0; q < 4; q++) {
      float x = a1[q] * dn + bias[cbase + 4 + q];
      v[4 + q] = (x > 0.f) ? x : (expf(x) - 1.f);
    }
    s16x8 hv, lv;
    split8(v, hv, lv);
    *(s16x8*)&Chi[(size_t)n * HC + cbase] = hv;
    *(s16x8*)&Clo[(size_t)n * HC + cbase] = lv;
  }
}

// ---------------- mean over heads + bias: [N, H*C] -> [N, C] ----------------
__global__ void mean_heads(const float* __restrict__ in,
                           const float* __restrict__ bias,
                           float* __restrict__ out, int N) {
  int t = blockIdx.x * blockDim.x + threadIdx.x;
  if (t >= N * HID) return;
  int n = t >> 8;
  int c = t & 255;
  const float* r = in + (size_t)n * HC + c;
  float s = 0.f;
#pragma unroll
  for (int h = 0; h < HEADS; h++) s += r[h * HID];
  out[t] = 0.125f * s + bias[c];
}

// ---------------- tiny final projection ----------------
__global__ void head_final(const float* __restrict__ hid,
                           const float* __restrict__ W,
                           const float* __restrict__ b,
                           float* __restrict__ out, int N, int K, int O) {
  int t = blockIdx.x * blockDim.x + threadIdx.x;
  if (t >= N * O) return;
  int n = t / O, j = t % O;
  float s = b[j];
  const float* hrow = hid + (size_t)n * K;
  for (int k = 0; k < K; k++) s += hrow[k] * W[(size_t)k * O + j];
  out[t] = s;
}

// ---------------- host side ----------------
static inline void run_big_gemm(const unsigned short* Ahi, const unsigned short* Alo,
                                const float* W, const float* bias,
                                float* out, int M, int Nc, int K, hipStream_t stream) {
  dim3 grid(Nc / 128, (M + 127) / 128);
  gemm_planes<<<grid, 256, 0, stream>>>(Ahi, Alo, W, bias, out, M, Nc, K);
}

static inline void run_gemm_f32(const float* A, const float* W, const float* bias,
                                float* out, int M, int Nc, int K, bool relu,
                                hipStream_t stream) {
  dim3 grid((Nc + BN - 1) / BN, (M + BM - 1) / BM);
  if (relu)
    gemm_bias<true><<<grid, 256, 0, stream>>>(A, W, bias, out, M, Nc, K);
  else
    gemm_bias<false><<<grid, 256, 0, stream>>>(A, W, bias, out, M, Nc, K);
}

extern "C" void kernel_launch(void* const* d_in, const int* in_sizes, int n_in,
                              void* d_out, int out_size, void* d_ws, size_t ws_size,
                              hipStream_t stream) {
  const float* x   = (const float*)d_in[0];
  const int*   ei  = (const int*)d_in[1];
  const float* Wl0 = (const float*)d_in[2];  const float* bl0 = (const float*)d_in[3];
  const float* Wr0 = (const float*)d_in[4];  const float* br0 = (const float*)d_in[5];
  const float* att0= (const float*)d_in[6];  const float* b0  = (const float*)d_in[7];
  const float* Wl1 = (const float*)d_in[8];  const float* bl1 = (const float*)d_in[9];
  const float* Wr1 = (const float*)d_in[10]; const float* br1 = (const float*)d_in[11];
  const float* att1= (const float*)d_in[12]; const float* b1  = (const float*)d_in[13];
  const float* Wl2 = (const float*)d_in[14]; const float* bl2 = (const float*)d_in[15];
  const float* Wr2 = (const float*)d_in[16]; const float* br2 = (const float*)d_in[17];
  const float* att2= (const float*)d_in[18]; const float* b2  = (const float*)d_in[19];
  const float* W_pam1 = (const float*)d_in[20]; const float* b_pam1 = (const float*)d_in[21];
  const float* W_pam2 = (const float*)d_in[22]; const float* b_pam2 = (const float*)d_in[23];
  const float* W_sur1 = (const float*)d_in[24]; const float* b_sur1 = (const float*)d_in[25];
  const float* W_sur2 = (const float*)d_in[26]; const float* b_sur2 = (const float*)d_in[27];

  const int N  = in_sizes[0] / IN_DIM;   // 10000
  const int E  = in_sizes[1] / 2;        // 40000
  const int Et = E + N;

  // ---- workspace layout (~251 MB, under the round-1-proven 263 MB) ----
  const size_t NF = (size_t)N * HC;
  float* bufA = (float*)d_ws;                                    // NF fp32 (hl)
  float* bufB = bufA + NF;                                       // NF fp32 (hr)
  unsigned short* Chi = (unsigned short*)(bufB + NF);            // M_PAD*HC bf16
  unsigned short* Clo = Chi + (size_t)M_PAD * HC;                // M_PAD*HC bf16
  float* scores = (float*)(Clo + (size_t)M_PAD * HC);            // Et*HEADS
  float* asort  = scores + (size_t)Et * HEADS;                   // Et*HEADS
  unsigned* m_int = (unsigned*)(asort + (size_t)Et * HEADS);     // N*HEADS
  float* denom  = (float*)(m_int + (size_t)N * HEADS);           // N*HEADS
  int* cnt      = (int*)(denom + (size_t)N * HEADS);             // N
  int* fill     = cnt + N;                                       // N
  int* row_off  = fill + N;                                      // N+1
  int* esrc     = row_off + (N + 1);                             // Et
  int* pos_of   = esrc + Et;                                     // Et
  // layer-0 x planes alias the (not-yet-written) Chi/Clo region
  unsigned short* Xhi = Chi;
  unsigned short* Xlo = Xhi + (size_t)M_PAD * IN_DIM;
  // head-stage buffers alias bufA (dead after layer-2 aggregation)
  float* hfin = bufA;                   // N*HID
  float* hid  = bufA + (size_t)N * HID; // N*128

  float* out_pam = (float*)d_out;
  float* out_sur = out_pam + (size_t)N * OUT_DIM;

  dim3 eblk(64, HEADS);
  int alpha_threads = Et * HEADS;

  // ---------- CSR build (graph identical for all layers) ----------
  hipMemsetAsync(cnt, 0, N * 4, stream);
  hipMemsetAsync(fill, 0, N * 4, stream);
  count_dst<<<(Et + 255) / 256, 256, 0, stream>>>(ei, cnt, E, Et);
  scan_offsets<<<1, SCAN_T, 0, stream>>>(cnt, row_off, N);
  scatter_edges<<<(Et + 255) / 256, 256, 0, stream>>>(ei, row_off, fill, esrc, pos_of, E, Et);

  // ---------- layer 0 ----------
  {
    long nvalid = (long)N * IN_DIM, ntotal = (long)M_PAD * IN_DIM;
    split_pad<<<(unsigned)((ntotal / 4 + 255) / 256), 256, 0, stream>>>(x, Xhi, Xlo, nvalid, ntotal);
  }
  run_big_gemm(Xhi, Xlo, Wl0, bl0, bufA, N, HC, IN_DIM, stream);
  run_big_gemm(Xhi, Xlo, Wr0, br0, bufB, N, HC, IN_DIM, stream);
  hipMemsetAsync(m_int, 0, (size_t)N * HEADS * 4, stream);
  hipMemsetAsync(denom, 0, (size_t)N * HEADS * 4, stream);
  edge_scores<<<Et, eblk, 0, stream>>>(bufA, bufB, ei, att0, scores, m_int, E, Et);
  edge_alpha<<<(alpha_threads + 255) / 256, 256, 0, stream>>>(scores, asort, m_int, denom, ei, pos_of, E, Et);
  aggregate_csr<1><<<N, 256, 0, stream>>>(bufA, asort, denom, row_off, esrc, b0, nullptr, Chi, Clo, N);

  // ---------- layer 1 ----------
  run_big_gemm(Chi, Clo, Wl1, bl1, bufA, N, HC, HC, stream);
  run_big_gemm(Chi, Clo, Wr1, br1, bufB, N, HC, HC, stream);
  hipMemsetAsync(m_int, 0, (size_t)N * HEADS * 4, stream);
  hipMemsetAsync(denom, 0, (size_t)N * HEADS * 4, stream);
  edge_scores<<<Et, eblk, 0, stream>>>(bufA, bufB, ei, att1, scores, m_int, E, Et);
  edge_alpha<<<(alpha_threads + 255) / 256, 256, 0, stream>>>(scores, asort, m_int, denom, ei, pos_of, E, Et);
  aggregate_csr<1><<<N, 256, 0, stream>>>(bufA, asort, denom, row_off, esrc, b1, nullptr, Chi, Clo, N);

  // ---------- layer 2 (mean over heads) ----------
  run_big_gemm(Chi, Clo, Wl2, bl2, bufA, N, HC, HC, stream);
  run_big_gemm(Chi, Clo, Wr2, br2, bufB, N, HC, HC, stream);
  hipMemsetAsync(m_int, 0, (size_t)N * HEADS * 4, stream);
  hipMemsetAsync(denom, 0, (size_t)N * HEADS * 4, stream);
  edge_scores<<<Et, eblk, 0, stream>>>(bufA, bufB, ei, att2, scores, m_int, E, Et);
  edge_alpha<<<(alpha_threads + 255) / 256, 256, 0, stream>>>(scores, asort, m_int, denom, ei, pos_of, E, Et);
  aggregate_csr<0><<<N, 256, 0, stream>>>(bufA, asort, denom, row_off, esrc, nullptr, bufB, nullptr, nullptr, N);
  mean_heads<<<(N * HID + 255) / 256, 256, 0, stream>>>(bufB, b2, hfin, N);

  // ---------- heads (tiny, fp32) ----------
  run_gemm_f32(hfin, W_pam1, b_pam1, hid, N, HID / 2, HID, true, stream);
  head_final<<<(N * OUT_DIM + 255) / 256, 256, 0, stream>>>(hid, W_pam2, b_pam2, out_pam, N, HID / 2, OUT_DIM);
  run_gemm_f32(hfin, W_sur1, b_sur1, hid, N, HID / 2, HID, true, stream);
  head_final<<<(N + 255) / 256, 256, 0, stream>>>(hid, W_sur2, b_sur2, out_sur, N, HID / 2, 1);
}

// Round 7
// 1999.131 us; speedup vs baseline: 6.1891x; 1.1345x over previous
//
#include <hip/hip_runtime.h>
#include <hip/hip_bf16.h>
#include <math.h>

// ---------------- constants of the problem ----------------
#define IN_DIM 512
#define HID 256
#define HEADS 8
#define HC (HEADS * HID)   // 2048
#define OUT_DIM 5
#define NEG_SLOPE 0.2f

typedef short s16x8 __attribute__((ext_vector_type(8)));
typedef float f32x4 __attribute__((ext_vector_type(4)));

// ---------------- bf16 split helpers (round-to-nearest-even) ----------------
__device__ inline unsigned short bf16_rne(float f) {
  unsigned u = __float_as_uint(f);
  unsigned r = (u + 0x7fffu + ((u >> 16) & 1u)) >> 16;
  return (unsigned short)r;
}
__device__ inline float bf16_to_f(unsigned short h) {
  return __uint_as_float(((unsigned)h) << 16);
}
__device__ inline void split8(const float* f, s16x8& hv, s16x8& lv) {
  s16x8 h, l;
#pragma unroll
  for (int i = 0; i < 8; i++) {
    unsigned short hs = bf16_rne(f[i]);
    h[i] = (short)hs;
    l[i] = (short)bf16_rne(f[i] - bf16_to_f(hs));
  }
  hv = h; lv = l;
}

// ---------------- split fp32 -> (hi, lo) bf16 planes ----------------
__global__ void split_pad(const float* __restrict__ X,
                          unsigned short* __restrict__ hi,
                          unsigned short* __restrict__ lo, long ntotal) {
  long i = ((long)blockIdx.x * blockDim.x + threadIdx.x) * 4;
  if (i >= ntotal) return;
  float4 v = *(const float4*)(X + i);
  ushort4 h, l;
  h.x = bf16_rne(v.x); l.x = bf16_rne(v.x - bf16_to_f(h.x));
  h.y = bf16_rne(v.y); l.y = bf16_rne(v.y - bf16_to_f(h.y));
  h.z = bf16_rne(v.z); l.z = bf16_rne(v.z - bf16_to_f(h.z));
  h.w = bf16_rne(v.w); l.w = bf16_rne(v.w - bf16_to_f(h.w));
  *(ushort4*)(hi + i) = h;
  *(ushort4*)(lo + i) = l;
}

// ---------------- transpose + split weights: W[K][N] -> Wt hi/lo [N][K] ----------------
__global__ __launch_bounds__(256) void wsplit_t(
    const float* __restrict__ W, unsigned short* __restrict__ thi,
    unsigned short* __restrict__ tlo, int K, int N) {
  __shared__ float tile[32][33];
  int tx = threadIdx.x & 31, ty = threadIdx.x >> 5;  // ty 0..7
  int n0 = blockIdx.x * 32, k0 = blockIdx.y * 32;
#pragma unroll
  for (int r = 0; r < 4; r++) {
    int k = k0 + ty + r * 8;
    tile[ty + r * 8][tx] = W[(size_t)k * N + n0 + tx];
  }
  __syncthreads();
#pragma unroll
  for (int r = 0; r < 4; r++) {
    int n = n0 + ty + r * 8;
    float v = tile[tx][ty + r * 8];
    unsigned short h = bf16_rne(v);
    thi[(size_t)n * K + k0 + tx] = h;
    tlo[(size_t)n * K + k0 + tx] = bf16_rne(v - bf16_to_f(h));
  }
}

// ---------------- split-bf16 MFMA GEMM, BOTH sides from pre-split planes ----------------
// C[M][Nc] = (Ahi+Alo)[M][K] @ (Bhi+Blo)^T[Nc][K] + bias   (3-product accumulation)
#define GL16(gp, lp) __builtin_amdgcn_global_load_lds( \
    (const __attribute__((address_space(1))) void*)(gp), \
    (__attribute__((address_space(3))) void*)(lp), 16, 0, 0)

__global__ __launch_bounds__(256, 3) void gemm_planes2(
    const unsigned short* __restrict__ Ahi, const unsigned short* __restrict__ Alo,
    const unsigned short* __restrict__ Bhi, const unsigned short* __restrict__ Blo,
    const float* __restrict__ bias, float* __restrict__ C,
    int M, int Nc, int K) {
  __shared__ __attribute__((aligned(16))) unsigned short ah_s[128 * 32];
  __shared__ __attribute__((aligned(16))) unsigned short al_s[128 * 32];
  __shared__ __attribute__((aligned(16))) unsigned short bh_s[128 * 32];
  __shared__ __attribute__((aligned(16))) unsigned short bl_s[128 * 32];

  const int tid = threadIdx.x;
  const int lane = tid & 63;
  const int w = tid >> 6;
  const int wr = w >> 1, wc = w & 1;

  // XCD-aware bijective swizzle (m204)
  int nwg = gridDim.x * gridDim.y;
  int wgid = blockIdx.y * gridDim.x + blockIdx.x;
  int qq = nwg >> 3, rr = nwg & 7, xcd = wgid & 7, lid = wgid >> 3;
  int nid = (xcd < rr) ? xcd * (qq + 1) + lid
                       : rr * (qq + 1) + (xcd - rr) * qq + lid;
  const int col0 = (nid % gridDim.x) * 128;
  const int row0 = (nid / gridDim.x) * 128;

  // staging: tile [128 rows][32 k] per plane = 8 chunks of 16 rows (1 KiB).
  // Wave w stages chunks {2w, 2w+1} of all 4 planes (8 GL16/wave).
  // chunk c: lane l -> row 16c + l/4, k-elems (l%4)*8..+8; LDS dest = base + c*1KiB + lane*16B.
  const int lr = lane >> 2;
  const int lk = (lane & 3) * 8;
  const unsigned short* gAh = Ahi + (size_t)(row0 + lr) * K + lk;
  const unsigned short* gAl = Alo + (size_t)(row0 + lr) * K + lk;
  const unsigned short* gBh = Bhi + (size_t)(col0 + lr) * K + lk;
  const unsigned short* gBl = Blo + (size_t)(col0 + lr) * K + lk;

  f32x4 acc[4][4];
#pragma unroll
  for (int i = 0; i < 4; i++)
#pragma unroll
    for (int j = 0; j < 4; j++) acc[i][j] = (f32x4){0.f, 0.f, 0.f, 0.f};

  const int fr = lane & 15;
  const int fq = lane >> 4;

  for (int k0 = 0; k0 < K; k0 += 32) {
    __syncthreads();   // previous iteration's fragment reads complete
#pragma unroll
    for (int c2 = 0; c2 < 2; c2++) {
      int c = w * 2 + c2;
      size_t roff = (size_t)c * 16 * K + k0;
      GL16(gAh + roff, &ah_s[c * 512]);
      GL16(gAl + roff, &al_s[c * 512]);
      GL16(gBh + roff, &bh_s[c * 512]);
      GL16(gBl + roff, &bl_s[c * 512]);
    }
    __syncthreads();   // vmcnt(0) drain -> tile published

    s16x8 ah[4], al[4], bh[4], bl[4];
#pragma unroll
    for (int i = 0; i < 4; i++) {
      int off = (wr * 64 + i * 16 + fr) * 32 + fq * 8;
      ah[i] = *(const s16x8*)&ah_s[off];
      al[i] = *(const s16x8*)&al_s[off];
    }
#pragma unroll
    for (int j = 0; j < 4; j++) {
      int off = (wc * 64 + j * 16 + fr) * 32 + fq * 8;
      bh[j] = *(const s16x8*)&bh_s[off];
      bl[j] = *(const s16x8*)&bl_s[off];
    }
#pragma unroll
    for (int i = 0; i < 4; i++)
#pragma unroll
      for (int j = 0; j < 4; j++) {
        acc[i][j] = __builtin_amdgcn_mfma_f32_16x16x32_bf16(ah[i], bh[j], acc[i][j], 0, 0, 0);
        acc[i][j] = __builtin_amdgcn_mfma_f32_16x16x32_bf16(ah[i], bl[j], acc[i][j], 0, 0, 0);
        acc[i][j] = __builtin_amdgcn_mfma_f32_16x16x32_bf16(al[i], bh[j], acc[i][j], 0, 0, 0);
      }
  }

  // epilogue: C col = lane&15, row = (lane>>4)*4 + reg (per 16x16 frag)
#pragma unroll
  for (int j = 0; j < 4; j++) {
    int col = col0 + wc * 64 + j * 16 + fr;
    float bj = bias[col];
#pragma unroll
    for (int i = 0; i < 4; i++) {
      int rbase = row0 + wr * 64 + i * 16 + fq * 4;
#pragma unroll
      for (int r = 0; r < 4; r++) {
        int row = rbase + r;
        if (row < M) C[(size_t)row * Nc + col] = acc[i][j][r] + bj;
      }
    }
  }
}

// ---------------- fp32 tiled GEMM (small head matmuls only) ----------------
#define BM 64
#define BN 64
#define BK 16

template <bool RELU>
__global__ __launch_bounds__(256) void gemm_bias(
    const float* __restrict__ A, const float* __restrict__ W,
    const float* __restrict__ bias, float* __restrict__ out,
    int M, int Nc, int K) {
  __shared__ float As[BK][BM + 1];
  __shared__ float Bs[BK][BN + 1];
  const int tid = threadIdx.x;
  const int tx = tid & 15;
  const int ty = tid >> 4;
  const int row0 = blockIdx.y * BM;
  const int col0 = blockIdx.x * BN;

  float acc[4][4] = {};

  for (int k0 = 0; k0 < K; k0 += BK) {
#pragma unroll
    for (int i = 0; i < 4; i++) {
      int idx = tid + i * 256;
      int m = idx >> 4;
      int kk = idx & 15;
      int gm = row0 + m;
      As[kk][m] = (gm < M) ? A[(size_t)gm * K + k0 + kk] : 0.f;
    }
#pragma unroll
    for (int i = 0; i < 4; i++) {
      int idx = tid + i * 256;
      int kk = idx >> 6;
      int nn = idx & 63;
      Bs[kk][nn] = W[(size_t)(k0 + kk) * Nc + col0 + nn];
    }
    __syncthreads();
#pragma unroll
    for (int kk = 0; kk < BK; kk++) {
      float a[4], b[4];
#pragma unroll
      for (int i = 0; i < 4; i++) a[i] = As[kk][ty * 4 + i];
#pragma unroll
      for (int j = 0; j < 4; j++) b[j] = Bs[kk][tx * 4 + j];
#pragma unroll
      for (int i = 0; i < 4; i++)
#pragma unroll
        for (int j = 0; j < 4; j++) acc[i][j] += a[i] * b[j];
    }
    __syncthreads();
  }

#pragma unroll
  for (int i = 0; i < 4; i++) {
    int gm = row0 + ty * 4 + i;
    if (gm >= M) continue;
#pragma unroll
    for (int j = 0; j < 4; j++) {
      int gn = col0 + tx * 4 + j;
      float v = acc[i][j] + bias[gn];
      if (RELU) v = fmaxf(v, 0.f);
      out[(size_t)gm * Nc + gn] = v;
    }
  }
}

// ---------------- monotone float<->uint encoding for atomicMax ----------------
__device__ inline unsigned fenc(float f) {
  unsigned u = __float_as_uint(f);
  return (u & 0x80000000u) ? ~u : (u | 0x80000000u);
}
__device__ inline float fdec(unsigned u) {
  return (u & 0x80000000u) ? __uint_as_float(u & 0x7FFFFFFFu)
                           : __uint_as_float(~u);
}

// ---------------- CSR build ----------------
__global__ void count_dst(const int* __restrict__ ei, int* __restrict__ cnt,
                          int E, int Et) {
  int t = blockIdx.x * blockDim.x + threadIdx.x;
  if (t >= Et) return;
  int d = (t < E) ? ei[E + t] : t - E;
  atomicAdd(&cnt[d], 1);
}

#define SCAN_T 1024
__global__ __launch_bounds__(SCAN_T) void scan_offsets(
    const int* __restrict__ cnt, int* __restrict__ row_off, int N) {
  __shared__ int ssum[SCAN_T];
  int t = threadIdx.x;
  int per = (N + SCAN_T - 1) / SCAN_T;
  int beg = t * per, end = min(beg + per, N);
  int s = 0;
  for (int i = beg; i < end; i++) s += cnt[i];
  ssum[t] = s;
  __syncthreads();
  for (int off = 1; off < SCAN_T; off <<= 1) {
    int v = (t >= off) ? ssum[t - off] : 0;
    __syncthreads();
    ssum[t] += v;
    __syncthreads();
  }
  int run = (t == 0) ? 0 : ssum[t - 1];
  for (int i = beg; i < end; i++) { row_off[i] = run; run += cnt[i]; }
  if (t == 0) row_off[N] = ssum[SCAN_T - 1];
}

__global__ void scatter_edges(const int* __restrict__ ei,
                              const int* __restrict__ row_off,
                              int* __restrict__ fill,
                              int* __restrict__ esrc, int* __restrict__ edst,
                              int E, int Et) {
  int t = blockIdx.x * blockDim.x + threadIdx.x;
  if (t >= Et) return;
  int s, d;
  if (t < E) { s = ei[t]; d = ei[E + t]; } else { s = t - E; d = s; }
  int pos = row_off[d] + atomicAdd(&fill[d], 1);
  esrc[pos] = s;
  edst[pos] = d;
}

// ---------------- edge scores (CSR-slot indexed) + segment max ----------------
__global__ __launch_bounds__(512) void edge_scores(
    const float* __restrict__ hl, const float* __restrict__ hr,
    const int* __restrict__ esrc, const int* __restrict__ edst,
    const float* __restrict__ att, float* __restrict__ scores,
    unsigned* __restrict__ m_int, int Et) {
  int j = blockIdx.x;
  int h = threadIdx.y;
  int lane = threadIdx.x;
  int s = esrc[j], d = edst[j];

  const float4 a4 = ((const float4*)(att + h * HID))[lane];
  const float4 l4 = ((const float4*)(hl + (size_t)s * HC + h * HID))[lane];
  const float4 r4 = ((const float4*)(hr + (size_t)d * HC + h * HID))[lane];

  float sum = 0.f, g;
  g = l4.x + r4.x; g = (g > 0.f) ? g : NEG_SLOPE * g; sum += a4.x * g;
  g = l4.y + r4.y; g = (g > 0.f) ? g : NEG_SLOPE * g; sum += a4.y * g;
  g = l4.z + r4.z; g = (g > 0.f) ? g : NEG_SLOPE * g; sum += a4.z * g;
  g = l4.w + r4.w; g = (g > 0.f) ? g : NEG_SLOPE * g; sum += a4.w * g;

#pragma unroll
  for (int off = 32; off > 0; off >>= 1) sum += __shfl_down(sum, off);

  if (lane == 0) {
    scores[(size_t)j * HEADS + h] = sum;
    atomicMax(&m_int[d * HEADS + h], fenc(sum));
  }
}

// ---------------- alpha = exp(score - m[dst]) in place; denom += alpha ----------------
__global__ void edge_alpha(float* __restrict__ scores,
                           const unsigned* __restrict__ m_int,
                           float* __restrict__ denom,
                           const int* __restrict__ edst, int Et) {
  int t = blockIdx.x * blockDim.x + threadIdx.x;
  if (t >= Et * HEADS) return;
  int j = t >> 3, h = t & 7;
  int d = edst[j];
  float m = fdec(m_int[d * HEADS + h]);
  float a = expf(scores[t] - m);
  scores[t] = a;
  atomicAdd(&denom[d * HEADS + h], a);
}

// ---------------- CSR aggregation ----------------
// MODE 0: fp32 out (layer 2).  MODE 1: bias+ELU, split to bf16 planes.
template <int MODE>
__global__ __launch_bounds__(256) void aggregate_csr(
    const float* __restrict__ hl, const float* __restrict__ alpha,
    const float* __restrict__ denom, const int* __restrict__ row_off,
    const int* __restrict__ esrc, const float* __restrict__ bias,
    float* __restrict__ outf, unsigned short* __restrict__ Chi,
    unsigned short* __restrict__ Clo, int N) {
  int n = blockIdx.x;
  int t = threadIdx.x;
  int h = t >> 5;
  int l = t & 31;
  int beg = row_off[n], end = row_off[n + 1];

  f32x4 a0 = {0.f, 0.f, 0.f, 0.f}, a1 = {0.f, 0.f, 0.f, 0.f};
  for (int j = beg; j < end; j++) {
    int src = esrc[j];
    float a = alpha[(size_t)j * HEADS + h];
    const f32x4* p = (const f32x4*)(hl + (size_t)src * HC + h * HID + l * 8);
    f32x4 v0 = p[0], v1 = p[1];
    a0 += a * v0;
    a1 += a * v1;
  }
  float dn = 1.f / (denom[n * HEADS + h] + 1e-16f);
  int cbase = h * HID + l * 8;
  if (MODE == 0) {
    float* o = outf + (size_t)n * HC + cbase;
#pragma unroll
    for (int q = 0; q < 4; q++) o[q] = a0[q] * dn;
#pragma unroll
    for (int q = 0; q < 4; q++) o[4 + q] = a1[q] * dn;
  } else {
    float v[8];
#pragma unroll
    for (int q = 0; q < 4; q++) {
      float x = a0[q] * dn + bias[cbase + q];
      v[q] = (x > 0.f) ? x : (expf(x) - 1.f);
    }
#pragma unroll
    for (int q = 0; q < 4; q++) {
      float x = a1[q] * dn + bias[cbase + 4 + q];
      v[4 + q] = (x > 0.f) ? x : (expf(x) - 1.f);
    }
    s16x8 hv, lv;
    split8(v, hv, lv);
    *(s16x8*)&Chi[(size_t)n * HC + cbase] = hv;
    *(s16x8*)&Clo[(size_t)n * HC + cbase] = lv;
  }
}

// ---------------- mean over heads + bias: [N, H*C] -> [N, C] ----------------
__global__ void mean_heads(const float* __restrict__ in,
                           const float* __restrict__ bias,
                           float* __restrict__ out, int N) {
  int t = blockIdx.x * blockDim.x + threadIdx.x;
  if (t >= N * HID) return;
  int n = t >> 8;
  int c = t & 255;
  const float* r = in + (size_t)n * HC + c;
  float s = 0.f;
#pragma unroll
  for (int h = 0; h < HEADS; h++) s += r[h * HID];
  out[t] = 0.125f * s + bias[c];
}

// ---------------- tiny final projection ----------------
__global__ void head_final(const float* __restrict__ hid,
                           const float* __restrict__ W,
                           const float* __restrict__ b,
                           float* __restrict__ out, int N, int K, int O) {
  int t = blockIdx.x * blockDim.x + threadIdx.x;
  if (t >= N * O) return;
  int n = t / O, j = t % O;
  float s = b[j];
  const float* hrow = hid + (size_t)n * K;
  for (int k = 0; k < K; k++) s += hrow[k] * W[(size_t)k * O + j];
  out[t] = s;
}

// ---------------- host side ----------------
static inline void run_big_gemm(const unsigned short* Ahi, const unsigned short* Alo,
                                const float* W, unsigned short* Wthi, unsigned short* Wtlo,
                                const float* bias, float* out, int M, int Nc, int K,
                                hipStream_t stream) {
  dim3 tg(Nc / 32, K / 32);
  wsplit_t<<<tg, 256, 0, stream>>>(W, Wthi, Wtlo, K, Nc);
  dim3 grid(Nc / 128, (M + 127) / 128);
  gemm_planes2<<<grid, 256, 0, stream>>>(Ahi, Alo, Wthi, Wtlo, bias, out, M, Nc, K);
}

static inline void run_gemm_f32(const float* A, const float* W, const float* bias,
                                float* out, int M, int Nc, int K, bool relu,
                                hipStream_t stream) {
  dim3 grid((Nc + BN - 1) / BN, (M + BM - 1) / BM);
  if (relu)
    gemm_bias<true><<<grid, 256, 0, stream>>>(A, W, bias, out, M, Nc, K);
  else
    gemm_bias<false><<<grid, 256, 0, stream>>>(A, W, bias, out, M, Nc, K);
}

extern "C" void kernel_launch(void* const* d_in, const int* in_sizes, int n_in,
                              void* d_out, int out_size, void* d_ws, size_t ws_size,
                              hipStream_t stream) {
  const float* x   = (const float*)d_in[0];
  const int*   ei  = (const int*)d_in[1];
  const float* Wl0 = (const float*)d_in[2];  const float* bl0 = (const float*)d_in[3];
  const float* Wr0 = (const float*)d_in[4];  const float* br0 = (const float*)d_in[5];
  const float* att0= (const float*)d_in[6];  const float* b0  = (const float*)d_in[7];
  const float* Wl1 = (const float*)d_in[8];  const float* bl1 = (const float*)d_in[9];
  const float* Wr1 = (const float*)d_in[10]; const float* br1 = (const float*)d_in[11];
  const float* att1= (const float*)d_in[12]; const float* b1  = (const float*)d_in[13];
  const float* Wl2 = (const float*)d_in[14]; const float* bl2 = (const float*)d_in[15];
  const float* Wr2 = (const float*)d_in[16]; const float* br2 = (const float*)d_in[17];
  const float* att2= (const float*)d_in[18]; const float* b2  = (const float*)d_in[19];
  const float* W_pam1 = (const float*)d_in[20]; const float* b_pam1 = (const float*)d_in[21];
  const float* W_pam2 = (const float*)d_in[22]; const float* b_pam2 = (const float*)d_in[23];
  const float* W_sur1 = (const float*)d_in[24]; const float* b_sur1 = (const float*)d_in[25];
  const float* W_sur2 = (const float*)d_in[26]; const float* b_sur2 = (const float*)d_in[27];

  const int N  = in_sizes[0] / IN_DIM;   // 10000
  const int E  = in_sizes[1] / 2;        // 40000
  const int Et = E + N;

  // ---- workspace layout (~263.0 MB; proven <= 263.4 round-1 footprint) ----
  char* p = (char*)d_ws;
  const size_t NF = (size_t)N * HC;
  float* bufA = (float*)p;                 p += NF * 4;               // hl (fp32)
  float* bufB = (float*)p;                 p += NF * 4;               // hr (fp32)
  unsigned short* Chi = (unsigned short*)p; p += NF * 2;              // A hi plane
  unsigned short* Clo = (unsigned short*)p; p += NF * 2;              // A lo plane
  // Wt region (16.78 MB). Edge scratch ALIASES its head: live only between
  // GEMM2 and the next wsplit_t (disjoint in time from Wt use).
  unsigned short* Wthi = (unsigned short*)p;
  unsigned short* Wtlo = Wthi + (size_t)HC * HC;
  float* scores  = (float*)p;                                   // Et*HEADS
  unsigned* m_int = (unsigned*)(scores + (size_t)Et * HEADS);   // N*HEADS
  float* denom   = (float*)(m_int + (size_t)N * HEADS);         // N*HEADS
  int* cnt       = (int*)(denom + (size_t)N * HEADS);           // N
  int* fill      = cnt + N;                                     // N
  p += (size_t)HC * HC * 2 * 2;
  int* row_off = (int*)p;                  p += (size_t)(N + 1) * 4;  // persistent CSR
  int* esrc    = (int*)p;                  p += (size_t)Et * 4;
  int* edst    = (int*)p;                  p += (size_t)Et * 4;
  // layer-0 x planes alias Chi/Clo region (N x IN_DIM each)
  unsigned short* Xhi = Chi;
  unsigned short* Xlo = Xhi + (size_t)N * IN_DIM;
  // head-stage buffers alias bufA (dead after layer-2 aggregation)
  float* hfin = bufA;                   // N*HID
  float* hid  = bufA + (size_t)N * HID; // N*128

  float* out_pam = (float*)d_out;
  float* out_sur = out_pam + (size_t)N * OUT_DIM;

  dim3 eblk(64, HEADS);
  int alpha_threads = Et * HEADS;

  // ---------- CSR build (graph identical for all layers; before any wsplit_t) ----------
  hipMemsetAsync(cnt, 0, N * 4, stream);
  hipMemsetAsync(fill, 0, N * 4, stream);
  count_dst<<<(Et + 255) / 256, 256, 0, stream>>>(ei, cnt, E, Et);
  scan_offsets<<<1, SCAN_T, 0, stream>>>(cnt, row_off, N);
  scatter_edges<<<(Et + 255) / 256, 256, 0, stream>>>(ei, row_off, fill, esrc, edst, E, Et);

  // ---------- layer 0 ----------
  split_pad<<<(unsigned)(((long)N * IN_DIM / 4 + 255) / 256), 256, 0, stream>>>(
      x, Xhi, Xlo, (long)N * IN_DIM);
  run_big_gemm(Xhi, Xlo, Wl0, Wthi, Wtlo, bl0, bufA, N, HC, IN_DIM, stream);
  run_big_gemm(Xhi, Xlo, Wr0, Wthi, Wtlo, br0, bufB, N, HC, IN_DIM, stream);
  hipMemsetAsync(m_int, 0, (size_t)N * HEADS * 4, stream);
  hipMemsetAsync(denom, 0, (size_t)N * HEADS * 4, stream);
  edge_scores<<<Et, eblk, 0, stream>>>(bufA, bufB, esrc, edst, att0, scores, m_int, Et);
  edge_alpha<<<(alpha_threads + 255) / 256, 256, 0, stream>>>(scores, m_int, denom, edst, Et);
  aggregate_csr<1><<<N, 256, 0, stream>>>(bufA, scores, denom, row_off, esrc, b0, nullptr, Chi, Clo, N);

  // ---------- layer 1 ----------
  run_big_gemm(Chi, Clo, Wl1, Wthi, Wtlo, bl1, bufA, N, HC, HC, stream);
  run_big_gemm(Chi, Clo, Wr1, Wthi, Wtlo, br1, bufB, N, HC, HC, stream);
  hipMemsetAsync(m_int, 0, (size_t)N * HEADS * 4, stream);
  hipMemsetAsync(denom, 0, (size_t)N * HEADS * 4, stream);
  edge_scores<<<Et, eblk, 0, stream>>>(bufA, bufB, esrc, edst, att1, scores, m_int, Et);
  edge_alpha<<<(alpha_threads + 255) / 256, 256, 0, stream>>>(scores, m_int, denom, edst, Et);
  aggregate_csr<1><<<N, 256, 0, stream>>>(bufA, scores, denom, row_off, esrc, b1, nullptr, Chi, Clo, N);

  // ---------- layer 2 (mean over heads) ----------
  run_big_gemm(Chi, Clo, Wl2, Wthi, Wtlo, bl2, bufA, N, HC, HC, stream);
  run_big_gemm(Chi, Clo, Wr2, Wthi, Wtlo, br2, bufB, N, HC, HC, stream);
  hipMemsetAsync(m_int, 0, (size_t)N * HEADS * 4, stream);
  hipMemsetAsync(denom, 0, (size_t)N * HEADS * 4, stream);
  edge_scores<<<Et, eblk, 0, stream>>>(bufA, bufB, esrc, edst, att2, scores, m_int, Et);
  edge_alpha<<<(alpha_threads + 255) / 256, 256, 0, stream>>>(scores, m_int, denom, edst, Et);
  aggregate_csr<0><<<N, 256, 0, stream>>>(bufA, scores, denom, row_off, esrc, nullptr, bufB, nullptr, nullptr, N);
  mean_heads<<<(N * HID + 255) / 256, 256, 0, stream>>>(bufB, b2, hfin, N);

  // ---------- heads (tiny, fp32) ----------
  run_gemm_f32(hfin, W_pam1, b_pam1, hid, N, HID / 2, HID, true, stream);
  head_final<<<(N * OUT_DIM + 255) / 256, 256, 0, stream>>>(hid, W_pam2, b_pam2, out_pam, N, HID / 2, OUT_DIM);
  run_gemm_f32(hfin, W_sur1, b_sur1, hid, N, HID / 2, HID, true, stream);
  head_final<<<(N + 255) / 256, 256, 0, stream>>>(hid, W_sur2, b_sur2, out_sur, N, HID / 2, 1);
}

// Round 8
// 1737.150 us; speedup vs baseline: 7.1224x; 1.1508x over previous
//
#include <hip/hip_runtime.h>
#include <hip/hip_bf16.h>
#include <math.h>

// ---------------- constants of the problem ----------------
#define IN_DIM 512
#define HID 256
#define HEADS 8
#define HC (HEADS * HID)   // 2048
#define OUT_DIM 5
#define NEG_SLOPE 0.2f

typedef short s16x8 __attribute__((ext_vector_type(8)));
typedef float f32x4 __attribute__((ext_vector_type(4)));

// ---------------- bf16 split helpers (round-to-nearest-even) ----------------
__device__ inline unsigned short bf16_rne(float f) {
  unsigned u = __float_as_uint(f);
  unsigned r = (u + 0x7fffu + ((u >> 16) & 1u)) >> 16;
  return (unsigned short)r;
}
__device__ inline float bf16_to_f(unsigned short h) {
  return __uint_as_float(((unsigned)h) << 16);
}
__device__ inline void split8(const float* f, s16x8& hv, s16x8& lv) {
  s16x8 h, l;
#pragma unroll
  for (int i = 0; i < 8; i++) {
    unsigned short hs = bf16_rne(f[i]);
    h[i] = (short)hs;
    l[i] = (short)bf16_rne(f[i] - bf16_to_f(hs));
  }
  hv = h; lv = l;
}

// ---------------- split fp32 -> (hi, lo) bf16 planes ----------------
__global__ void split_pad(const float* __restrict__ X,
                          unsigned short* __restrict__ hi,
                          unsigned short* __restrict__ lo, long ntotal) {
  long i = ((long)blockIdx.x * blockDim.x + threadIdx.x) * 4;
  if (i >= ntotal) return;
  float4 v = *(const float4*)(X + i);
  ushort4 h, l;
  h.x = bf16_rne(v.x); l.x = bf16_rne(v.x - bf16_to_f(h.x));
  h.y = bf16_rne(v.y); l.y = bf16_rne(v.y - bf16_to_f(h.y));
  h.z = bf16_rne(v.z); l.z = bf16_rne(v.z - bf16_to_f(h.z));
  h.w = bf16_rne(v.w); l.w = bf16_rne(v.w - bf16_to_f(h.w));
  *(ushort4*)(hi + i) = h;
  *(ushort4*)(lo + i) = l;
}

// ---------------- transpose + split weights: W[K][N] -> Wt hi/lo [N][K] ----------------
__global__ __launch_bounds__(256) void wsplit_t(
    const float* __restrict__ W, unsigned short* __restrict__ thi,
    unsigned short* __restrict__ tlo, int K, int N) {
  __shared__ float tile[32][33];
  int tx = threadIdx.x & 31, ty = threadIdx.x >> 5;  // ty 0..7
  int n0 = blockIdx.x * 32, k0 = blockIdx.y * 32;
#pragma unroll
  for (int r = 0; r < 4; r++) {
    int k = k0 + ty + r * 8;
    tile[ty + r * 8][tx] = W[(size_t)k * N + n0 + tx];
  }
  __syncthreads();
#pragma unroll
  for (int r = 0; r < 4; r++) {
    int n = n0 + ty + r * 8;
    float v = tile[tx][ty + r * 8];
    unsigned short h = bf16_rne(v);
    thi[(size_t)n * K + k0 + tx] = h;
    tlo[(size_t)n * K + k0 + tx] = bf16_rne(v - bf16_to_f(h));
  }
}

// ---------------- split-bf16 MFMA GEMM, both sides pre-split planes, T2 swizzle ----------------
// C[M][Nc] = (Ahi+Alo)[M][K] @ (Bhi+Blo)^T[Nc][K] + bias   (3-product accumulation)
// LDS layout per plane: [128 rows][4 slots of 16B]; LDS (r,s) holds global (r, s ^ ((r>>1)&3)).
// Write side: linear GL16 dest + pre-swizzled per-lane GLOBAL k-slot (rule #21 / m173).
// Read side: slot = fq ^ ((fr>>1)&3) -> 8-way bank conflict becomes 2-way (free, m136).
#define GL16(gp, lp) __builtin_amdgcn_global_load_lds( \
    (const __attribute__((address_space(1))) void*)(gp), \
    (__attribute__((address_space(3))) void*)(lp), 16, 0, 0)

__global__ __launch_bounds__(256, 3) void gemm_planes2(
    const unsigned short* __restrict__ Ahi, const unsigned short* __restrict__ Alo,
    const unsigned short* __restrict__ Bhi, const unsigned short* __restrict__ Blo,
    const float* __restrict__ bias, float* __restrict__ C,
    int M, int Nc, int K) {
  __shared__ __attribute__((aligned(16))) unsigned short ah_s[128 * 32];
  __shared__ __attribute__((aligned(16))) unsigned short al_s[128 * 32];
  __shared__ __attribute__((aligned(16))) unsigned short bh_s[128 * 32];
  __shared__ __attribute__((aligned(16))) unsigned short bl_s[128 * 32];

  const int tid = threadIdx.x;
  const int lane = tid & 63;
  const int w = tid >> 6;
  const int wr = w >> 1, wc = w & 1;

  // XCD-aware bijective swizzle (m204)
  int nwg = gridDim.x * gridDim.y;
  int wgid = blockIdx.y * gridDim.x + blockIdx.x;
  int qq = nwg >> 3, rr = nwg & 7, xcd = wgid & 7, lid = wgid >> 3;
  int nid = (xcd < rr) ? xcd * (qq + 1) + lid
                       : rr * (qq + 1) + (xcd - rr) * qq + lid;
  const int col0 = (nid % gridDim.x) * 128;
  const int row0 = (nid / gridDim.x) * 128;

  // staging: chunk c = 16 rows (1 KiB). Wave w stages chunks {2w,2w+1} of all 4 planes.
  // lane l -> row 16c + (l>>2); global k-slot PRE-SWIZZLED: (l&3) ^ ((l>>3)&3).
  const int lr = lane >> 2;
  const int lk = (((lane & 3) ^ ((lane >> 3) & 3))) * 8;
  const unsigned short* gAh = Ahi + (size_t)(row0 + lr) * K + lk;
  const unsigned short* gAl = Alo + (size_t)(row0 + lr) * K + lk;
  const unsigned short* gBh = Bhi + (size_t)(col0 + lr) * K + lk;
  const unsigned short* gBl = Blo + (size_t)(col0 + lr) * K + lk;

  f32x4 acc[4][4];
#pragma unroll
  for (int i = 0; i < 4; i++)
#pragma unroll
    for (int j = 0; j < 4; j++) acc[i][j] = (f32x4){0.f, 0.f, 0.f, 0.f};

  const int fr = lane & 15;
  const int fq = lane >> 4;
  const int sfq = (fq ^ ((fr >> 1) & 3)) * 8;   // swizzled read slot (shorts)

  for (int k0 = 0; k0 < K; k0 += 32) {
    __syncthreads();   // previous iteration's fragment reads complete
#pragma unroll
    for (int c2 = 0; c2 < 2; c2++) {
      int c = w * 2 + c2;
      size_t roff = (size_t)c * 16 * K + k0;
      GL16(gAh + roff, &ah_s[c * 512]);
      GL16(gAl + roff, &al_s[c * 512]);
      GL16(gBh + roff, &bh_s[c * 512]);
      GL16(gBl + roff, &bl_s[c * 512]);
    }
    __syncthreads();   // vmcnt(0) drain -> tile published

    s16x8 ah[4], al[4], bh[4], bl[4];
#pragma unroll
    for (int i = 0; i < 4; i++) {
      int off = (wr * 64 + i * 16 + fr) * 32 + sfq;
      ah[i] = *(const s16x8*)&ah_s[off];
      al[i] = *(const s16x8*)&al_s[off];
    }
#pragma unroll
    for (int j = 0; j < 4; j++) {
      int off = (wc * 64 + j * 16 + fr) * 32 + sfq;
      bh[j] = *(const s16x8*)&bh_s[off];
      bl[j] = *(const s16x8*)&bl_s[off];
    }
#pragma unroll
    for (int i = 0; i < 4; i++)
#pragma unroll
      for (int j = 0; j < 4; j++) {
        acc[i][j] = __builtin_amdgcn_mfma_f32_16x16x32_bf16(ah[i], bh[j], acc[i][j], 0, 0, 0);
        acc[i][j] = __builtin_amdgcn_mfma_f32_16x16x32_bf16(ah[i], bl[j], acc[i][j], 0, 0, 0);
        acc[i][j] = __builtin_amdgcn_mfma_f32_16x16x32_bf16(al[i], bh[j], acc[i][j], 0, 0, 0);
      }
  }

  // epilogue: C col = lane&15, row = (lane>>4)*4 + reg (per 16x16 frag)
#pragma unroll
  for (int j = 0; j < 4; j++) {
    int col = col0 + wc * 64 + j * 16 + fr;
    float bj = bias[col];
#pragma unroll
    for (int i = 0; i < 4; i++) {
      int rbase = row0 + wr * 64 + i * 16 + fq * 4;
#pragma unroll
      for (int r = 0; r < 4; r++) {
        int row = rbase + r;
        if (row < M) C[(size_t)row * Nc + col] = acc[i][j][r] + bj;
      }
    }
  }
}

// ---------------- fp32 tiled GEMM (small head matmuls only) ----------------
#define BM 64
#define BN 64
#define BK 16

template <bool RELU>
__global__ __launch_bounds__(256) void gemm_bias(
    const float* __restrict__ A, const float* __restrict__ W,
    const float* __restrict__ bias, float* __restrict__ out,
    int M, int Nc, int K) {
  __shared__ float As[BK][BM + 1];
  __shared__ float Bs[BK][BN + 1];
  const int tid = threadIdx.x;
  const int tx = tid & 15;
  const int ty = tid >> 4;
  const int row0 = blockIdx.y * BM;
  const int col0 = blockIdx.x * BN;

  float acc[4][4] = {};

  for (int k0 = 0; k0 < K; k0 += BK) {
#pragma unroll
    for (int i = 0; i < 4; i++) {
      int idx = tid + i * 256;
      int m = idx >> 4;
      int kk = idx & 15;
      int gm = row0 + m;
      As[kk][m] = (gm < M) ? A[(size_t)gm * K + k0 + kk] : 0.f;
    }
#pragma unroll
    for (int i = 0; i < 4; i++) {
      int idx = tid + i * 256;
      int kk = idx >> 6;
      int nn = idx & 63;
      Bs[kk][nn] = W[(size_t)(k0 + kk) * Nc + col0 + nn];
    }
    __syncthreads();
#pragma unroll
    for (int kk = 0; kk < BK; kk++) {
      float a[4], b[4];
#pragma unroll
      for (int i = 0; i < 4; i++) a[i] = As[kk][ty * 4 + i];
#pragma unroll
      for (int j = 0; j < 4; j++) b[j] = Bs[kk][tx * 4 + j];
#pragma unroll
      for (int i = 0; i < 4; i++)
#pragma unroll
        for (int j = 0; j < 4; j++) acc[i][j] += a[i] * b[j];
    }
    __syncthreads();
  }

#pragma unroll
  for (int i = 0; i < 4; i++) {
    int gm = row0 + ty * 4 + i;
    if (gm >= M) continue;
#pragma unroll
    for (int j = 0; j < 4; j++) {
      int gn = col0 + tx * 4 + j;
      float v = acc[i][j] + bias[gn];
      if (RELU) v = fmaxf(v, 0.f);
      out[(size_t)gm * Nc + gn] = v;
    }
  }
}

// ---------------- CSR build ----------------
__global__ void count_dst(const int* __restrict__ ei, int* __restrict__ cnt,
                          int E, int Et) {
  int t = blockIdx.x * blockDim.x + threadIdx.x;
  if (t >= Et) return;
  int d = (t < E) ? ei[E + t] : t - E;
  atomicAdd(&cnt[d], 1);
}

#define SCAN_T 1024
__global__ __launch_bounds__(SCAN_T) void scan_offsets(
    const int* __restrict__ cnt, int* __restrict__ row_off, int N) {
  __shared__ int ssum[SCAN_T];
  int t = threadIdx.x;
  int per = (N + SCAN_T - 1) / SCAN_T;
  int beg = t * per, end = min(beg + per, N);
  int s = 0;
  for (int i = beg; i < end; i++) s += cnt[i];
  ssum[t] = s;
  __syncthreads();
  for (int off = 1; off < SCAN_T; off <<= 1) {
    int v = (t >= off) ? ssum[t - off] : 0;
    __syncthreads();
    ssum[t] += v;
    __syncthreads();
  }
  int run = (t == 0) ? 0 : ssum[t - 1];
  for (int i = beg; i < end; i++) { row_off[i] = run; run += cnt[i]; }
  if (t == 0) row_off[N] = ssum[SCAN_T - 1];
}

__global__ void scatter_edges(const int* __restrict__ ei,
                              const int* __restrict__ row_off,
                              int* __restrict__ fill,
                              int* __restrict__ esrc, int E, int Et) {
  int t = blockIdx.x * blockDim.x + threadIdx.x;
  if (t >= Et) return;
  int s, d;
  if (t < E) { s = ei[t]; d = ei[E + t]; } else { s = t - E; d = s; }
  int pos = row_off[d] + atomicAdd(&fill[d], 1);
  esrc[pos] = s;
}

// ---------------- fused per-node attention: scores + softmax + aggregate ----------------
// block = 256 threads = 8 heads x 32 lanes; one destination node per block.
// pass 1: online (max,sum) over in-edges; pass 2: recompute score, accumulate alpha*hl[src].
// MODE 1: epilogue bias+ELU -> split bf16 planes.  MODE 0: mean over heads + bias -> hfin.
template <int MODE>
__global__ __launch_bounds__(256) void node_attn(
    const float* __restrict__ hl, const float* __restrict__ hr,
    const int* __restrict__ row_off, const int* __restrict__ esrc,
    const float* __restrict__ att, const float* __restrict__ bias,
    float* __restrict__ outf, unsigned short* __restrict__ Chi,
    unsigned short* __restrict__ Clo, int N) {
  __shared__ float red[HC];   // used only in MODE 0 head-mean
  int n = blockIdx.x;
  int t = threadIdx.x;
  int h = t >> 5;
  int l = t & 31;
  int beg = row_off[n], end = row_off[n + 1];

  const f32x4* attp = (const f32x4*)(att + h * HID + l * 8);
  const f32x4 at0 = attp[0], at1 = attp[1];
  const f32x4* hrp = (const f32x4*)(hr + (size_t)n * HC + h * HID + l * 8);
  const f32x4 hr0 = hrp[0], hr1 = hrp[1];

  // ---- pass 1: online softmax stats ----
  float m = -1e30f, s = 0.f;
  for (int j = beg; j < end; j++) {
    int src = esrc[j];
    const f32x4* p = (const f32x4*)(hl + (size_t)src * HC + h * HID + l * 8);
    f32x4 v0 = p[0], v1 = p[1];
    float sc = 0.f;
#pragma unroll
    for (int q = 0; q < 4; q++) {
      float g0 = v0[q] + hr0[q]; g0 = (g0 > 0.f) ? g0 : NEG_SLOPE * g0; sc += at0[q] * g0;
      float g1 = v1[q] + hr1[q]; g1 = (g1 > 0.f) ? g1 : NEG_SLOPE * g1; sc += at1[q] * g1;
    }
#pragma unroll
    for (int off = 16; off > 0; off >>= 1) sc += __shfl_xor(sc, off);
    float mn = fmaxf(m, sc);
    s = s * expf(m - mn) + expf(sc - mn);
    m = mn;
  }
  float inv = 1.f / (s + 1e-16f);

  // ---- pass 2: aggregate ----
  f32x4 a0 = {0.f, 0.f, 0.f, 0.f}, a1 = {0.f, 0.f, 0.f, 0.f};
  for (int j = beg; j < end; j++) {
    int src = esrc[j];
    const f32x4* p = (const f32x4*)(hl + (size_t)src * HC + h * HID + l * 8);
    f32x4 v0 = p[0], v1 = p[1];
    float sc = 0.f;
#pragma unroll
    for (int q = 0; q < 4; q++) {
      float g0 = v0[q] + hr0[q]; g0 = (g0 > 0.f) ? g0 : NEG_SLOPE * g0; sc += at0[q] * g0;
      float g1 = v1[q] + hr1[q]; g1 = (g1 > 0.f) ? g1 : NEG_SLOPE * g1; sc += at1[q] * g1;
    }
#pragma unroll
    for (int off = 16; off > 0; off >>= 1) sc += __shfl_xor(sc, off);
    float al = expf(sc - m) * inv;
    a0 += al * v0;
    a1 += al * v1;
  }

  int cbase = h * HID + l * 8;
  if (MODE == 1) {
    float v[8];
#pragma unroll
    for (int q = 0; q < 4; q++) {
      float xx = a0[q] + bias[cbase + q];
      v[q] = (xx > 0.f) ? xx : (expf(xx) - 1.f);
    }
#pragma unroll
    for (int q = 0; q < 4; q++) {
      float xx = a1[q] + bias[cbase + 4 + q];
      v[4 + q] = (xx > 0.f) ? xx : (expf(xx) - 1.f);
    }
    s16x8 hv, lv;
    split8(v, hv, lv);
    *(s16x8*)&Chi[(size_t)n * HC + cbase] = hv;
    *(s16x8*)&Clo[(size_t)n * HC + cbase] = lv;
  } else {
    // head-mean + bias -> outf[n][HID]
#pragma unroll
    for (int q = 0; q < 4; q++) red[cbase + q] = a0[q];
#pragma unroll
    for (int q = 0; q < 4; q++) red[cbase + 4 + q] = a1[q];
    __syncthreads();
    int c = t;  // 0..255
    float sm = 0.f;
#pragma unroll
    for (int hh = 0; hh < HEADS; hh++) sm += red[hh * HID + c];
    outf[(size_t)n * HID + c] = 0.125f * sm + bias[c];
  }
}

// ---------------- tiny final projection ----------------
__global__ void head_final(const float* __restrict__ hid,
                           const float* __restrict__ W,
                           const float* __restrict__ b,
                           float* __restrict__ out, int N, int K, int O) {
  int t = blockIdx.x * blockDim.x + threadIdx.x;
  if (t >= N * O) return;
  int n = t / O, j = t % O;
  float s = b[j];
  const float* hrow = hid + (size_t)n * K;
  for (int k = 0; k < K; k++) s += hrow[k] * W[(size_t)k * O + j];
  out[t] = s;
}

// ---------------- host side ----------------
static inline void run_big_gemm(const unsigned short* Ahi, const unsigned short* Alo,
                                const float* W, unsigned short* Wthi, unsigned short* Wtlo,
                                const float* bias, float* out, int M, int Nc, int K,
                                hipStream_t stream) {
  dim3 tg(Nc / 32, K / 32);
  wsplit_t<<<tg, 256, 0, stream>>>(W, Wthi, Wtlo, K, Nc);
  dim3 grid(Nc / 128, (M + 127) / 128);
  gemm_planes2<<<grid, 256, 0, stream>>>(Ahi, Alo, Wthi, Wtlo, bias, out, M, Nc, K);
}

static inline void run_gemm_f32(const float* A, const float* W, const float* bias,
                                float* out, int M, int Nc, int K, bool relu,
                                hipStream_t stream) {
  dim3 grid((Nc + BN - 1) / BN, (M + BM - 1) / BM);
  if (relu)
    gemm_bias<true><<<grid, 256, 0, stream>>>(A, W, bias, out, M, Nc, K);
  else
    gemm_bias<false><<<grid, 256, 0, stream>>>(A, W, bias, out, M, Nc, K);
}

extern "C" void kernel_launch(void* const* d_in, const int* in_sizes, int n_in,
                              void* d_out, int out_size, void* d_ws, size_t ws_size,
                              hipStream_t stream) {
  const float* x   = (const float*)d_in[0];
  const int*   ei  = (const int*)d_in[1];
  const float* Wl0 = (const float*)d_in[2];  const float* bl0 = (const float*)d_in[3];
  const float* Wr0 = (const float*)d_in[4];  const float* br0 = (const float*)d_in[5];
  const float* att0= (const float*)d_in[6];  const float* b0  = (const float*)d_in[7];
  const float* Wl1 = (const float*)d_in[8];  const float* bl1 = (const float*)d_in[9];
  const float* Wr1 = (const float*)d_in[10]; const float* br1 = (const float*)d_in[11];
  const float* att1= (const float*)d_in[12]; const float* b1  = (const float*)d_in[13];
  const float* Wl2 = (const float*)d_in[14]; const float* bl2 = (const float*)d_in[15];
  const float* Wr2 = (const float*)d_in[16]; const float* br2 = (const float*)d_in[17];
  const float* att2= (const float*)d_in[18]; const float* b2  = (const float*)d_in[19];
  const float* W_pam1 = (const float*)d_in[20]; const float* b_pam1 = (const float*)d_in[21];
  const float* W_pam2 = (const float*)d_in[22]; const float* b_pam2 = (const float*)d_in[23];
  const float* W_sur1 = (const float*)d_in[24]; const float* b_sur1 = (const float*)d_in[25];
  const float* W_sur2 = (const float*)d_in[26]; const float* b_sur2 = (const float*)d_in[27];

  const int N  = in_sizes[0] / IN_DIM;   // 10000
  const int E  = in_sizes[1] / 2;        // 40000
  const int Et = E + N;

  // ---- workspace layout (~262.8 MB) ----
  char* p = (char*)d_ws;
  const size_t NF = (size_t)N * HC;
  float* bufA = (float*)p;                 p += NF * 4;               // hl (fp32)
  float* bufB = (float*)p;                 p += NF * 4;               // hr (fp32)
  unsigned short* Chi = (unsigned short*)p; p += NF * 2;              // A hi plane
  unsigned short* Clo = (unsigned short*)p; p += NF * 2;              // A lo plane
  unsigned short* Wthi = (unsigned short*)p; p += (size_t)HC * HC * 2;
  unsigned short* Wtlo = (unsigned short*)p; p += (size_t)HC * HC * 2;
  int* row_off = (int*)p;                  p += (size_t)(N + 1) * 4;  // persistent CSR
  int* esrc    = (int*)p;                  p += (size_t)Et * 4;
  int* cnt     = (int*)p;                  p += (size_t)N * 4;
  int* fill    = (int*)p;                  p += (size_t)N * 4;
  // layer-0 x planes alias Chi/Clo region (2 x N*IN_DIM shorts = 20.5 MB < 41 MB)
  unsigned short* Xhi = Chi;
  unsigned short* Xlo = Xhi + (size_t)N * IN_DIM;
  // head-stage buffers alias Chi/Clo (dead after layer-2 GEMMs); NOT bufA (read as hl)
  float* hfin = (float*)Chi;            // N*HID
  float* hid  = (float*)Clo;            // N*128

  float* out_pam = (float*)d_out;
  float* out_sur = out_pam + (size_t)N * OUT_DIM;

  // ---------- CSR build (graph identical for all layers) ----------
  hipMemsetAsync(cnt, 0, N * 4, stream);
  hipMemsetAsync(fill, 0, N * 4, stream);
  count_dst<<<(Et + 255) / 256, 256, 0, stream>>>(ei, cnt, E, Et);
  scan_offsets<<<1, SCAN_T, 0, stream>>>(cnt, row_off, N);
  scatter_edges<<<(Et + 255) / 256, 256, 0, stream>>>(ei, row_off, fill, esrc, E, Et);

  // ---------- layer 0 ----------
  split_pad<<<(unsigned)(((long)N * IN_DIM / 4 + 255) / 256), 256, 0, stream>>>(
      x, Xhi, Xlo, (long)N * IN_DIM);
  run_big_gemm(Xhi, Xlo, Wl0, Wthi, Wtlo, bl0, bufA, N, HC, IN_DIM, stream);
  run_big_gemm(Xhi, Xlo, Wr0, Wthi, Wtlo, br0, bufB, N, HC, IN_DIM, stream);
  node_attn<1><<<N, 256, 0, stream>>>(bufA, bufB, row_off, esrc, att0, b0,
                                      nullptr, Chi, Clo, N);

  // ---------- layer 1 ----------
  run_big_gemm(Chi, Clo, Wl1, Wthi, Wtlo, bl1, bufA, N, HC, HC, stream);
  run_big_gemm(Chi, Clo, Wr1, Wthi, Wtlo, br1, bufB, N, HC, HC, stream);
  node_attn<1><<<N, 256, 0, stream>>>(bufA, bufB, row_off, esrc, att1, b1,
                                      nullptr, Chi, Clo, N);

  // ---------- layer 2 (fused head-mean) ----------
  run_big_gemm(Chi, Clo, Wl2, Wthi, Wtlo, bl2, bufA, N, HC, HC, stream);
  run_big_gemm(Chi, Clo, Wr2, Wthi, Wtlo, br2, bufB, N, HC, HC, stream);
  node_attn<0><<<N, 256, 0, stream>>>(bufA, bufB, row_off, esrc, att2, b2,
                                      hfin, nullptr, nullptr, N);

  // ---------- heads (tiny, fp32) ----------
  run_gemm_f32(hfin, W_pam1, b_pam1, hid, N, HID / 2, HID, true, stream);
  head_final<<<(N * OUT_DIM + 255) / 256, 256, 0, stream>>>(hid, W_pam2, b_pam2, out_pam, N, HID / 2, OUT_DIM);
  run_gemm_f32(hfin, W_sur1, b_sur1, hid, N, HID / 2, HID, true, stream);
  head_final<<<(N + 255) / 256, 256, 0, stream>>>(hid, W_sur2, b_sur2, out_sur, N, HID / 2, 1);
}

// Round 9
// 1687.953 us; speedup vs baseline: 7.3300x; 1.0291x over previous
//
#include <hip/hip_runtime.h>
#include <hip/hip_bf16.h>
#include <math.h>

// ---------------- constants of the problem ----------------
#define IN_DIM 512
#define HID 256
#define HEADS 8
#define HC (HEADS * HID)   // 2048
#define OUT_DIM 5
#define NEG_SLOPE 0.2f

typedef short s16x8 __attribute__((ext_vector_type(8)));
typedef float f32x4 __attribute__((ext_vector_type(4)));

// ---------------- bf16 split helpers (round-to-nearest-even) ----------------
__device__ inline unsigned short bf16_rne(float f) {
  unsigned u = __float_as_uint(f);
  unsigned r = (u + 0x7fffu + ((u >> 16) & 1u)) >> 16;
  return (unsigned short)r;
}
__device__ inline float bf16_to_f(unsigned short h) {
  return __uint_as_float(((unsigned)h) << 16);
}
__device__ inline void split8(const float* f, s16x8& hv, s16x8& lv) {
  s16x8 h, l;
#pragma unroll
  for (int i = 0; i < 8; i++) {
    unsigned short hs = bf16_rne(f[i]);
    h[i] = (short)hs;
    l[i] = (short)bf16_rne(f[i] - bf16_to_f(hs));
  }
  hv = h; lv = l;
}

// ---------------- split fp32 -> (hi, lo) bf16 planes ----------------
__global__ void split_pad(const float* __restrict__ X,
                          unsigned short* __restrict__ hi,
                          unsigned short* __restrict__ lo, long ntotal) {
  long i = ((long)blockIdx.x * blockDim.x + threadIdx.x) * 4;
  if (i >= ntotal) return;
  float4 v = *(const float4*)(X + i);
  ushort4 h, l;
  h.x = bf16_rne(v.x); l.x = bf16_rne(v.x - bf16_to_f(h.x));
  h.y = bf16_rne(v.y); l.y = bf16_rne(v.y - bf16_to_f(h.y));
  h.z = bf16_rne(v.z); l.z = bf16_rne(v.z - bf16_to_f(h.z));
  h.w = bf16_rne(v.w); l.w = bf16_rne(v.w - bf16_to_f(h.w));
  *(ushort4*)(hi + i) = h;
  *(ushort4*)(lo + i) = l;
}

// ---------------- transpose + split weights: W[K][N] -> Wt hi/lo [N][K] ----------------
__global__ __launch_bounds__(256) void wsplit_t(
    const float* __restrict__ W, unsigned short* __restrict__ thi,
    unsigned short* __restrict__ tlo, int K, int N) {
  __shared__ float tile[32][33];
  int tx = threadIdx.x & 31, ty = threadIdx.x >> 5;  // ty 0..7
  int n0 = blockIdx.x * 32, k0 = blockIdx.y * 32;
#pragma unroll
  for (int r = 0; r < 4; r++) {
    int k = k0 + ty + r * 8;
    tile[ty + r * 8][tx] = W[(size_t)k * N + n0 + tx];
  }
  __syncthreads();
#pragma unroll
  for (int r = 0; r < 4; r++) {
    int n = n0 + ty + r * 8;
    float v = tile[tx][ty + r * 8];
    unsigned short h = bf16_rne(v);
    thi[(size_t)n * K + k0 + tx] = h;
    tlo[(size_t)n * K + k0 + tx] = bf16_rne(v - bf16_to_f(h));
  }
}

// ---------------- split-bf16 MFMA GEMM, both sides pre-split planes, T2 swizzle ----------------
// C[M][Nc] = (Ahi+Alo)[M][K] @ (Bhi+Blo)^T[Nc][K] + bias   (3-product accumulation)
// LDS layout per plane: [128 rows][4 slots of 16B]; LDS (r,s) holds global (r, s ^ ((r>>1)&3)).
// Write side: linear GL16 dest + pre-swizzled per-lane GLOBAL k-slot (rule #21 / m173).
// Read side: slot = fq ^ ((fr>>1)&3) -> conflict-free (verified: SQ_LDS_BANK_CONFLICT 2e7 -> 0).
#define GL16(gp, lp) __builtin_amdgcn_global_load_lds( \
    (const __attribute__((address_space(1))) void*)(gp), \
    (__attribute__((address_space(3))) void*)(lp), 16, 0, 0)

__global__ __launch_bounds__(256, 4) void gemm_planes2(
    const unsigned short* __restrict__ Ahi, const unsigned short* __restrict__ Alo,
    const unsigned short* __restrict__ Bhi, const unsigned short* __restrict__ Blo,
    const float* __restrict__ bias, float* __restrict__ C,
    int M, int Nc, int K) {
  __shared__ __attribute__((aligned(16))) unsigned short ah_s[128 * 32];
  __shared__ __attribute__((aligned(16))) unsigned short al_s[128 * 32];
  __shared__ __attribute__((aligned(16))) unsigned short bh_s[128 * 32];
  __shared__ __attribute__((aligned(16))) unsigned short bl_s[128 * 32];

  const int tid = threadIdx.x;
  const int lane = tid & 63;
  const int w = tid >> 6;
  const int wr = w >> 1, wc = w & 1;

  // XCD-aware bijective swizzle (m204)
  int nwg = gridDim.x * gridDim.y;
  int wgid = blockIdx.y * gridDim.x + blockIdx.x;
  int qq = nwg >> 3, rr = nwg & 7, xcd = wgid & 7, lid = wgid >> 3;
  int nid = (xcd < rr) ? xcd * (qq + 1) + lid
                       : rr * (qq + 1) + (xcd - rr) * qq + lid;
  const int col0 = (nid % gridDim.x) * 128;
  const int row0 = (nid / gridDim.x) * 128;

  // staging: chunk c = 16 rows (1 KiB). Wave w stages chunks {2w,2w+1} of all 4 planes.
  // lane l -> row 16c + (l>>2); global k-slot PRE-SWIZZLED: (l&3) ^ ((l>>3)&3).
  const int lr = lane >> 2;
  const int lk = (((lane & 3) ^ ((lane >> 3) & 3))) * 8;
  const unsigned short* gAh = Ahi + (size_t)(row0 + lr) * K + lk;
  const unsigned short* gAl = Alo + (size_t)(row0 + lr) * K + lk;
  const unsigned short* gBh = Bhi + (size_t)(col0 + lr) * K + lk;
  const unsigned short* gBl = Blo + (size_t)(col0 + lr) * K + lk;

  f32x4 acc[4][4];
#pragma unroll
  for (int i = 0; i < 4; i++)
#pragma unroll
    for (int j = 0; j < 4; j++) acc[i][j] = (f32x4){0.f, 0.f, 0.f, 0.f};

  const int fr = lane & 15;
  const int fq = lane >> 4;
  const int sfq = (fq ^ ((fr >> 1) & 3)) * 8;   // swizzled read slot (shorts)

  for (int k0 = 0; k0 < K; k0 += 32) {
    __syncthreads();   // previous iteration's fragment reads complete
#pragma unroll
    for (int c2 = 0; c2 < 2; c2++) {
      int c = w * 2 + c2;
      size_t roff = (size_t)c * 16 * K + k0;
      GL16(gAh + roff, &ah_s[c * 512]);
      GL16(gAl + roff, &al_s[c * 512]);
      GL16(gBh + roff, &bh_s[c * 512]);
      GL16(gBl + roff, &bl_s[c * 512]);
    }
    __syncthreads();   // vmcnt(0) drain -> tile published

    s16x8 ah[4], al[4], bh[4], bl[4];
#pragma unroll
    for (int i = 0; i < 4; i++) {
      int off = (wr * 64 + i * 16 + fr) * 32 + sfq;
      ah[i] = *(const s16x8*)&ah_s[off];
      al[i] = *(const s16x8*)&al_s[off];
    }
#pragma unroll
    for (int j = 0; j < 4; j++) {
      int off = (wc * 64 + j * 16 + fr) * 32 + sfq;
      bh[j] = *(const s16x8*)&bh_s[off];
      bl[j] = *(const s16x8*)&bl_s[off];
    }
#pragma unroll
    for (int i = 0; i < 4; i++)
#pragma unroll
      for (int j = 0; j < 4; j++) {
        acc[i][j] = __builtin_amdgcn_mfma_f32_16x16x32_bf16(ah[i], bh[j], acc[i][j], 0, 0, 0);
        acc[i][j] = __builtin_amdgcn_mfma_f32_16x16x32_bf16(ah[i], bl[j], acc[i][j], 0, 0, 0);
        acc[i][j] = __builtin_amdgcn_mfma_f32_16x16x32_bf16(al[i], bh[j], acc[i][j], 0, 0, 0);
      }
  }

  // epilogue: C col = lane&15, row = (lane>>4)*4 + reg (per 16x16 frag)
#pragma unroll
  for (int j = 0; j < 4; j++) {
    int col = col0 + wc * 64 + j * 16 + fr;
    float bj = bias[col];
#pragma unroll
    for (int i = 0; i < 4; i++) {
      int rbase = row0 + wr * 64 + i * 16 + fq * 4;
#pragma unroll
      for (int r = 0; r < 4; r++) {
        int row = rbase + r;
        if (row < M) C[(size_t)row * Nc + col] = acc[i][j][r] + bj;
      }
    }
  }
}

// ---------------- fp32 tiled GEMM (small head matmuls only) ----------------
#define BM 64
#define BN 64
#define BK 16

template <bool RELU>
__global__ __launch_bounds__(256) void gemm_bias(
    const float* __restrict__ A, const float* __restrict__ W,
    const float* __restrict__ bias, float* __restrict__ out,
    int M, int Nc, int K) {
  __shared__ float As[BK][BM + 1];
  __shared__ float Bs[BK][BN + 1];
  const int tid = threadIdx.x;
  const int tx = tid & 15;
  const int ty = tid >> 4;
  const int row0 = blockIdx.y * BM;
  const int col0 = blockIdx.x * BN;

  float acc[4][4] = {};

  for (int k0 = 0; k0 < K; k0 += BK) {
#pragma unroll
    for (int i = 0; i < 4; i++) {
      int idx = tid + i * 256;
      int m = idx >> 4;
      int kk = idx & 15;
      int gm = row0 + m;
      As[kk][m] = (gm < M) ? A[(size_t)gm * K + k0 + kk] : 0.f;
    }
#pragma unroll
    for (int i = 0; i < 4; i++) {
      int idx = tid + i * 256;
      int kk = idx >> 6;
      int nn = idx & 63;
      Bs[kk][nn] = W[(size_t)(k0 + kk) * Nc + col0 + nn];
    }
    __syncthreads();
#pragma unroll
    for (int kk = 0; kk < BK; kk++) {
      float a[4], b[4];
#pragma unroll
      for (int i = 0; i < 4; i++) a[i] = As[kk][ty * 4 + i];
#pragma unroll
      for (int j = 0; j < 4; j++) b[j] = Bs[kk][tx * 4 + j];
#pragma unroll
      for (int i = 0; i < 4; i++)
#pragma unroll
        for (int j = 0; j < 4; j++) acc[i][j] += a[i] * b[j];
    }
    __syncthreads();
  }

#pragma unroll
  for (int i = 0; i < 4; i++) {
    int gm = row0 + ty * 4 + i;
    if (gm >= M) continue;
#pragma unroll
    for (int j = 0; j < 4; j++) {
      int gn = col0 + tx * 4 + j;
      float v = acc[i][j] + bias[gn];
      if (RELU) v = fmaxf(v, 0.f);
      out[(size_t)gm * Nc + gn] = v;
    }
  }
}

// ---------------- CSR build ----------------
__global__ void count_dst(const int* __restrict__ ei, int* __restrict__ cnt,
                          int E, int Et) {
  int t = blockIdx.x * blockDim.x + threadIdx.x;
  if (t >= Et) return;
  int d = (t < E) ? ei[E + t] : t - E;
  atomicAdd(&cnt[d], 1);
}

#define SCAN_T 1024
__global__ __launch_bounds__(SCAN_T) void scan_offsets(
    const int* __restrict__ cnt, int* __restrict__ row_off, int N) {
  __shared__ int ssum[SCAN_T];
  int t = threadIdx.x;
  int per = (N + SCAN_T - 1) / SCAN_T;
  int beg = t * per, end = min(beg + per, N);
  int s = 0;
  for (int i = beg; i < end; i++) s += cnt[i];
  ssum[t] = s;
  __syncthreads();
  for (int off = 1; off < SCAN_T; off <<= 1) {
    int v = (t >= off) ? ssum[t - off] : 0;
    __syncthreads();
    ssum[t] += v;
    __syncthreads();
  }
  int run = (t == 0) ? 0 : ssum[t - 1];
  for (int i = beg; i < end; i++) { row_off[i] = run; run += cnt[i]; }
  if (t == 0) row_off[N] = ssum[SCAN_T - 1];
}

__global__ void scatter_edges(const int* __restrict__ ei,
                              const int* __restrict__ row_off,
                              int* __restrict__ fill,
                              int* __restrict__ esrc, int E, int Et) {
  int t = blockIdx.x * blockDim.x + threadIdx.x;
  if (t >= Et) return;
  int s, d;
  if (t < E) { s = ei[t]; d = ei[E + t]; } else { s = t - E; d = s; }
  int pos = row_off[d] + atomicAdd(&fill[d], 1);
  esrc[pos] = s;
}

// ---------------- fused per-node attention: SINGLE-PASS online softmax+aggregate ----------------
// block = 256 threads = 8 heads x 32 lanes; one destination node per block.
// Flash-style: running (m, s, acc); per edge rescale by exp(m_old - m_new).
// Post-reduce score is uniform across the 32-lane group, so m/s/rescale are coherent.
// MODE 1: epilogue bias+ELU -> split bf16 planes.  MODE 0: mean over heads + bias -> outf.
template <int MODE>
__global__ __launch_bounds__(256) void node_attn(
    const float* __restrict__ hl, const float* __restrict__ hr,
    const int* __restrict__ row_off, const int* __restrict__ esrc,
    const float* __restrict__ att, const float* __restrict__ bias,
    float* __restrict__ outf, unsigned short* __restrict__ Chi,
    unsigned short* __restrict__ Clo, int N) {
  __shared__ float red[HC];   // used only in MODE 0 head-mean
  int n = blockIdx.x;
  int t = threadIdx.x;
  int h = t >> 5;
  int l = t & 31;
  int beg = row_off[n], end = row_off[n + 1];

  const f32x4* attp = (const f32x4*)(att + h * HID + l * 8);
  const f32x4 at0 = attp[0], at1 = attp[1];
  const f32x4* hrp = (const f32x4*)(hr + (size_t)n * HC + h * HID + l * 8);
  const f32x4 hr0 = hrp[0], hr1 = hrp[1];

  float m = -1e30f, s = 0.f;
  f32x4 a0 = {0.f, 0.f, 0.f, 0.f}, a1 = {0.f, 0.f, 0.f, 0.f};
  for (int j = beg; j < end; j++) {
    int src = esrc[j];
    const f32x4* p = (const f32x4*)(hl + (size_t)src * HC + h * HID + l * 8);
    f32x4 v0 = p[0], v1 = p[1];
    float sc = 0.f;
#pragma unroll
    for (int q = 0; q < 4; q++) {
      float g0 = v0[q] + hr0[q]; g0 = (g0 > 0.f) ? g0 : NEG_SLOPE * g0; sc += at0[q] * g0;
      float g1 = v1[q] + hr1[q]; g1 = (g1 > 0.f) ? g1 : NEG_SLOPE * g1; sc += at1[q] * g1;
    }
#pragma unroll
    for (int off = 16; off > 0; off >>= 1) sc += __shfl_xor(sc, off);
    float mn = fmaxf(m, sc);
    float fold = expf(m - mn);       // first iter: exp(-inf) = 0
    float e = expf(sc - mn);
    s = s * fold + e;
    a0 = a0 * fold + e * v0;
    a1 = a1 * fold + e * v1;
    m = mn;
  }
  float inv = 1.f / (s + 1e-16f);
  a0 *= inv;
  a1 *= inv;

  int cbase = h * HID + l * 8;
  if (MODE == 1) {
    float v[8];
#pragma unroll
    for (int q = 0; q < 4; q++) {
      float xx = a0[q] + bias[cbase + q];
      v[q] = (xx > 0.f) ? xx : (expf(xx) - 1.f);
    }
#pragma unroll
    for (int q = 0; q < 4; q++) {
      float xx = a1[q] + bias[cbase + 4 + q];
      v[4 + q] = (xx > 0.f) ? xx : (expf(xx) - 1.f);
    }
    s16x8 hv, lv;
    split8(v, hv, lv);
    *(s16x8*)&Chi[(size_t)n * HC + cbase] = hv;
    *(s16x8*)&Clo[(size_t)n * HC + cbase] = lv;
  } else {
    // head-mean + bias -> outf[n][HID]
#pragma unroll
    for (int q = 0; q < 4; q++) red[cbase + q] = a0[q];
#pragma unroll
    for (int q = 0; q < 4; q++) red[cbase + 4 + q] = a1[q];
    __syncthreads();
    int c = t;  // 0..255
    float sm = 0.f;
#pragma unroll
    for (int hh = 0; hh < HEADS; hh++) sm += red[hh * HID + c];
    outf[(size_t)n * HID + c] = 0.125f * sm + bias[c];
  }
}

// ---------------- tiny final projection ----------------
__global__ void head_final(const float* __restrict__ hid,
                           const float* __restrict__ W,
                           const float* __restrict__ b,
                           float* __restrict__ out, int N, int K, int O) {
  int t = blockIdx.x * blockDim.x + threadIdx.x;
  if (t >= N * O) return;
  int n = t / O, j = t % O;
  float s = b[j];
  const float* hrow = hid + (size_t)n * K;
  for (int k = 0; k < K; k++) s += hrow[k] * W[(size_t)k * O + j];
  out[t] = s;
}

// ---------------- host side ----------------
static inline void run_big_gemm(const unsigned short* Ahi, const unsigned short* Alo,
                                const float* W, unsigned short* Wthi, unsigned short* Wtlo,
                                const float* bias, float* out, int M, int Nc, int K,
                                hipStream_t stream) {
  dim3 tg(Nc / 32, K / 32);
  wsplit_t<<<tg, 256, 0, stream>>>(W, Wthi, Wtlo, K, Nc);
  dim3 grid(Nc / 128, (M + 127) / 128);
  gemm_planes2<<<grid, 256, 0, stream>>>(Ahi, Alo, Wthi, Wtlo, bias, out, M, Nc, K);
}

static inline void run_gemm_f32(const float* A, const float* W, const float* bias,
                                float* out, int M, int Nc, int K, bool relu,
                                hipStream_t stream) {
  dim3 grid((Nc + BN - 1) / BN, (M + BM - 1) / BM);
  if (relu)
    gemm_bias<true><<<grid, 256, 0, stream>>>(A, W, bias, out, M, Nc, K);
  else
    gemm_bias<false><<<grid, 256, 0, stream>>>(A, W, bias, out, M, Nc, K);
}

extern "C" void kernel_launch(void* const* d_in, const int* in_sizes, int n_in,
                              void* d_out, int out_size, void* d_ws, size_t ws_size,
                              hipStream_t stream) {
  const float* x   = (const float*)d_in[0];
  const int*   ei  = (const int*)d_in[1];
  const float* Wl0 = (const float*)d_in[2];  const float* bl0 = (const float*)d_in[3];
  const float* Wr0 = (const float*)d_in[4];  const float* br0 = (const float*)d_in[5];
  const float* att0= (const float*)d_in[6];  const float* b0  = (const float*)d_in[7];
  const float* Wl1 = (const float*)d_in[8];  const float* bl1 = (const float*)d_in[9];
  const float* Wr1 = (const float*)d_in[10]; const float* br1 = (const float*)d_in[11];
  const float* att1= (const float*)d_in[12]; const float* b1  = (const float*)d_in[13];
  const float* Wl2 = (const float*)d_in[14]; const float* bl2 = (const float*)d_in[15];
  const float* Wr2 = (const float*)d_in[16]; const float* br2 = (const float*)d_in[17];
  const float* att2= (const float*)d_in[18]; const float* b2  = (const float*)d_in[19];
  const float* W_pam1 = (const float*)d_in[20]; const float* b_pam1 = (const float*)d_in[21];
  const float* W_pam2 = (const float*)d_in[22]; const float* b_pam2 = (const float*)d_in[23];
  const float* W_sur1 = (const float*)d_in[24]; const float* b_sur1 = (const float*)d_in[25];
  const float* W_sur2 = (const float*)d_in[26]; const float* b_sur2 = (const float*)d_in[27];

  const int N  = in_sizes[0] / IN_DIM;   // 10000
  const int E  = in_sizes[1] / 2;        // 40000
  const int Et = E + N;

  // ---- workspace layout (~262.8 MB) ----
  char* p = (char*)d_ws;
  const size_t NF = (size_t)N * HC;
  float* bufA = (float*)p;                 p += NF * 4;               // hl (fp32)
  float* bufB = (float*)p;                 p += NF * 4;               // hr (fp32)
  unsigned short* Chi = (unsigned short*)p; p += NF * 2;              // A hi plane
  unsigned short* Clo = (unsigned short*)p; p += NF * 2;              // A lo plane
  unsigned short* Wthi = (unsigned short*)p; p += (size_t)HC * HC * 2;
  unsigned short* Wtlo = (unsigned short*)p; p += (size_t)HC * HC * 2;
  int* row_off = (int*)p;                  p += (size_t)(N + 1) * 4;  // persistent CSR
  int* esrc    = (int*)p;                  p += (size_t)Et * 4;
  int* cnt     = (int*)p;                  p += (size_t)N * 4;
  int* fill    = (int*)p;                  p += (size_t)N * 4;
  // layer-0 x planes alias Chi/Clo region (2 x N*IN_DIM shorts = 20.5 MB < 41 MB)
  unsigned short* Xhi = Chi;
  unsigned short* Xlo = Xhi + (size_t)N * IN_DIM;
  // head-stage buffers alias Chi/Clo (dead after layer-2 GEMMs); NOT bufA (read as hl)
  float* hfin = (float*)Chi;            // N*HID
  float* hid  = (float*)Clo;            // N*128

  float* out_pam = (float*)d_out;
  float* out_sur = out_pam + (size_t)N * OUT_DIM;

  // ---------- CSR build (graph identical for all layers) ----------
  hipMemsetAsync(cnt, 0, N * 4, stream);
  hipMemsetAsync(fill, 0, N * 4, stream);
  count_dst<<<(Et + 255) / 256, 256, 0, stream>>>(ei, cnt, E, Et);
  scan_offsets<<<1, SCAN_T, 0, stream>>>(cnt, row_off, N);
  scatter_edges<<<(Et + 255) / 256, 256, 0, stream>>>(ei, row_off, fill, esrc, E, Et);

  // ---------- layer 0 ----------
  split_pad<<<(unsigned)(((long)N * IN_DIM / 4 + 255) / 256), 256, 0, stream>>>(
      x, Xhi, Xlo, (long)N * IN_DIM);
  run_big_gemm(Xhi, Xlo, Wl0, Wthi, Wtlo, bl0, bufA, N, HC, IN_DIM, stream);
  run_big_gemm(Xhi, Xlo, Wr0, Wthi, Wtlo, br0, bufB, N, HC, IN_DIM, stream);
  node_attn<1><<<N, 256, 0, stream>>>(bufA, bufB, row_off, esrc, att0, b0,
                                      nullptr, Chi, Clo, N);

  // ---------- layer 1 ----------
  run_big_gemm(Chi, Clo, Wl1, Wthi, Wtlo, bl1, bufA, N, HC, HC, stream);
  run_big_gemm(Chi, Clo, Wr1, Wthi, Wtlo, br1, bufB, N, HC, HC, stream);
  node_attn<1><<<N, 256, 0, stream>>>(bufA, bufB, row_off, esrc, att1, b1,
                                      nullptr, Chi, Clo, N);

  // ---------- layer 2 (fused head-mean) ----------
  run_big_gemm(Chi, Clo, Wl2, Wthi, Wtlo, bl2, bufA, N, HC, HC, stream);
  run_big_gemm(Chi, Clo, Wr2, Wthi, Wtlo, br2, bufB, N, HC, HC, stream);
  node_attn<0><<<N, 256, 0, stream>>>(bufA, bufB, row_off, esrc, att2, b2,
                                      hfin, nullptr, nullptr, N);

  // ---------- heads (tiny, fp32) ----------
  run_gemm_f32(hfin, W_pam1, b_pam1, hid, N, HID / 2, HID, true, stream);
  head_final<<<(N * OUT_DIM + 255) / 256, 256, 0, stream>>>(hid, W_pam2, b_pam2, out_pam, N, HID / 2, OUT_DIM);
  run_gemm_f32(hfin, W_sur1, b_sur1, hid, N, HID / 2, HID, true, stream);
  head_final<<<(N + 255) / 256, 256, 0, stream>>>(hid, W_sur2, b_sur2, out_sur, N, HID / 2, 1);
}

// Round 10
// 1572.743 us; speedup vs baseline: 7.8670x; 1.0733x over previous
//
#include <hip/hip_runtime.h>
#include <hip/hip_bf16.h>
#include <math.h>

// ---------------- constants of the problem ----------------
#define IN_DIM 512
#define HID 256
#define HEADS 8
#define HC (HEADS * HID)   // 2048
#define HCX (2 * HC)       // 4096: interleaved hl|hr row stride
#define OUT_DIM 5
#define NEG_SLOPE 0.2f

typedef short s16x8 __attribute__((ext_vector_type(8)));
typedef float f32x4 __attribute__((ext_vector_type(4)));

// ---------------- bf16 split helpers (round-to-nearest-even) ----------------
__device__ inline unsigned short bf16_rne(float f) {
  unsigned u = __float_as_uint(f);
  unsigned r = (u + 0x7fffu + ((u >> 16) & 1u)) >> 16;
  return (unsigned short)r;
}
__device__ inline float bf16_to_f(unsigned short h) {
  return __uint_as_float(((unsigned)h) << 16);
}
__device__ inline void split8(const float* f, s16x8& hv, s16x8& lv) {
  s16x8 h, l;
#pragma unroll
  for (int i = 0; i < 8; i++) {
    unsigned short hs = bf16_rne(f[i]);
    h[i] = (short)hs;
    l[i] = (short)bf16_rne(f[i] - bf16_to_f(hs));
  }
  hv = h; lv = l;
}

// ---------------- split fp32 -> (hi, lo) bf16 planes ----------------
__global__ void split_pad(const float* __restrict__ X,
                          unsigned short* __restrict__ hi,
                          unsigned short* __restrict__ lo, long ntotal) {
  long i = ((long)blockIdx.x * blockDim.x + threadIdx.x) * 4;
  if (i >= ntotal) return;
  float4 v = *(const float4*)(X + i);
  ushort4 h, l;
  h.x = bf16_rne(v.x); l.x = bf16_rne(v.x - bf16_to_f(h.x));
  h.y = bf16_rne(v.y); l.y = bf16_rne(v.y - bf16_to_f(h.y));
  h.z = bf16_rne(v.z); l.z = bf16_rne(v.z - bf16_to_f(h.z));
  h.w = bf16_rne(v.w); l.w = bf16_rne(v.w - bf16_to_f(h.w));
  *(ushort4*)(hi + i) = h;
  *(ushort4*)(lo + i) = l;
}

// ---------------- transpose + split weights: W[K][N] -> Wt hi/lo [N][K] ----------------
__global__ __launch_bounds__(256) void wsplit_t(
    const float* __restrict__ W, unsigned short* __restrict__ thi,
    unsigned short* __restrict__ tlo, int K, int N) {
  __shared__ float tile[32][33];
  int tx = threadIdx.x & 31, ty = threadIdx.x >> 5;  // ty 0..7
  int n0 = blockIdx.x * 32, k0 = blockIdx.y * 32;
#pragma unroll
  for (int r = 0; r < 4; r++) {
    int k = k0 + ty + r * 8;
    tile[ty + r * 8][tx] = W[(size_t)k * N + n0 + tx];
  }
  __syncthreads();
#pragma unroll
  for (int r = 0; r < 4; r++) {
    int n = n0 + ty + r * 8;
    float v = tile[tx][ty + r * 8];
    unsigned short h = bf16_rne(v);
    thi[(size_t)n * K + k0 + tx] = h;
    tlo[(size_t)n * K + k0 + tx] = bf16_rne(v - bf16_to_f(h));
  }
}

// ---------------- split-bf16 MFMA GEMM, both sides pre-split planes, T2 swizzle ----------------
// C[M][.] (ldC stride) = (Ahi+Alo)[M][K] @ (Bhi+Blo)^T[Nc][K] + bias  (3-product accum)
// bias: col < halfN -> biasL[col], else biasR[col-halfN]  (halfN=Nc => always biasL)
#define GL16(gp, lp) __builtin_amdgcn_global_load_lds( \
    (const __attribute__((address_space(1))) void*)(gp), \
    (__attribute__((address_space(3))) void*)(lp), 16, 0, 0)

__global__ __launch_bounds__(256, 3) void gemm_planes2(
    const unsigned short* __restrict__ Ahi, const unsigned short* __restrict__ Alo,
    const unsigned short* __restrict__ Bhi, const unsigned short* __restrict__ Blo,
    const float* __restrict__ biasL, const float* __restrict__ biasR,
    float* __restrict__ C, int M, int Nc, int ldC, int K, int halfN) {
  __shared__ __attribute__((aligned(16))) unsigned short ah_s[128 * 32];
  __shared__ __attribute__((aligned(16))) unsigned short al_s[128 * 32];
  __shared__ __attribute__((aligned(16))) unsigned short bh_s[128 * 32];
  __shared__ __attribute__((aligned(16))) unsigned short bl_s[128 * 32];

  const int tid = threadIdx.x;
  const int lane = tid & 63;
  const int w = tid >> 6;
  const int wr = w >> 1, wc = w & 1;

  // XCD-aware bijective swizzle (m204)
  int nwg = gridDim.x * gridDim.y;
  int wgid = blockIdx.y * gridDim.x + blockIdx.x;
  int qq = nwg >> 3, rr = nwg & 7, xcd = wgid & 7, lid = wgid >> 3;
  int nid = (xcd < rr) ? xcd * (qq + 1) + lid
                       : rr * (qq + 1) + (xcd - rr) * qq + lid;
  const int col0 = (nid % gridDim.x) * 128;
  const int row0 = (nid / gridDim.x) * 128;

  // staging: chunk c = 16 rows (1 KiB). Wave w stages chunks {2w,2w+1} of all 4 planes.
  // lane l -> row 16c + (l>>2); global k-slot PRE-SWIZZLED: (l&3) ^ ((l>>3)&3).
  const int lr = lane >> 2;
  const int lk = (((lane & 3) ^ ((lane >> 3) & 3))) * 8;
  const unsigned short* gAh = Ahi + (size_t)(row0 + lr) * K + lk;
  const unsigned short* gAl = Alo + (size_t)(row0 + lr) * K + lk;
  const unsigned short* gBh = Bhi + (size_t)(col0 + lr) * K + lk;
  const unsigned short* gBl = Blo + (size_t)(col0 + lr) * K + lk;

  f32x4 acc[4][4];
#pragma unroll
  for (int i = 0; i < 4; i++)
#pragma unroll
    for (int j = 0; j < 4; j++) acc[i][j] = (f32x4){0.f, 0.f, 0.f, 0.f};

  const int fr = lane & 15;
  const int fq = lane >> 4;
  const int sfq = (fq ^ ((fr >> 1) & 3)) * 8;   // swizzled read slot (shorts)

  for (int k0 = 0; k0 < K; k0 += 32) {
    __syncthreads();   // previous iteration's fragment reads complete
#pragma unroll
    for (int c2 = 0; c2 < 2; c2++) {
      int c = w * 2 + c2;
      size_t roff = (size_t)c * 16 * K + k0;
      GL16(gAh + roff, &ah_s[c * 512]);
      GL16(gAl + roff, &al_s[c * 512]);
      GL16(gBh + roff, &bh_s[c * 512]);
      GL16(gBl + roff, &bl_s[c * 512]);
    }
    __syncthreads();   // vmcnt(0) drain -> tile published

    s16x8 ah[4], al[4], bh[4], bl[4];
#pragma unroll
    for (int i = 0; i < 4; i++) {
      int off = (wr * 64 + i * 16 + fr) * 32 + sfq;
      ah[i] = *(const s16x8*)&ah_s[off];
      al[i] = *(const s16x8*)&al_s[off];
    }
#pragma unroll
    for (int j = 0; j < 4; j++) {
      int off = (wc * 64 + j * 16 + fr) * 32 + sfq;
      bh[j] = *(const s16x8*)&bh_s[off];
      bl[j] = *(const s16x8*)&bl_s[off];
    }
#pragma unroll
    for (int i = 0; i < 4; i++)
#pragma unroll
      for (int j = 0; j < 4; j++) {
        acc[i][j] = __builtin_amdgcn_mfma_f32_16x16x32_bf16(ah[i], bh[j], acc[i][j], 0, 0, 0);
        acc[i][j] = __builtin_amdgcn_mfma_f32_16x16x32_bf16(ah[i], bl[j], acc[i][j], 0, 0, 0);
        acc[i][j] = __builtin_amdgcn_mfma_f32_16x16x32_bf16(al[i], bh[j], acc[i][j], 0, 0, 0);
      }
  }

  // epilogue: C col = lane&15, row = (lane>>4)*4 + reg (per 16x16 frag)
#pragma unroll
  for (int j = 0; j < 4; j++) {
    int col = col0 + wc * 64 + j * 16 + fr;
    float bj = (col < halfN) ? biasL[col] : biasR[col - halfN];
#pragma unroll
    for (int i = 0; i < 4; i++) {
      int rbase = row0 + wr * 64 + i * 16 + fq * 4;
#pragma unroll
      for (int r = 0; r < 4; r++) {
        int row = rbase + r;
        if (row < M) C[(size_t)row * ldC + col] = acc[i][j][r] + bj;
      }
    }
  }
}

// ---------------- fp32 tiled GEMM (merged head matmul only) ----------------
#define BM 64
#define BN 64
#define BK 16

template <bool RELU>
__global__ __launch_bounds__(256) void gemm_bias(
    const float* __restrict__ A, const float* __restrict__ W,
    const float* __restrict__ bias, float* __restrict__ out,
    int M, int Nc, int K) {
  __shared__ float As[BK][BM + 1];
  __shared__ float Bs[BK][BN + 1];
  const int tid = threadIdx.x;
  const int tx = tid & 15;
  const int ty = tid >> 4;
  const int row0 = blockIdx.y * BM;
  const int col0 = blockIdx.x * BN;

  float acc[4][4] = {};

  for (int k0 = 0; k0 < K; k0 += BK) {
#pragma unroll
    for (int i = 0; i < 4; i++) {
      int idx = tid + i * 256;
      int m = idx >> 4;
      int kk = idx & 15;
      int gm = row0 + m;
      As[kk][m] = (gm < M) ? A[(size_t)gm * K + k0 + kk] : 0.f;
    }
#pragma unroll
    for (int i = 0; i < 4; i++) {
      int idx = tid + i * 256;
      int kk = idx >> 6;
      int nn = idx & 63;
      Bs[kk][nn] = W[(size_t)(k0 + kk) * Nc + col0 + nn];
    }
    __syncthreads();
#pragma unroll
    for (int kk = 0; kk < BK; kk++) {
      float a[4], b[4];
#pragma unroll
      for (int i = 0; i < 4; i++) a[i] = As[kk][ty * 4 + i];
#pragma unroll
      for (int j = 0; j < 4; j++) b[j] = Bs[kk][tx * 4 + j];
#pragma unroll
      for (int i = 0; i < 4; i++)
#pragma unroll
        for (int j = 0; j < 4; j++) acc[i][j] += a[i] * b[j];
    }
    __syncthreads();
  }

#pragma unroll
  for (int i = 0; i < 4; i++) {
    int gm = row0 + ty * 4 + i;
    if (gm >= M) continue;
#pragma unroll
    for (int j = 0; j < 4; j++) {
      int gn = col0 + tx * 4 + j;
      float v = acc[i][j] + bias[gn];
      if (RELU) v = fmaxf(v, 0.f);
      out[(size_t)gm * Nc + gn] = v;
    }
  }
}

// ---------------- CSR build ----------------
__global__ void count_dst(const int* __restrict__ ei, int* __restrict__ cnt,
                          int E, int Et) {
  int t = blockIdx.x * blockDim.x + threadIdx.x;
  if (t >= Et) return;
  int d = (t < E) ? ei[E + t] : t - E;
  atomicAdd(&cnt[d], 1);
}

#define SCAN_T 1024
__global__ __launch_bounds__(SCAN_T) void scan_offsets(
    const int* __restrict__ cnt, int* __restrict__ row_off, int N) {
  __shared__ int ssum[SCAN_T];
  int t = threadIdx.x;
  int per = (N + SCAN_T - 1) / SCAN_T;
  int beg = t * per, end = min(beg + per, N);
  int s = 0;
  for (int i = beg; i < end; i++) s += cnt[i];
  ssum[t] = s;
  __syncthreads();
  for (int off = 1; off < SCAN_T; off <<= 1) {
    int v = (t >= off) ? ssum[t - off] : 0;
    __syncthreads();
    ssum[t] += v;
    __syncthreads();
  }
  int run = (t == 0) ? 0 : ssum[t - 1];
  for (int i = beg; i < end; i++) { row_off[i] = run; run += cnt[i]; }
  if (t == 0) row_off[N] = ssum[SCAN_T - 1];
}

__global__ void scatter_edges(const int* __restrict__ ei,
                              const int* __restrict__ row_off,
                              int* __restrict__ fill,
                              int* __restrict__ esrc, int E, int Et) {
  int t = blockIdx.x * blockDim.x + threadIdx.x;
  if (t >= Et) return;
  int s, d;
  if (t < E) { s = ei[t]; d = ei[E + t]; } else { s = t - E; d = s; }
  int pos = row_off[d] + atomicAdd(&fill[d], 1);
  esrc[pos] = s;
}

// ---------------- fused per-node attention: SINGLE-PASS online softmax+aggregate ----------------
// hl/hr both stride HCX (interleaved layout). block = 8 heads x 32 lanes; 1 node/block.
template <int MODE>
__global__ __launch_bounds__(256) void node_attn(
    const float* __restrict__ hl, const float* __restrict__ hr,
    const int* __restrict__ row_off, const int* __restrict__ esrc,
    const float* __restrict__ att, const float* __restrict__ bias,
    float* __restrict__ outf, unsigned short* __restrict__ Chi,
    unsigned short* __restrict__ Clo, int N) {
  __shared__ float red[HC];   // used only in MODE 0 head-mean
  int n = blockIdx.x;
  int t = threadIdx.x;
  int h = t >> 5;
  int l = t & 31;
  int beg = row_off[n], end = row_off[n + 1];

  const f32x4* attp = (const f32x4*)(att + h * HID + l * 8);
  const f32x4 at0 = attp[0], at1 = attp[1];
  const f32x4* hrp = (const f32x4*)(hr + (size_t)n * HCX + h * HID + l * 8);
  const f32x4 hr0 = hrp[0], hr1 = hrp[1];

  float m = -1e30f, s = 0.f;
  f32x4 a0 = {0.f, 0.f, 0.f, 0.f}, a1 = {0.f, 0.f, 0.f, 0.f};
  for (int j = beg; j < end; j++) {
    int src = esrc[j];
    const f32x4* p = (const f32x4*)(hl + (size_t)src * HCX + h * HID + l * 8);
    f32x4 v0 = p[0], v1 = p[1];
    float sc = 0.f;
#pragma unroll
    for (int q = 0; q < 4; q++) {
      float g0 = v0[q] + hr0[q]; g0 = (g0 > 0.f) ? g0 : NEG_SLOPE * g0; sc += at0[q] * g0;
      float g1 = v1[q] + hr1[q]; g1 = (g1 > 0.f) ? g1 : NEG_SLOPE * g1; sc += at1[q] * g1;
    }
#pragma unroll
    for (int off = 16; off > 0; off >>= 1) sc += __shfl_xor(sc, off);
    float mn = fmaxf(m, sc);
    float fold = expf(m - mn);       // first iter: exp(-inf) = 0
    float e = expf(sc - mn);
    s = s * fold + e;
    a0 = a0 * fold + e * v0;
    a1 = a1 * fold + e * v1;
    m = mn;
  }
  float inv = 1.f / (s + 1e-16f);
  a0 *= inv;
  a1 *= inv;

  int cbase = h * HID + l * 8;
  if (MODE == 1) {
    float v[8];
#pragma unroll
    for (int q = 0; q < 4; q++) {
      float xx = a0[q] + bias[cbase + q];
      v[q] = (xx > 0.f) ? xx : (expf(xx) - 1.f);
    }
#pragma unroll
    for (int q = 0; q < 4; q++) {
      float xx = a1[q] + bias[cbase + 4 + q];
      v[4 + q] = (xx > 0.f) ? xx : (expf(xx) - 1.f);
    }
    s16x8 hv, lv;
    split8(v, hv, lv);
    *(s16x8*)&Chi[(size_t)n * HC + cbase] = hv;
    *(s16x8*)&Clo[(size_t)n * HC + cbase] = lv;
  } else {
    // head-mean + bias -> outf[n][HID]
#pragma unroll
    for (int q = 0; q < 4; q++) red[cbase + q] = a0[q];
#pragma unroll
    for (int q = 0; q < 4; q++) red[cbase + 4 + q] = a1[q];
    __syncthreads();
    int c = t;  // 0..255
    float sm = 0.f;
#pragma unroll
    for (int hh = 0; hh < HEADS; hh++) sm += red[hh * HID + c];
    outf[(size_t)n * HID + c] = 0.125f * sm + bias[c];
  }
}

// ---------------- concat head weights: [256][128]|[256][128] -> [256][256] ----------------
__global__ void cat_heads(const float* __restrict__ Wp, const float* __restrict__ Ws,
                          const float* __restrict__ bp, const float* __restrict__ bs,
                          float* __restrict__ Wcat, float* __restrict__ bcat) {
  int r = blockIdx.x, c = threadIdx.x;   // 256 x 256
  Wcat[r * 256 + c] = (c < 128) ? Wp[r * 128 + c] : Ws[r * 128 + (c - 128)];
  if (r == 0) bcat[c] = (c < 128) ? bp[c] : bs[c - 128];
}

// ---------------- tiny final projection (reads a column-slice of hid) ----------------
__global__ void head_final(const float* __restrict__ hid, int ldH, int off,
                           const float* __restrict__ W,
                           const float* __restrict__ b,
                           float* __restrict__ out, int N, int K, int O) {
  int t = blockIdx.x * blockDim.x + threadIdx.x;
  if (t >= N * O) return;
  int n = t / O, j = t % O;
  float s = b[j];
  const float* hrow = hid + (size_t)n * ldH + off;
  for (int k = 0; k < K; k++) s += hrow[k] * W[(size_t)k * O + j];
  out[t] = s;
}

// ---------------- host side ----------------
extern "C" void kernel_launch(void* const* d_in, const int* in_sizes, int n_in,
                              void* d_out, int out_size, void* d_ws, size_t ws_size,
                              hipStream_t stream) {
  const float* x   = (const float*)d_in[0];
  const int*   ei  = (const int*)d_in[1];
  const float* Wl0 = (const float*)d_in[2];  const float* bl0 = (const float*)d_in[3];
  const float* Wr0 = (const float*)d_in[4];  const float* br0 = (const float*)d_in[5];
  const float* att0= (const float*)d_in[6];  const float* b0  = (const float*)d_in[7];
  const float* Wl1 = (const float*)d_in[8];  const float* bl1 = (const float*)d_in[9];
  const float* Wr1 = (const float*)d_in[10]; const float* br1 = (const float*)d_in[11];
  const float* att1= (const float*)d_in[12]; const float* b1  = (const float*)d_in[13];
  const float* Wl2 = (const float*)d_in[14]; const float* bl2 = (const float*)d_in[15];
  const float* Wr2 = (const float*)d_in[16]; const float* br2 = (const float*)d_in[17];
  const float* att2= (const float*)d_in[18]; const float* b2  = (const float*)d_in[19];
  const float* W_pam1 = (const float*)d_in[20]; const float* b_pam1 = (const float*)d_in[21];
  const float* W_pam2 = (const float*)d_in[22]; const float* b_pam2 = (const float*)d_in[23];
  const float* W_sur1 = (const float*)d_in[24]; const float* b_sur1 = (const float*)d_in[25];
  const float* W_sur2 = (const float*)d_in[26]; const float* b_sur2 = (const float*)d_in[27];

  const int N  = in_sizes[0] / IN_DIM;   // 10000
  const int E  = in_sizes[1] / 2;        // 40000
  const int Et = E + N;

  // ---- workspace layout (~263.1 MB; <= proven 263.4) ----
  char* p = (char*)d_ws;
  const size_t NF = (size_t)N * HC;
  float* bufAB = (float*)p;                 p += NF * 2 * 4;          // [N][4096] hl|hr fp32
  unsigned short* Chi = (unsigned short*)p; p += NF * 2;              // A hi plane
  unsigned short* Clo = (unsigned short*)p; p += NF * 2;              // A lo plane
  unsigned short* Wthi = (unsigned short*)p; p += (size_t)HC * HC * 2;
  unsigned short* Wtlo = (unsigned short*)p; p += (size_t)HC * HC * 2;
  int* row_off = (int*)p;                  p += (size_t)(N + 1) * 4;  // persistent CSR
  int* esrc    = (int*)p;                  p += (size_t)Et * 4;
  int* cnt     = (int*)p;                  p += (size_t)N * 4;
  int* fill    = (int*)p;                  p += (size_t)N * 4;
  float* Wcat  = (float*)p;                p += 256 * 256 * 4;        // merged head W
  float* bcat  = (float*)p;                p += 256 * 4;
  // layer-0 x planes alias Chi/Clo region (2 x N*IN_DIM shorts = 20.5 MB < 41 MB)
  unsigned short* Xhi = Chi;
  unsigned short* Xlo = Xhi + (size_t)N * IN_DIM;
  // head-stage buffers alias Chi/Clo (dead after layer-2 GEMMs)
  float* hfin = (float*)Chi;            // N*HID
  float* hid  = (float*)Clo;            // N*256 (pam|sur halves)

  float* out_pam = (float*)d_out;
  float* out_sur = out_pam + (size_t)N * OUT_DIM;

  float* hlp = bufAB;          // hl half (cols 0..2047), stride HCX
  float* hrp = bufAB + HC;     // hr half (cols 2048..4095), stride HCX

  // ---------- CSR build (graph identical for all layers) ----------
  hipMemsetAsync(cnt, 0, N * 4, stream);
  hipMemsetAsync(fill, 0, N * 4, stream);
  count_dst<<<(Et + 255) / 256, 256, 0, stream>>>(ei, cnt, E, Et);
  scan_offsets<<<1, SCAN_T, 0, stream>>>(cnt, row_off, N);
  scatter_edges<<<(Et + 255) / 256, 256, 0, stream>>>(ei, row_off, fill, esrc, E, Et);
  cat_heads<<<256, 256, 0, stream>>>(W_pam1, W_sur1, b_pam1, b_sur1, Wcat, bcat);

  // ---------- layer 0 (merged Wl|Wr, Nc=4096, K=512) ----------
  split_pad<<<(unsigned)(((long)N * IN_DIM / 4 + 255) / 256), 256, 0, stream>>>(
      x, Xhi, Xlo, (long)N * IN_DIM);
  {
    dim3 tg(HC / 32, IN_DIM / 32);
    wsplit_t<<<tg, 256, 0, stream>>>(Wl0, Wthi, Wtlo, IN_DIM, HC);
    wsplit_t<<<tg, 256, 0, stream>>>(Wr0, Wthi + (size_t)HC * IN_DIM,
                                     Wtlo + (size_t)HC * IN_DIM, IN_DIM, HC);
    dim3 grid(HCX / 128, (N + 127) / 128);
    gemm_planes2<<<grid, 256, 0, stream>>>(Xhi, Xlo, Wthi, Wtlo, bl0, br0,
                                           bufAB, N, HCX, HCX, IN_DIM, HC);
  }
  node_attn<1><<<N, 256, 0, stream>>>(hlp, hrp, row_off, esrc, att0, b0,
                                      nullptr, Chi, Clo, N);

  // ---------- layer 1 ----------
  {
    dim3 tg(HC / 32, HC / 32);
    dim3 grid(HC / 128, (N + 127) / 128);
    wsplit_t<<<tg, 256, 0, stream>>>(Wl1, Wthi, Wtlo, HC, HC);
    gemm_planes2<<<grid, 256, 0, stream>>>(Chi, Clo, Wthi, Wtlo, bl1, bl1,
                                           bufAB, N, HC, HCX, HC, HC);
    wsplit_t<<<tg, 256, 0, stream>>>(Wr1, Wthi, Wtlo, HC, HC);
    gemm_planes2<<<grid, 256, 0, stream>>>(Chi, Clo, Wthi, Wtlo, br1, br1,
                                           bufAB + HC, N, HC, HCX, HC, HC);
  }
  node_attn<1><<<N, 256, 0, stream>>>(hlp, hrp, row_off, esrc, att1, b1,
                                      nullptr, Chi, Clo, N);

  // ---------- layer 2 (fused head-mean) ----------
  {
    dim3 tg(HC / 32, HC / 32);
    dim3 grid(HC / 128, (N + 127) / 128);
    wsplit_t<<<tg, 256, 0, stream>>>(Wl2, Wthi, Wtlo, HC, HC);
    gemm_planes2<<<grid, 256, 0, stream>>>(Chi, Clo, Wthi, Wtlo, bl2, bl2,
                                           bufAB, N, HC, HCX, HC, HC);
    wsplit_t<<<tg, 256, 0, stream>>>(Wr2, Wthi, Wtlo, HC, HC);
    gemm_planes2<<<grid, 256, 0, stream>>>(Chi, Clo, Wthi, Wtlo, br2, br2,
                                           bufAB + HC, N, HC, HCX, HC, HC);
  }
  node_attn<0><<<N, 256, 0, stream>>>(hlp, hrp, row_off, esrc, att2, b2,
                                      hfin, nullptr, nullptr, N);

  // ---------- heads (merged first GEMM, fp32) ----------
  {
    dim3 grid(256 / BN, (N + BM - 1) / BM);
    gemm_bias<true><<<grid, 256, 0, stream>>>(hfin, Wcat, bcat, hid, N, 256, HID);
  }
  head_final<<<(N * OUT_DIM + 255) / 256, 256, 0, stream>>>(
      hid, 256, 0, W_pam2, b_pam2, out_pam, N, HID / 2, OUT_DIM);
  head_final<<<(N + 255) / 256, 256, 0, stream>>>(
      hid, 256, 128, W_sur2, b_sur2, out_sur, N, HID / 2, 1);
}

// Round 11
// 1527.319 us; speedup vs baseline: 8.1010x; 1.0297x over previous
//
#include <hip/hip_runtime.h>
#include <hip/hip_bf16.h>
#include <math.h>

// ---------------- constants of the problem ----------------
#define IN_DIM 512
#define HID 256
#define HEADS 8
#define HC (HEADS * HID)   // 2048
#define HCX (2 * HC)       // 4096: interleaved hl|hr row stride
#define OUT_DIM 5
#define NEG_SLOPE 0.2f

typedef short s16x8 __attribute__((ext_vector_type(8)));
typedef float f32x4 __attribute__((ext_vector_type(4)));

// ---------------- bf16 split helpers (round-to-nearest-even) ----------------
__device__ inline unsigned short bf16_rne(float f) {
  unsigned u = __float_as_uint(f);
  unsigned r = (u + 0x7fffu + ((u >> 16) & 1u)) >> 16;
  return (unsigned short)r;
}
__device__ inline float bf16_to_f(unsigned short h) {
  return __uint_as_float(((unsigned)h) << 16);
}
__device__ inline void split8(const float* f, s16x8& hv, s16x8& lv) {
  s16x8 h, l;
#pragma unroll
  for (int i = 0; i < 8; i++) {
    unsigned short hs = bf16_rne(f[i]);
    h[i] = (short)hs;
    l[i] = (short)bf16_rne(f[i] - bf16_to_f(hs));
  }
  hv = h; lv = l;
}

// ---------------- split fp32 -> (hi, lo) bf16 planes ----------------
__global__ void split_pad(const float* __restrict__ X,
                          unsigned short* __restrict__ hi,
                          unsigned short* __restrict__ lo, long ntotal) {
  long i = ((long)blockIdx.x * blockDim.x + threadIdx.x) * 4;
  if (i >= ntotal) return;
  float4 v = *(const float4*)(X + i);
  ushort4 h, l;
  h.x = bf16_rne(v.x); l.x = bf16_rne(v.x - bf16_to_f(h.x));
  h.y = bf16_rne(v.y); l.y = bf16_rne(v.y - bf16_to_f(h.y));
  h.z = bf16_rne(v.z); l.z = bf16_rne(v.z - bf16_to_f(h.z));
  h.w = bf16_rne(v.w); l.w = bf16_rne(v.w - bf16_to_f(h.w));
  *(ushort4*)(hi + i) = h;
  *(ushort4*)(lo + i) = l;
}

// ---------------- transpose + split weights: W[K][N] -> Wt hi/lo [N][K] ----------------
__global__ __launch_bounds__(256) void wsplit_t(
    const float* __restrict__ W, unsigned short* __restrict__ thi,
    unsigned short* __restrict__ tlo, int K, int N) {
  __shared__ float tile[32][33];
  int tx = threadIdx.x & 31, ty = threadIdx.x >> 5;  // ty 0..7
  int n0 = blockIdx.x * 32, k0 = blockIdx.y * 32;
#pragma unroll
  for (int r = 0; r < 4; r++) {
    int k = k0 + ty + r * 8;
    tile[ty + r * 8][tx] = W[(size_t)k * N + n0 + tx];
  }
  __syncthreads();
#pragma unroll
  for (int r = 0; r < 4; r++) {
    int n = n0 + ty + r * 8;
    float v = tile[tx][ty + r * 8];
    unsigned short h = bf16_rne(v);
    thi[(size_t)n * K + k0 + tx] = h;
    tlo[(size_t)n * K + k0 + tx] = bf16_rne(v - bf16_to_f(h));
  }
}

// ---------------- split-bf16 MFMA GEMM, both sides pre-split planes, T2 swizzle ----------------
// C[M][.] (ldC stride) = (Ahi+Alo)[M][K] @ (Bhi+Blo)^T[Nc][K] + bias  (3-product accum)
// bias: col < halfN -> biasL[col], else biasR[col-halfN]  (halfN=Nc => always biasL)
#define GL16(gp, lp) __builtin_amdgcn_global_load_lds( \
    (const __attribute__((address_space(1))) void*)(gp), \
    (__attribute__((address_space(3))) void*)(lp), 16, 0, 0)

__global__ __launch_bounds__(256, 3) void gemm_planes2(
    const unsigned short* __restrict__ Ahi, const unsigned short* __restrict__ Alo,
    const unsigned short* __restrict__ Bhi, const unsigned short* __restrict__ Blo,
    const float* __restrict__ biasL, const float* __restrict__ biasR,
    float* __restrict__ C, int M, int Nc, int ldC, int K, int halfN) {
  __shared__ __attribute__((aligned(16))) unsigned short ah_s[128 * 32];
  __shared__ __attribute__((aligned(16))) unsigned short al_s[128 * 32];
  __shared__ __attribute__((aligned(16))) unsigned short bh_s[128 * 32];
  __shared__ __attribute__((aligned(16))) unsigned short bl_s[128 * 32];

  const int tid = threadIdx.x;
  const int lane = tid & 63;
  const int w = tid >> 6;
  const int wr = w >> 1, wc = w & 1;

  // XCD-aware bijective swizzle (m204)
  int nwg = gridDim.x * gridDim.y;
  int wgid = blockIdx.y * gridDim.x + blockIdx.x;
  int qq = nwg >> 3, rr = nwg & 7, xcd = wgid & 7, lid = wgid >> 3;
  int nid = (xcd < rr) ? xcd * (qq + 1) + lid
                       : rr * (qq + 1) + (xcd - rr) * qq + lid;
  const int col0 = (nid % gridDim.x) * 128;
  const int row0 = (nid / gridDim.x) * 128;

  // staging: chunk c = 16 rows (1 KiB). Wave w stages chunks {2w,2w+1} of all 4 planes.
  // lane l -> row 16c + (l>>2); global k-slot PRE-SWIZZLED: (l&3) ^ ((l>>3)&3).
  const int lr = lane >> 2;
  const int lk = (((lane & 3) ^ ((lane >> 3) & 3))) * 8;
  const unsigned short* gAh = Ahi + (size_t)(row0 + lr) * K + lk;
  const unsigned short* gAl = Alo + (size_t)(row0 + lr) * K + lk;
  const unsigned short* gBh = Bhi + (size_t)(col0 + lr) * K + lk;
  const unsigned short* gBl = Blo + (size_t)(col0 + lr) * K + lk;

  f32x4 acc[4][4];
#pragma unroll
  for (int i = 0; i < 4; i++)
#pragma unroll
    for (int j = 0; j < 4; j++) acc[i][j] = (f32x4){0.f, 0.f, 0.f, 0.f};

  const int fr = lane & 15;
  const int fq = lane >> 4;
  const int sfq = (fq ^ ((fr >> 1) & 3)) * 8;   // swizzled read slot (shorts)

  for (int k0 = 0; k0 < K; k0 += 32) {
    __syncthreads();   // previous iteration's fragment reads complete
#pragma unroll
    for (int c2 = 0; c2 < 2; c2++) {
      int c = w * 2 + c2;
      size_t roff = (size_t)c * 16 * K + k0;
      GL16(gAh + roff, &ah_s[c * 512]);
      GL16(gAl + roff, &al_s[c * 512]);
      GL16(gBh + roff, &bh_s[c * 512]);
      GL16(gBl + roff, &bl_s[c * 512]);
    }
    __syncthreads();   // vmcnt(0) drain -> tile published

    s16x8 ah[4], al[4], bh[4], bl[4];
#pragma unroll
    for (int i = 0; i < 4; i++) {
      int off = (wr * 64 + i * 16 + fr) * 32 + sfq;
      ah[i] = *(const s16x8*)&ah_s[off];
      al[i] = *(const s16x8*)&al_s[off];
    }
#pragma unroll
    for (int j = 0; j < 4; j++) {
      int off = (wc * 64 + j * 16 + fr) * 32 + sfq;
      bh[j] = *(const s16x8*)&bh_s[off];
      bl[j] = *(const s16x8*)&bl_s[off];
    }
#pragma unroll
    for (int i = 0; i < 4; i++)
#pragma unroll
      for (int j = 0; j < 4; j++) {
        acc[i][j] = __builtin_amdgcn_mfma_f32_16x16x32_bf16(ah[i], bh[j], acc[i][j], 0, 0, 0);
        acc[i][j] = __builtin_amdgcn_mfma_f32_16x16x32_bf16(ah[i], bl[j], acc[i][j], 0, 0, 0);
        acc[i][j] = __builtin_amdgcn_mfma_f32_16x16x32_bf16(al[i], bh[j], acc[i][j], 0, 0, 0);
      }
  }

  // epilogue: C col = lane&15, row = (lane>>4)*4 + reg (per 16x16 frag)
#pragma unroll
  for (int j = 0; j < 4; j++) {
    int col = col0 + wc * 64 + j * 16 + fr;
    float bj = (col < halfN) ? biasL[col] : biasR[col - halfN];
#pragma unroll
    for (int i = 0; i < 4; i++) {
      int rbase = row0 + wr * 64 + i * 16 + fq * 4;
#pragma unroll
      for (int r = 0; r < 4; r++) {
        int row = rbase + r;
        if (row < M) C[(size_t)row * ldC + col] = acc[i][j][r] + bj;
      }
    }
  }
}

// ---------------- CSR build ----------------
__global__ void count_dst(const int* __restrict__ ei, int* __restrict__ cnt,
                          int E, int Et) {
  int t = blockIdx.x * blockDim.x + threadIdx.x;
  if (t >= Et) return;
  int d = (t < E) ? ei[E + t] : t - E;
  atomicAdd(&cnt[d], 1);
}

#define SCAN_T 1024
__global__ __launch_bounds__(SCAN_T) void scan_offsets(
    const int* __restrict__ cnt, int* __restrict__ row_off, int N) {
  __shared__ int ssum[SCAN_T];
  int t = threadIdx.x;
  int per = (N + SCAN_T - 1) / SCAN_T;
  int beg = t * per, end = min(beg + per, N);
  int s = 0;
  for (int i = beg; i < end; i++) s += cnt[i];
  ssum[t] = s;
  __syncthreads();
  for (int off = 1; off < SCAN_T; off <<= 1) {
    int v = (t >= off) ? ssum[t - off] : 0;
    __syncthreads();
    ssum[t] += v;
    __syncthreads();
  }
  int run = (t == 0) ? 0 : ssum[t - 1];
  for (int i = beg; i < end; i++) { row_off[i] = run; run += cnt[i]; }
  if (t == 0) row_off[N] = ssum[SCAN_T - 1];
}

__global__ void scatter_edges(const int* __restrict__ ei,
                              const int* __restrict__ row_off,
                              int* __restrict__ fill,
                              int* __restrict__ esrc, int E, int Et) {
  int t = blockIdx.x * blockDim.x + threadIdx.x;
  if (t >= Et) return;
  int s, d;
  if (t < E) { s = ei[t]; d = ei[E + t]; } else { s = t - E; d = s; }
  int pos = row_off[d] + atomicAdd(&fill[d], 1);
  esrc[pos] = s;
}

// ---------------- fused per-node attention: SINGLE-PASS online softmax+aggregate ----------------
// hl/hr both stride HCX (interleaved layout). block = 8 heads x 32 lanes; 1 node/block.
template <int MODE>
__global__ __launch_bounds__(256) void node_attn(
    const float* __restrict__ hl, const float* __restrict__ hr,
    const int* __restrict__ row_off, const int* __restrict__ esrc,
    const float* __restrict__ att, const float* __restrict__ bias,
    float* __restrict__ outf, unsigned short* __restrict__ Chi,
    unsigned short* __restrict__ Clo, int N) {
  int n = blockIdx.x;
  int t = threadIdx.x;
  int h = t >> 5;
  int l = t & 31;
  int beg = row_off[n], end = row_off[n + 1];

  const f32x4* attp = (const f32x4*)(att + h * HID + l * 8);
  const f32x4 at0 = attp[0], at1 = attp[1];
  const f32x4* hrp = (const f32x4*)(hr + (size_t)n * HCX + h * HID + l * 8);
  const f32x4 hr0 = hrp[0], hr1 = hrp[1];

  float m = -1e30f, s = 0.f;
  f32x4 a0 = {0.f, 0.f, 0.f, 0.f}, a1 = {0.f, 0.f, 0.f, 0.f};
  for (int j = beg; j < end; j++) {
    int src = esrc[j];
    const f32x4* p = (const f32x4*)(hl + (size_t)src * HCX + h * HID + l * 8);
    f32x4 v0 = p[0], v1 = p[1];
    float sc = 0.f;
#pragma unroll
    for (int q = 0; q < 4; q++) {
      float g0 = v0[q] + hr0[q]; g0 = (g0 > 0.f) ? g0 : NEG_SLOPE * g0; sc += at0[q] * g0;
      float g1 = v1[q] + hr1[q]; g1 = (g1 > 0.f) ? g1 : NEG_SLOPE * g1; sc += at1[q] * g1;
    }
#pragma unroll
    for (int off = 16; off > 0; off >>= 1) sc += __shfl_xor(sc, off);
    float mn = fmaxf(m, sc);
    float fold = expf(m - mn);       // first iter: exp(-inf) = 0
    float e = expf(sc - mn);
    s = s * fold + e;
    a0 = a0 * fold + e * v0;
    a1 = a1 * fold + e * v1;
    m = mn;
  }
  float inv = 1.f / (s + 1e-16f);
  a0 *= inv;
  a1 *= inv;

  int cbase = h * HID + l * 8;
  if (MODE == 1) {
    float v[8];
#pragma unroll
    for (int q = 0; q < 4; q++) {
      float xx = a0[q] + bias[cbase + q];
      v[q] = (xx > 0.f) ? xx : (expf(xx) - 1.f);
    }
#pragma unroll
    for (int q = 0; q < 4; q++) {
      float xx = a1[q] + bias[cbase + 4 + q];
      v[4 + q] = (xx > 0.f) ? xx : (expf(xx) - 1.f);
    }
    s16x8 hv, lv;
    split8(v, hv, lv);
    *(s16x8*)&Chi[(size_t)n * HC + cbase] = hv;
    *(s16x8*)&Clo[(size_t)n * HC + cbase] = lv;
  } else {
    // head-mean + bias -> outf[n][HID]
    __shared__ float red[HC];
#pragma unroll
    for (int q = 0; q < 4; q++) red[cbase + q] = a0[q];
#pragma unroll
    for (int q = 0; q < 4; q++) red[cbase + 4 + q] = a1[q];
    __syncthreads();
    int c = t;  // 0..255
    float sm = 0.f;
#pragma unroll
    for (int hh = 0; hh < HEADS; hh++) sm += red[hh * HID + c];
    outf[(size_t)n * HID + c] = 0.125f * sm + bias[c];
  }
}

// ---------------- concat head weights: [256][128]|[256][128] -> [256][256] ----------------
__global__ void cat_heads(const float* __restrict__ Wp, const float* __restrict__ Ws,
                          const float* __restrict__ bp, const float* __restrict__ bs,
                          float* __restrict__ Wcat, float* __restrict__ bcat) {
  int r = blockIdx.x, c = threadIdx.x;   // 256 x 256
  Wcat[r * 256 + c] = (c < 128) ? Wp[r * 128 + c] : Ws[r * 128 + (c - 128)];
  if (r == 0) bcat[c] = (c < 128) ? bp[c] : bs[c - 128];
}

// ---------------- merged final projections (ReLU applied on read of hid) ----------------
// hid[N][256]: cols 0..127 = pam hidden (pre-relu), 128..255 = sur hidden (pre-relu)
__global__ void head_final2(const float* __restrict__ hid,
                            const float* __restrict__ Wp2, const float* __restrict__ bp2,
                            const float* __restrict__ Ws2, const float* __restrict__ bs2,
                            float* __restrict__ out_pam, float* __restrict__ out_sur,
                            int N) {
  int t = blockIdx.x * blockDim.x + threadIdx.x;
  if (t >= N * 6) return;
  int n = t / 6, j = t % 6;
  if (j < OUT_DIM) {
    float s = bp2[j];
    const float* row = hid + (size_t)n * 256;
    for (int k = 0; k < 128; k++) s += fmaxf(row[k], 0.f) * Wp2[k * OUT_DIM + j];
    out_pam[n * OUT_DIM + j] = s;
  } else {
    float s = bs2[0];
    const float* row = hid + (size_t)n * 256 + 128;
    for (int k = 0; k < 128; k++) s += fmaxf(row[k], 0.f) * Ws2[k];
    out_sur[n] = s;
  }
}

// ---------------- host side ----------------
extern "C" void kernel_launch(void* const* d_in, const int* in_sizes, int n_in,
                              void* d_out, int out_size, void* d_ws, size_t ws_size,
                              hipStream_t stream) {
  const float* x   = (const float*)d_in[0];
  const int*   ei  = (const int*)d_in[1];
  const float* Wl0 = (const float*)d_in[2];  const float* bl0 = (const float*)d_in[3];
  const float* Wr0 = (const float*)d_in[4];  const float* br0 = (const float*)d_in[5];
  const float* att0= (const float*)d_in[6];  const float* b0  = (const float*)d_in[7];
  const float* Wl1 = (const float*)d_in[8];  const float* bl1 = (const float*)d_in[9];
  const float* Wr1 = (const float*)d_in[10]; const float* br1 = (const float*)d_in[11];
  const float* att1= (const float*)d_in[12]; const float* b1  = (const float*)d_in[13];
  const float* Wl2 = (const float*)d_in[14]; const float* bl2 = (const float*)d_in[15];
  const float* Wr2 = (const float*)d_in[16]; const float* br2 = (const float*)d_in[17];
  const float* att2= (const float*)d_in[18]; const float* b2  = (const float*)d_in[19];
  const float* W_pam1 = (const float*)d_in[20]; const float* b_pam1 = (const float*)d_in[21];
  const float* W_pam2 = (const float*)d_in[22]; const float* b_pam2 = (const float*)d_in[23];
  const float* W_sur1 = (const float*)d_in[24]; const float* b_sur1 = (const float*)d_in[25];
  const float* W_sur2 = (const float*)d_in[26]; const float* b_sur2 = (const float*)d_in[27];

  const int N  = in_sizes[0] / IN_DIM;   // 10000
  const int E  = in_sizes[1] / 2;        // 40000
  const int Et = E + N;

  // ---- workspace layout (~263.1 MB; <= proven 263.4) ----
  char* p = (char*)d_ws;
  const size_t NF = (size_t)N * HC;
  float* bufAB = (float*)p;                 p += NF * 2 * 4;          // [N][4096] hl|hr fp32
  unsigned short* Chi = (unsigned short*)p; p += NF * 2;              // A hi plane
  unsigned short* Clo = (unsigned short*)p; p += NF * 2;              // A lo plane
  unsigned short* Wthi = (unsigned short*)p; p += (size_t)HC * HC * 2;
  unsigned short* Wtlo = (unsigned short*)p; p += (size_t)HC * HC * 2;
  int* row_off = (int*)p;                  p += (size_t)(N + 1) * 4;  // persistent CSR
  int* esrc    = (int*)p;                  p += (size_t)Et * 4;
  int* cnt     = (int*)p;                  p += (size_t)N * 4;
  int* fill    = (int*)p;                  p += (size_t)N * 4;
  float* Wcat  = (float*)p;                p += 256 * 256 * 4;        // merged head W
  float* bcat  = (float*)p;                p += 256 * 4;
  // layer-0 x planes alias Chi/Clo region (2 x N*IN_DIM shorts = 20.5 MB < 41 MB)
  unsigned short* Xhi = Chi;
  unsigned short* Xlo = Xhi + (size_t)N * IN_DIM;
  // head-stage buffers alias Chi/Clo (dead after layer-2 GEMMs)
  float* hfin = (float*)Chi;                         // N*HID fp32 (10.24 MB)
  unsigned short* Hhi = (unsigned short*)Clo;        // N*HID bf16 (5.12 MB)
  unsigned short* Hlo = Hhi + (size_t)N * HID;       // N*HID bf16
  float* hid  = (float*)(Hlo + (size_t)N * HID);     // N*256 fp32 (10.24 MB)

  float* out_pam = (float*)d_out;
  float* out_sur = out_pam + (size_t)N * OUT_DIM;

  float* hlp = bufAB;          // hl half (cols 0..2047), stride HCX
  float* hrp = bufAB + HC;     // hr half (cols 2048..4095), stride HCX

  // ---------- CSR build (graph identical for all layers) ----------
  hipMemsetAsync(cnt, 0, N * 4, stream);
  hipMemsetAsync(fill, 0, N * 4, stream);
  count_dst<<<(Et + 255) / 256, 256, 0, stream>>>(ei, cnt, E, Et);
  scan_offsets<<<1, SCAN_T, 0, stream>>>(cnt, row_off, N);
  scatter_edges<<<(Et + 255) / 256, 256, 0, stream>>>(ei, row_off, fill, esrc, E, Et);
  cat_heads<<<256, 256, 0, stream>>>(W_pam1, W_sur1, b_pam1, b_sur1, Wcat, bcat);

  // ---------- layer 0 (merged Wl|Wr, Nc=4096, K=512) ----------
  split_pad<<<(unsigned)(((long)N * IN_DIM / 4 + 255) / 256), 256, 0, stream>>>(
      x, Xhi, Xlo, (long)N * IN_DIM);
  {
    dim3 tg(HC / 32, IN_DIM / 32);
    wsplit_t<<<tg, 256, 0, stream>>>(Wl0, Wthi, Wtlo, IN_DIM, HC);
    wsplit_t<<<tg, 256, 0, stream>>>(Wr0, Wthi + (size_t)HC * IN_DIM,
                                     Wtlo + (size_t)HC * IN_DIM, IN_DIM, HC);
    dim3 grid(HCX / 128, (N + 127) / 128);
    gemm_planes2<<<grid, 256, 0, stream>>>(Xhi, Xlo, Wthi, Wtlo, bl0, br0,
                                           bufAB, N, HCX, HCX, IN_DIM, HC);
  }
  node_attn<1><<<N, 256, 0, stream>>>(hlp, hrp, row_off, esrc, att0, b0,
                                      nullptr, Chi, Clo, N);

  // ---------- layer 1 ----------
  {
    dim3 tg(HC / 32, HC / 32);
    dim3 grid(HC / 128, (N + 127) / 128);
    wsplit_t<<<tg, 256, 0, stream>>>(Wl1, Wthi, Wtlo, HC, HC);
    gemm_planes2<<<grid, 256, 0, stream>>>(Chi, Clo, Wthi, Wtlo, bl1, bl1,
                                           bufAB, N, HC, HCX, HC, HC);
    wsplit_t<<<tg, 256, 0, stream>>>(Wr1, Wthi, Wtlo, HC, HC);
    gemm_planes2<<<grid, 256, 0, stream>>>(Chi, Clo, Wthi, Wtlo, br1, br1,
                                           bufAB + HC, N, HC, HCX, HC, HC);
  }
  node_attn<1><<<N, 256, 0, stream>>>(hlp, hrp, row_off, esrc, att1, b1,
                                      nullptr, Chi, Clo, N);

  // ---------- layer 2 (fused head-mean) ----------
  {
    dim3 tg(HC / 32, HC / 32);
    dim3 grid(HC / 128, (N + 127) / 128);
    wsplit_t<<<tg, 256, 0, stream>>>(Wl2, Wthi, Wtlo, HC, HC);
    gemm_planes2<<<grid, 256, 0, stream>>>(Chi, Clo, Wthi, Wtlo, bl2, bl2,
                                           bufAB, N, HC, HCX, HC, HC);
    wsplit_t<<<tg, 256, 0, stream>>>(Wr2, Wthi, Wtlo, HC, HC);
    gemm_planes2<<<grid, 256, 0, stream>>>(Chi, Clo, Wthi, Wtlo, br2, br2,
                                           bufAB + HC, N, HC, HCX, HC, HC);
  }
  node_attn<0><<<N, 256, 0, stream>>>(hlp, hrp, row_off, esrc, att2, b2,
                                      hfin, nullptr, nullptr, N);

  // ---------- heads: MFMA first GEMM (ReLU deferred into head_final2) ----------
  split_pad<<<(unsigned)(((long)N * HID / 4 + 255) / 256), 256, 0, stream>>>(
      hfin, Hhi, Hlo, (long)N * HID);
  {
    dim3 tg(256 / 32, 256 / 32);
    wsplit_t<<<tg, 256, 0, stream>>>(Wcat, Wthi, Wtlo, 256, 256);
    dim3 grid(256 / 128, (N + 127) / 128);
    gemm_planes2<<<grid, 256, 0, stream>>>(Hhi, Hlo, Wthi, Wtlo, bcat, bcat,
                                           hid, N, 256, 256, 256, 256);
  }
  head_final2<<<(N * 6 + 255) / 256, 256, 0, stream>>>(
      hid, W_pam2, b_pam2, W_sur2, b_sur2, out_pam, out_sur, N);
}